// Round 1
// 628.909 us; speedup vs baseline: 1.0353x; 1.0353x over previous
//
#include <hip/hip_runtime.h>
#include <hip/hip_bf16.h>

// All inputs and the output are fp32 (established empirically in rounds 1-2).
// Workspace layout is lifetime-aliased (high-water 56.5 MiB; see round-5 note).
//
// ROUND 6: k_tobasis1 rewritten as split-precision f16x3 MFMA GEMM.
//   Old: fp32 outer-product, 138 us, VALUBusy 47%, MfmaUtil 0, hbm 12% --
//   LDS-BW co-saturated with VALU (0.5 B/FLOP), occupancy-capped at 2 blk/CU.
//   New: a = hi(f16) + lo(f16 residual); spec = ah*bh + ah*bl + al*bh with
//   v_mfma_f32_16x16x32_f16, fp32 accumulate (per-term rel err ~2^-22).
//   Staging: global_load_lds (16B) -> fp32 LDS scratch -> transpose+split into
//   [k][n]/[c][n] f16 hi/lo tiles -> contiguous f16x8 frag reads.
//   Raw s_barrier + explicit vmcnt/lgkmcnt so next strip's loads stay in
//   flight across compute (no __syncthreads vmcnt-drain).
//   Predicted: ~35-40 us, HBM-bound. Everything else unchanged.

#define Bn 4
#define Nn 32768
#define Kn 128
#define Cn 256
#define Mn 1024
#define Hn 8
#define Dn 32
#define NCH 64   // n-chunks for to_basis1 (chunk = 512 rows)
#define MCH 16   // m-chunks for to_basis2 (chunk = 64 rows)
#define SEG 8    // key segments in flash attention (128 keys each)

typedef _Float16 f16;
typedef _Float16 f16x8 __attribute__((ext_vector_type(8)));
typedef float f32x4 __attribute__((ext_vector_type(4)));

__device__ __forceinline__ void gload_lds16(const float* g, float* l) {
    __builtin_amdgcn_global_load_lds(
        (const __attribute__((address_space(1))) void*)g,
        (__attribute__((address_space(3))) void*)l, 16, 0, 0);
}

// ---------------------------------------------------------------------------
// K1: to_basis #1 (f16x3 MFMA).
// part[b][nch][k][c] = sum_{n in chunk} evecs[b,n,k] * x[b,n,c]*mass[b,n]
// Block: full 128K x 256C tile, 512 threads = 8 waves (2 m-halves x 4 c-qtrs),
// 16 strips of 32 rows. LDS 110.6 KB -> 1 block/CU.
// ---------------------------------------------------------------------------
__global__ __launch_bounds__(512) void k_tobasis1(
    const float* __restrict__ x, const float* __restrict__ mass,
    const float* __restrict__ evecs, float* __restrict__ part)
{
    const int nch = blockIdx.x, b = blockIdx.z;
    const int n0 = nch * (Nn / NCH);
    const int t = threadIdx.x;
    const int lane = t & 63, w = t >> 6;
    const int lr = lane & 15, lg = lane >> 4;
    const int wm = (w & 1) * 64;        // m-offset (k-basis rows)
    const int wc = (w >> 1) * 64;       // c-offset

    __shared__ float evS[32][128];                  // 16 KB fp32 scratch
    __shared__ float xS[32][256];                   // 32 KB fp32 scratch
    __shared__ __align__(16) f16 evH[128][40];      // [k][n] hi
    __shared__ __align__(16) f16 evL[128][40];      // [k][n] lo
    __shared__ __align__(16) f16 xH[256][40];       // [c][n] hi
    __shared__ __align__(16) f16 xL[256][40];       // [c][n] lo

    const size_t rb0 = (size_t)b * Nn + n0;

    f32x4 acc[4][4] = {};

    // prologue: stage strip 0 (ev: 16 x 1KB slices, x: 32 x 1KB slices)
    {
        const float* eb = evecs + rb0 * Kn;
        const float* xb = x + rb0 * Cn;
#pragma unroll
        for (int iw = 0; iw < 2; iw++) {
            const int sl = w * 2 + iw;
            gload_lds16(eb + sl * 256 + lane * 4, (float*)evS + sl * 256);
        }
#pragma unroll
        for (int iw = 0; iw < 4; iw++) {
            const int sl = w * 4 + iw;
            gload_lds16(xb + sl * 256 + lane * 4, (float*)xS + sl * 256);
        }
    }

    for (int s = 0; s < 16; s++) {
        // B1: this strip's global_load_lds data landed; f16 tiles free
        asm volatile("s_waitcnt vmcnt(0)" ::: "memory");
        __builtin_amdgcn_s_barrier();

        // phase2: scratch -> transposed f16 hi/lo tiles
        {
            const int k = (w & 1) * 64 + lane;   // = t & 127
            const int g = w >> 1;                // = t >> 7, wave-uniform
            f16x8 hv, lv;
#pragma unroll
            for (int r = 0; r < 8; r++) {
                const float f = evS[g * 8 + r][k];
                const f16 h = (f16)f;
                hv[r] = h;
                lv[r] = (f16)(f - (float)h);
            }
            *(f16x8*)&evH[k][g * 8] = hv;
            *(f16x8*)&evL[k][g * 8] = lv;
        }
#pragma unroll
        for (int i = 0; i < 2; i++) {
            const int c = (w & 3) * 64 + lane;   // = id & 255
            const int g = i * 2 + (w >> 2);      // = id >> 8, wave-uniform
            const size_t rowb = rb0 + s * 32 + g * 8;
            f16x8 hv, lv;
#pragma unroll
            for (int r = 0; r < 8; r++) {
                const float f = xS[g * 8 + r][c] * mass[rowb + r];
                const f16 h = (f16)f;
                hv[r] = h;
                lv[r] = (f16)(f - (float)h);
            }
            *(f16x8*)&xH[c][g * 8] = hv;
            *(f16x8*)&xL[c][g * 8] = lv;
        }

        // B2: f16 tiles visible to all waves; scratch fully consumed.
        // lgkm only -- next strip's loads must stay in flight past here.
        asm volatile("s_waitcnt lgkmcnt(0)" ::: "memory");
        __builtin_amdgcn_s_barrier();

        if (s < 15) {
            const float* eb = evecs + (rb0 + (size_t)(s + 1) * 32) * Kn;
            const float* xb = x + (rb0 + (size_t)(s + 1) * 32) * Cn;
#pragma unroll
            for (int iw = 0; iw < 2; iw++) {
                const int sl = w * 2 + iw;
                gload_lds16(eb + sl * 256 + lane * 4, (float*)evS + sl * 256);
            }
#pragma unroll
            for (int iw = 0; iw < 4; iw++) {
                const int sl = w * 4 + iw;
                gload_lds16(xb + sl * 256 + lane * 4, (float*)xS + sl * 256);
            }
        }

        // MFMA: A[m][n]=evecs[n][m] from evH/evL, B[n][c]=xm[n][c] from xH/xL
        f16x8 aH[4], aL[4], bH[4], bL[4];
#pragma unroll
        for (int i = 0; i < 4; i++) {
            aH[i] = *(const f16x8*)&evH[wm + i * 16 + lr][lg * 8];
            aL[i] = *(const f16x8*)&evL[wm + i * 16 + lr][lg * 8];
            bH[i] = *(const f16x8*)&xH[wc + i * 16 + lr][lg * 8];
            bL[i] = *(const f16x8*)&xL[wc + i * 16 + lr][lg * 8];
        }
#pragma unroll
        for (int i = 0; i < 4; i++)
#pragma unroll
            for (int j = 0; j < 4; j++) {
                acc[i][j] = __builtin_amdgcn_mfma_f32_16x16x32_f16(aH[i], bH[j], acc[i][j], 0, 0, 0);
                acc[i][j] = __builtin_amdgcn_mfma_f32_16x16x32_f16(aH[i], bL[j], acc[i][j], 0, 0, 0);
                acc[i][j] = __builtin_amdgcn_mfma_f32_16x16x32_f16(aL[i], bH[j], acc[i][j], 0, 0, 0);
            }
    }

    // epilogue: C/D layout col=lane&15, row=(lane>>4)*4+reg  [m89]
    float* dst = part + ((size_t)b * NCH + nch) * (Kn * Cn);
#pragma unroll
    for (int i = 0; i < 4; i++)
#pragma unroll
        for (int j = 0; j < 4; j++) {
            const int m0 = wm + i * 16 + lg * 4;
            const int c = wc + j * 16 + lr;
#pragma unroll
            for (int r = 0; r < 4; r++)
                dst[(size_t)(m0 + r) * Cn + c] = acc[i][j][r];
        }
}

// ---------------------------------------------------------------------------
// Reduce chunk partials and apply heat coefficient exp(-eval * t_c)
// ---------------------------------------------------------------------------
__global__ __launch_bounds__(256) void k_reduce(
    const float* __restrict__ part, int nchunks,
    const float* __restrict__ evals, const float* __restrict__ tvec,
    float* __restrict__ spec)
{
    const int b = blockIdx.x >> 7, k = blockIdx.x & 127, c = threadIdx.x;
    float ssum = 0.f;
    const float* p = part + ((size_t)b * nchunks * Kn + k) * Cn + c;
    for (int j = 0; j < nchunks; j++) ssum += p[(size_t)j * Kn * Cn];
    const float lam = evals[b * Kn + k];
    const float tt = fmaxf(tvec[c], 1e-8f);
    spec[((size_t)b * Kn + k) * Cn + c] = ssum * __expf(-lam * tt);
}

// ---------------------------------------------------------------------------
// Gather evecs & mass at far indices
// ---------------------------------------------------------------------------
__global__ __launch_bounds__(128) void k_gather(
    const float* __restrict__ evecs, const float* __restrict__ mass,
    const int* __restrict__ far, float* __restrict__ evf, float* __restrict__ massf)
{
    const int row = blockIdx.x;  // b*M + m
    const int b = row >> 10;
    const int idx = far[row];
    const int t = threadIdx.x;
    evf[(size_t)row * Kn + t] = evecs[((size_t)b * Nn + idx) * Kn + t];
    if (t == 0) massf[row] = mass[(size_t)b * Nn + idx];
}

// ---------------------------------------------------------------------------
// Generic 64x64-tile GEMM: out[row][c'] = X[row][0:KD] @ W[KD][256] (+bias)(*mass)
// ---------------------------------------------------------------------------
struct G3 {
    const float* W[3];
    const float* bias[3];
    float* out[3];
};

template<int KD, bool PERB, bool MMASS>
__global__ __launch_bounds__(256) void k_gemm64(
    const float* __restrict__ X, G3 g, const float* __restrict__ massf)
{
    const int mt = blockIdx.x, ct = blockIdx.y, z = blockIdx.z;
    const int row0 = mt * 64, c0 = ct * 64;
    const int b = row0 >> 10;
    const float* Wp = g.W[z];
    const float* bias = g.bias[z];
    float* out = g.out[z];
    const size_t woff = PERB ? (size_t)b * KD * 256 : 0;

    __shared__ float xT[32][68];   // 68*4 = 272 B rows (16B-aligned)
    __shared__ float wl[32][64];
    const int t = threadIdx.x, tx = t & 15, ty = t >> 4;
    float acc[4][4] = {};

    for (int k0 = 0; k0 < KD; k0 += 32) {
        {
            const int m = t >> 2, cc0 = (t & 3) * 8;
            const float* xs = X + (size_t)(row0 + m) * KD + k0 + cc0;
            float4 a0 = *(const float4*)xs, a1 = *(const float4*)(xs + 4);
            xT[cc0 + 0][m] = a0.x; xT[cc0 + 1][m] = a0.y; xT[cc0 + 2][m] = a0.z; xT[cc0 + 3][m] = a0.w;
            xT[cc0 + 4][m] = a1.x; xT[cc0 + 5][m] = a1.y; xT[cc0 + 6][m] = a1.z; xT[cc0 + 7][m] = a1.w;
        }
        {
            const int cc = t >> 3, col = (t & 7) * 8;
            const float* wsrc = Wp + woff + (size_t)(k0 + cc) * 256 + c0 + col;
            float4 a0 = *(const float4*)wsrc, a1 = *(const float4*)(wsrc + 4);
            wl[cc][col + 0] = a0.x; wl[cc][col + 1] = a0.y; wl[cc][col + 2] = a0.z; wl[cc][col + 3] = a0.w;
            wl[cc][col + 4] = a1.x; wl[cc][col + 5] = a1.y; wl[cc][col + 6] = a1.z; wl[cc][col + 7] = a1.w;
        }
        __syncthreads();
#pragma unroll 8
        for (int cc = 0; cc < 32; cc++) {
            float4 xv = *(const float4*)&xT[cc][ty * 4];
            float4 wv = *(const float4*)&wl[cc][tx * 4];
            float xa[4] = {xv.x, xv.y, xv.z, xv.w};
            float wa[4] = {wv.x, wv.y, wv.z, wv.w};
#pragma unroll
            for (int i = 0; i < 4; i++)
#pragma unroll
                for (int j = 0; j < 4; j++) acc[i][j] += xa[i] * wa[j];
        }
        __syncthreads();
    }
    float bj[4] = {0.f, 0.f, 0.f, 0.f};
    if (bias) {
#pragma unroll
        for (int j = 0; j < 4; j++) bj[j] = bias[c0 + tx * 4 + j];
    }
#pragma unroll
    for (int i = 0; i < 4; i++) {
        const int row = row0 + ty * 4 + i;
        const float mm = MMASS ? massf[row] : 1.f;
        *(float4*)(out + (size_t)row * 256 + c0 + tx * 4) =
            make_float4((acc[i][0] + bj[0]) * mm, (acc[i][1] + bj[1]) * mm,
                        (acc[i][2] + bj[2]) * mm, (acc[i][3] + bj[3]) * mm);
    }
}

// ---------------------------------------------------------------------------
// GroupNorm stats: per (b, g) mean/invstd over M x 8 channels
// ---------------------------------------------------------------------------
__global__ __launch_bounds__(256) void k_gnstats(const float* __restrict__ xfar, float* __restrict__ gst)
{
    const int b = blockIdx.x >> 5, g = blockIdx.x & 31;
    const int t = threadIdx.x;
    float s = 0.f, s2 = 0.f;
#pragma unroll
    for (int i = 0; i < 4; i++) {
        const int m = t * 4 + i;
        const float* p = xfar + ((size_t)b * Mn + m) * Cn + g * 8;
        float4 a = *(const float4*)p;
        float4 c = *(const float4*)(p + 4);
        s += a.x + a.y + a.z + a.w + c.x + c.y + c.z + c.w;
        s2 += a.x * a.x + a.y * a.y + a.z * a.z + a.w * a.w +
              c.x * c.x + c.y * c.y + c.z * c.z + c.w * c.w;
    }
    __shared__ float sb[256], sb2[256];
    sb[t] = s; sb2[t] = s2;
    __syncthreads();
    for (int o = 128; o > 0; o >>= 1) {
        if (t < o) { sb[t] += sb[t + o]; sb2[t] += sb2[t + o]; }
        __syncthreads();
    }
    if (t == 0) {
        const float mean = sb[0] * (1.f / 8192.f);
        const float var = sb2[0] * (1.f / 8192.f) - mean * mean;
        gst[2 * blockIdx.x] = mean;
        gst[2 * blockIdx.x + 1] = rsqrtf(var + 1e-6f);
    }
}

__global__ __launch_bounds__(256) void k_gnapply(
    const float* __restrict__ xfar, const float* __restrict__ gst,
    const float* __restrict__ gw, const float* __restrict__ gb, float* __restrict__ xn)
{
    const int idx = (blockIdx.x * 256 + threadIdx.x) * 4;
    const int c = idx & 255;
    const int row = idx >> 8;
    const int b = row >> 10;
    const int g = c >> 3;
    const float2 st = *(const float2*)&gst[2 * (b * 32 + g)];
    float4 vv = *(const float4*)&xfar[idx];
    float4 w4 = *(const float4*)&gw[c];
    float4 b4 = *(const float4*)&gb[c];
    float4 o;
    o.x = (vv.x - st.x) * st.y * w4.x + b4.x;
    o.y = (vv.y - st.x) * st.y * w4.y + b4.y;
    o.z = (vv.z - st.x) * st.y * w4.z + b4.z;
    o.w = (vv.w - st.x) * st.y * w4.w + b4.w;
    *(float4*)&xn[idx] = o;
}

// ---------------------------------------------------------------------------
// Flash attention, outer-product tiles (64 q x 128 keys per block).
// ---------------------------------------------------------------------------
__global__ __launch_bounds__(256) void k_attn(
    const float* __restrict__ q, const float* __restrict__ kbuf, const float* __restrict__ vbuf,
    float* __restrict__ pacc, float* __restrict__ pm, float* __restrict__ pl)
{
    const int qt = blockIdx.x;      // 16 tiles of 64 q-rows
    const int seg = blockIdx.y;     // SEG segs of 128 keys
    const int bh = blockIdx.z;
    const int b = bh >> 3, h = bh & 7;
    const int t = threadIdx.x;
    const int tx = t & 15, ty = t >> 4;

    __shared__ float qT[32][68];    // [d][q-row]
    __shared__ float kT[32][68];    // [d][key]
    __shared__ float vsm[64][36];   // [key][d]
    __shared__ float psT[64][72];   // [key][q-row]
    __shared__ float red[64][16];   // per-q-row cross-thread partials

    const int q0 = qt * 64;
    {
        const int row = t >> 2, d0 = (t & 3) * 8;
        const float* qp = q + ((size_t)b * Mn + q0 + row) * Cn + h * Dn + d0;
        float4 a0 = *(const float4*)qp, a1 = *(const float4*)(qp + 4);
        qT[d0 + 0][row] = a0.x; qT[d0 + 1][row] = a0.y; qT[d0 + 2][row] = a0.z; qT[d0 + 3][row] = a0.w;
        qT[d0 + 4][row] = a1.x; qT[d0 + 5][row] = a1.y; qT[d0 + 6][row] = a1.z; qT[d0 + 7][row] = a1.w;
    }

    const float scale = 0.17677669529663687f;  // 1/sqrt(32)
    float m_i[4], l_i[4], acc[4][2];
#pragma unroll
    for (int i = 0; i < 4; i++) { m_i[i] = -1e30f; l_i[i] = 0.f; acc[i][0] = 0.f; acc[i][1] = 0.f; }

    for (int kt = 0; kt < 2; kt++) {
        __syncthreads();  // qT visible (kt=0); psT/kT/vsm reads done (kt=1)
        {
            const int row = t >> 2, d0 = (t & 3) * 8;
            const int k0 = seg * 128 + kt * 64;
            const float* kp = kbuf + ((size_t)b * Mn + k0 + row) * Cn + h * Dn + d0;
            float4 a0 = *(const float4*)kp, a1 = *(const float4*)(kp + 4);
            kT[d0 + 0][row] = a0.x; kT[d0 + 1][row] = a0.y; kT[d0 + 2][row] = a0.z; kT[d0 + 3][row] = a0.w;
            kT[d0 + 4][row] = a1.x; kT[d0 + 5][row] = a1.y; kT[d0 + 6][row] = a1.z; kT[d0 + 7][row] = a1.w;
            const float* vp = vbuf + ((size_t)b * Mn + k0 + row) * Cn + h * Dn + d0;
            *(float4*)&vsm[row][d0] = *(const float4*)vp;
            *(float4*)&vsm[row][d0 + 4] = *(const float4*)(vp + 4);
        }
        __syncthreads();

        float s[4][4] = {};
#pragma unroll 8
        for (int d = 0; d < 32; d++) {
            float4 qv = *(const float4*)&qT[d][ty * 4];
            float4 kv = *(const float4*)&kT[d][tx * 4];
            float qa[4] = {qv.x, qv.y, qv.z, qv.w};
            float ka[4] = {kv.x, kv.y, kv.z, kv.w};
#pragma unroll
            for (int i = 0; i < 4; i++)
#pragma unroll
                for (int j = 0; j < 4; j++) s[i][j] += qa[i] * ka[j];
        }
        float tmax[4];
#pragma unroll
        for (int i = 0; i < 4; i++) {
            s[i][0] *= scale; s[i][1] *= scale; s[i][2] *= scale; s[i][3] *= scale;
            tmax[i] = fmaxf(fmaxf(s[i][0], s[i][1]), fmaxf(s[i][2], s[i][3]));
        }
#pragma unroll
        for (int i = 0; i < 4; i++) red[ty * 4 + i][tx] = tmax[i];
        __syncthreads();
        float nm[4];
#pragma unroll
        for (int i = 0; i < 4; i++) {
            const int row = ty * 4 + i;
            float mx = m_i[i];
#pragma unroll
            for (int xj = 0; xj < 16; xj++) mx = fmaxf(mx, red[row][xj]);
            nm[i] = mx;
        }
        __syncthreads();  // red reads done before sum-phase writes
        float tsum[4];
#pragma unroll
        for (int i = 0; i < 4; i++) {
            float p0 = __expf(s[i][0] - nm[i]);
            float p1 = __expf(s[i][1] - nm[i]);
            float p2 = __expf(s[i][2] - nm[i]);
            float p3 = __expf(s[i][3] - nm[i]);
            s[i][0] = p0; s[i][1] = p1; s[i][2] = p2; s[i][3] = p3;
            tsum[i] = p0 + p1 + p2 + p3;
        }
#pragma unroll
        for (int kk = 0; kk < 4; kk++)
            *(float4*)&psT[tx * 4 + kk][ty * 4] = make_float4(s[0][kk], s[1][kk], s[2][kk], s[3][kk]);
#pragma unroll
        for (int i = 0; i < 4; i++) red[ty * 4 + i][tx] = tsum[i];
        __syncthreads();
#pragma unroll
        for (int i = 0; i < 4; i++) {
            const int row = ty * 4 + i;
            float rs = 0.f;
#pragma unroll
            for (int xj = 0; xj < 16; xj++) rs += red[row][xj];
            const float r = __expf(m_i[i] - nm[i]);
            l_i[i] = l_i[i] * r + rs;
            m_i[i] = nm[i];
            acc[i][0] *= r; acc[i][1] *= r;
        }
#pragma unroll 8
        for (int k = 0; k < 64; k++) {
            float4 pv = *(const float4*)&psT[k][ty * 4];
            float2 vv = *(const float2*)&vsm[k][tx * 2];
            acc[0][0] += pv.x * vv.x; acc[0][1] += pv.x * vv.y;
            acc[1][0] += pv.y * vv.x; acc[1][1] += pv.y * vv.y;
            acc[2][0] += pv.z * vv.x; acc[2][1] += pv.z * vv.y;
            acc[3][0] += pv.w * vv.x; acc[3][1] += pv.w * vv.y;
        }
    }
#pragma unroll
    for (int i = 0; i < 4; i++) {
        const int m = q0 + ty * 4 + i;
        const size_t pr = (((size_t)seg * Bn + b) * Hn + h) * Mn + m;
        if (tx == 0) { pm[pr] = m_i[i]; pl[pr] = l_i[i]; }
        *(float2*)(pacc + pr * 32 + tx * 2) = make_float2(acc[i][0], acc[i][1]);
    }
}

__global__ __launch_bounds__(256) void k_comb(
    const float* __restrict__ pacc, const float* __restrict__ pm, const float* __restrict__ pl,
    float* __restrict__ att)
{
    const int t = threadIdx.x;
    const size_t row = (size_t)blockIdx.x * 8 + (t >> 5);  // (b*8+h)*1024 + m
    const int j = t & 31;
    float M = -1e30f;
#pragma unroll
    for (int s = 0; s < SEG; s++) M = fmaxf(M, pm[(size_t)s * 32768 + row]);
    float L = 0.f, a = 0.f;
#pragma unroll
    for (int s = 0; s < SEG; s++) {
        const float w = __expf(pm[(size_t)s * 32768 + row] - M);
        L += w * pl[(size_t)s * 32768 + row];
        a += w * pacc[((size_t)s * 32768 + row) * 32 + j];
    }
    const int bh = (int)(row >> 10);
    const int mrow = (int)(row & 1023);
    const int b = bh >> 3, h = bh & 7;
    att[((size_t)b * Mn + mrow) * Cn + h * 32 + j] = a / L;
}

// ---------------------------------------------------------------------------
// to_basis #2 over far rows only
// ---------------------------------------------------------------------------
__global__ __launch_bounds__(256) void k_tobasis2(
    const float* __restrict__ evf, const float* __restrict__ xo, float* __restrict__ part)
{
    const int mch = blockIdx.x, ct = blockIdx.y, b = blockIdx.z;
    const int m0 = mch * (Mn / MCH);
    const int c0 = ct * 128;
    __shared__ float ev[32][128];
    __shared__ float xm[32][128];
    const int t = threadIdx.x, tx = t & 15, ty = t >> 4;
    float acc[8][8];
#pragma unroll
    for (int i = 0; i < 8; i++)
#pragma unroll
        for (int j = 0; j < 8; j++) acc[i][j] = 0.f;
    const int lr = t >> 3, lc = (t & 7) * 16;
    for (int s = 0; s < Mn / MCH; s += 32) {
        const size_t mrow = (size_t)b * Mn + m0 + s + lr;
        {
            const float* es = evf + mrow * Kn + lc;
            *(float4*)&ev[lr][lc]      = *(const float4*)es;
            *(float4*)&ev[lr][lc + 4]  = *(const float4*)(es + 4);
            *(float4*)&ev[lr][lc + 8]  = *(const float4*)(es + 8);
            *(float4*)&ev[lr][lc + 12] = *(const float4*)(es + 12);
            const float* xs = xo + mrow * Cn + c0 + lc;
            *(float4*)&xm[lr][lc]      = *(const float4*)xs;
            *(float4*)&xm[lr][lc + 4]  = *(const float4*)(xs + 4);
            *(float4*)&xm[lr][lc + 8]  = *(const float4*)(xs + 8);
            *(float4*)&xm[lr][lc + 12] = *(const float4*)(xs + 12);
        }
        __syncthreads();
#pragma unroll 4
        for (int nn = 0; nn < 32; nn++) {
            float4 e0 = *(const float4*)&ev[nn][ty * 4];
            float4 e1 = *(const float4*)&ev[nn][64 + ty * 4];
            float4 x0 = *(const float4*)&xm[nn][tx * 4];
            float4 x1 = *(const float4*)&xm[nn][64 + tx * 4];
            float ee[8] = {e0.x, e0.y, e0.z, e0.w, e1.x, e1.y, e1.z, e1.w};
            float xx[8] = {x0.x, x0.y, x0.z, x0.w, x1.x, x1.y, x1.z, x1.w};
#pragma unroll
            for (int i = 0; i < 8; i++)
#pragma unroll
                for (int j = 0; j < 8; j++) acc[i][j] += ee[i] * xx[j];
        }
        __syncthreads();
    }
    float* dst = part + ((size_t)b * MCH + mch) * (Kn * Cn);
#pragma unroll
    for (int i = 0; i < 8; i++) {
        const int k = (i < 4) ? (ty * 4 + i) : (64 + ty * 4 + i - 4);
        *(float4*)(dst + (size_t)k * Cn + c0 + tx * 4) =
            make_float4(acc[i][0], acc[i][1], acc[i][2], acc[i][3]);
        *(float4*)(dst + (size_t)k * Cn + c0 + 64 + tx * 4) =
            make_float4(acc[i][4], acc[i][5], acc[i][6], acc[i][7]);
    }
}

// ---------------------------------------------------------------------------
// from_basis #2: out[b,n,c] = out_w[c] * sum_k evecs[b,n,k]*spec2'[b,k,c]
// ---------------------------------------------------------------------------
__global__ __launch_bounds__(256) void k_frombasis2(
    const float* __restrict__ evecs, const float* __restrict__ spec,
    const float* __restrict__ outw, float* __restrict__ out)
{
    const int nt = blockIdx.x, ct = blockIdx.y, b = blockIdx.z;
    const int n0 = nt * 128, c0 = ct * 128;
    __shared__ float evT[32][132];
    __shared__ float sp[32][128];
    const int t = threadIdx.x, tx = t & 15, ty = t >> 4;
    float acc[8][8];
#pragma unroll
    for (int i = 0; i < 8; i++)
#pragma unroll
        for (int j = 0; j < 8; j++) acc[i][j] = 0.f;
    const int en = t >> 1, ek0 = (t & 1) * 16;
    const int sr = t >> 3, sc = (t & 7) * 16;
    for (int k0 = 0; k0 < Kn; k0 += 32) {
        {
            const float* es = evecs + ((size_t)b * Nn + n0 + en) * Kn + k0 + ek0;
            float4 a0 = *(const float4*)es, a1 = *(const float4*)(es + 4);
            float4 a2 = *(const float4*)(es + 8), a3 = *(const float4*)(es + 12);
            evT[ek0 + 0][en] = a0.x; evT[ek0 + 1][en] = a0.y; evT[ek0 + 2][en] = a0.z; evT[ek0 + 3][en] = a0.w;
            evT[ek0 + 4][en] = a1.x; evT[ek0 + 5][en] = a1.y; evT[ek0 + 6][en] = a1.z; evT[ek0 + 7][en] = a1.w;
            evT[ek0 + 8][en] = a2.x; evT[ek0 + 9][en] = a2.y; evT[ek0 + 10][en] = a2.z; evT[ek0 + 11][en] = a2.w;
            evT[ek0 + 12][en] = a3.x; evT[ek0 + 13][en] = a3.y; evT[ek0 + 14][en] = a3.z; evT[ek0 + 15][en] = a3.w;
            const float* ss = spec + ((size_t)b * Kn + k0 + sr) * Cn + c0 + sc;
            *(float4*)&sp[sr][sc]      = *(const float4*)ss;
            *(float4*)&sp[sr][sc + 4]  = *(const float4*)(ss + 4);
            *(float4*)&sp[sr][sc + 8]  = *(const float4*)(ss + 8);
            *(float4*)&sp[sr][sc + 12] = *(const float4*)(ss + 12);
        }
        __syncthreads();
#pragma unroll 4
        for (int kk2 = 0; kk2 < 32; kk2++) {
            float4 e0 = *(const float4*)&evT[kk2][ty * 4];
            float4 e1 = *(const float4*)&evT[kk2][64 + ty * 4];
            float4 s0 = *(const float4*)&sp[kk2][tx * 4];
            float4 s1 = *(const float4*)&sp[kk2][64 + tx * 4];
            float ee[8] = {e0.x, e0.y, e0.z, e0.w, e1.x, e1.y, e1.z, e1.w};
            float sv[8] = {s0.x, s0.y, s0.z, s0.w, s1.x, s1.y, s1.z, s1.w};
#pragma unroll
            for (int i = 0; i < 8; i++)
#pragma unroll
                for (int j = 0; j < 8; j++) acc[i][j] += ee[i] * sv[j];
        }
        __syncthreads();
    }
    float ow[8];
#pragma unroll
    for (int j = 0; j < 8; j++) {
        const int c = c0 + ((j < 4) ? (tx * 4 + j) : (64 + tx * 4 + j - 4));
        ow[j] = fmaxf(outw[c], 1e-8f);
    }
#pragma unroll
    for (int i = 0; i < 8; i++) {
        const int n = n0 + ((i < 4) ? (ty * 4 + i) : (64 + ty * 4 + i - 4));
        float* od = out + ((size_t)b * Nn + n) * Cn + c0;
        *(float4*)(od + tx * 4) =
            make_float4(acc[i][0] * ow[0], acc[i][1] * ow[1], acc[i][2] * ow[2], acc[i][3] * ow[3]);
        *(float4*)(od + 64 + tx * 4) =
            make_float4(acc[i][4] * ow[4], acc[i][5] * ow[5], acc[i][6] * ow[6], acc[i][7] * ow[7]);
    }
}

// ---------------------------------------------------------------------------
extern "C" void kernel_launch(void* const* d_in, const int* in_sizes, int n_in,
                              void* d_out, int out_size, void* d_ws, size_t ws_size,
                              hipStream_t stream)
{
    const float* x     = (const float*)d_in[0];
    const float* mass  = (const float*)d_in[1];
    const float* evals = (const float*)d_in[2];
    const float* evecs = (const float*)d_in[3];
    const int*   far   = (const int*)d_in[4];
    const float* t_in  = (const float*)d_in[5];
    const float* t_out = (const float*)d_in[6];
    const float* gn_w  = (const float*)d_in[7];
    const float* gn_b  = (const float*)d_in[8];
    const float* Wq    = (const float*)d_in[9];
    const float* bq    = (const float*)d_in[10];
    const float* Wk    = (const float*)d_in[11];
    const float* bk    = (const float*)d_in[12];
    const float* Wv    = (const float*)d_in[13];
    const float* bv    = (const float*)d_in[14];
    const float* Wo    = (const float*)d_in[15];
    const float* bo    = (const float*)d_in[16];
    const float* outw  = (const float*)d_in[17];
    float* out = (float*)d_out;
    float* ws = (float*)d_ws;

    // --- Tight lifetime-aliased workspace layout (high-water 14,815,488 floats
    // = 56.5 MiB). Lifetimes:
    //   A: part1(k1-2) -> pacc(k8-9) -> part2(k11-12)
    //   spec1(k2-4) / spec2(k11-12) share; xfar(k4-5) / xo(k9-10) share;
    //   xn(k5-6) / att(k8-9) share; q,kk,v(k6-7) exclusive.
    float* A     = ws;                      // 8,388,608
    float* evf   = ws    + 8388608;         //   524,288 (k3..k10)
    float* massf = evf   + 524288;          //     4,096 (k3..k9)
    float* gst   = massf + 4096;            //       256
    float* pm    = gst   + 256;             //   262,144 (k7..k8)
    float* pl    = pm    + 262144;          //   262,144
    float* spec1 = pl    + 262144;          //   131,072
    float* xfar  = spec1 + 131072;          // 1,048,576
    float* xn    = xfar  + 1048576;         // 1,048,576
    float* q     = xn    + 1048576;         // 1,048,576
    float* kk    = q     + 1048576;         // 1,048,576
    float* v     = kk    + 1048576;         // 1,048,576  (ends at 14,815,488)
    float* pacc  = A;
    float* part2 = A;
    float* spec2 = spec1;   // spec1 dead after from_basis1
    float* xo    = xfar;    // xfar dead after gnapply
    float* att   = xn;      // xn dead after QKV gemm

    k_tobasis1<<<dim3(NCH, 1, Bn), 512, 0, stream>>>(x, mass, evecs, A);
    k_reduce<<<Bn * Kn, Cn, 0, stream>>>(A, NCH, evals, t_in, spec1);
    k_gather<<<Bn * Mn, Kn, 0, stream>>>(evecs, mass, far, evf, massf);
    {
        G3 g{};
        g.W[0] = spec1; g.bias[0] = nullptr; g.out[0] = xfar;
        k_gemm64<128, true, false><<<dim3(64, 4, 1), 256, 0, stream>>>(evf, g, nullptr);
    }
    k_gnstats<<<Bn * 32, 256, 0, stream>>>(xfar, gst);
    k_gnapply<<<1024, 256, 0, stream>>>(xfar, gst, gn_w, gn_b, xn);
    {
        G3 g{};
        g.W[0] = Wq; g.W[1] = Wk; g.W[2] = Wv;
        g.bias[0] = bq; g.bias[1] = bk; g.bias[2] = bv;
        g.out[0] = q; g.out[1] = kk; g.out[2] = v;
        k_gemm64<256, false, false><<<dim3(64, 4, 3), 256, 0, stream>>>(xn, g, nullptr);
    }
    k_attn<<<dim3(16, SEG, 32), 256, 0, stream>>>(q, kk, v, pacc, pm, pl);
    k_comb<<<4096, 256, 0, stream>>>(pacc, pm, pl, att);
    {
        G3 g{};
        g.W[0] = Wo; g.bias[0] = bo; g.out[0] = xo;
        k_gemm64<256, false, true><<<dim3(64, 4, 1), 256, 0, stream>>>(att, g, massf);
    }
    k_tobasis2<<<dim3(MCH, 2, Bn), 256, 0, stream>>>(evf, xo, part2);
    k_reduce<<<Bn * Kn, Cn, 0, stream>>>(part2, MCH, evals, t_out, spec2);
    k_frombasis2<<<dim3(256, 2, Bn), 256, 0, stream>>>(evecs, spec2, outw, out);
}

// Round 2
// 600.712 us; speedup vs baseline: 1.0839x; 1.0469x over previous
//
#include <hip/hip_runtime.h>
#include <hip/hip_bf16.h>

// All inputs and the output are fp32 (established empirically in rounds 1-2).
// Workspace layout is lifetime-aliased (high-water 56.5 MiB; see round-5 note).
//
// ROUND 7: k_tobasis1 f16x3 MFMA, take 2.
//   Round-6 version landed at ~116 us (total only -22): the [*][40] f16 tiles
//   (80 B rows = 20 dwords, period-8 bank cycle) made EVERY ds_read_b128 /
//   ds_write_b128 an 8-way conflict (~67 us of LDS serialization), and the
//   per-strip vmcnt(0) drain + in-loop global mass[] loads added stall bubbles.
//   Fixes:
//   (1) hi|lo interleaved [row][64] f16 tiles (128 B rows, 8x16B chunks,
//       chunk' = chunk ^ (row&7) XOR swizzle) -> balanced banks on both the
//       transpose writes and the frag reads (conflict-free).
//   (2) double-buffered fp32 scratch + counted s_waitcnt vmcnt(6): strip s+2
//       stages while strip s computes; memory never drains in the main loop.
//   (3) mass[] staged to LDS once in the prologue.
//   Predicted: ~38 us, HBM-bound (~230 MB traffic). Everything else unchanged.

#define Bn 4
#define Nn 32768
#define Kn 128
#define Cn 256
#define Mn 1024
#define Hn 8
#define Dn 32
#define NCH 64   // n-chunks for to_basis1 (chunk = 512 rows)
#define MCH 16   // m-chunks for to_basis2 (chunk = 64 rows)
#define SEG 8    // key segments in flash attention (128 keys each)

typedef _Float16 f16;
typedef _Float16 f16x8 __attribute__((ext_vector_type(8)));
typedef float f32x4 __attribute__((ext_vector_type(4)));

__device__ __forceinline__ void gload_lds16(const float* g, float* l) {
    __builtin_amdgcn_global_load_lds(
        (const __attribute__((address_space(1))) void*)g,
        (__attribute__((address_space(3))) void*)l, 16, 0, 0);
}

// ---------------------------------------------------------------------------
// K1: to_basis #1 (f16x3 MFMA).
// part[b][nch][k][c] = sum_{n in chunk} evecs[b,n,k] * x[b,n,c]*mass[b,n]
// Block: full 128K x 256C tile, 512 threads = 8 waves (2 k-halves x 4 c-qtrs),
// 16 strips of 32 rows. LDS 146 KB -> 1 block/CU, 2 waves/SIMD.
// ---------------------------------------------------------------------------
__global__ __launch_bounds__(512) void k_tobasis1(
    const float* __restrict__ x, const float* __restrict__ mass,
    const float* __restrict__ evecs, float* __restrict__ part)
{
    const int nch = blockIdx.x, b = blockIdx.z;
    const int n0 = nch * (Nn / NCH);
    const int t = threadIdx.x;
    const int lane = t & 63, w = t >> 6;
    const int lr = lane & 15, lg = lane >> 4;
    const int wm = (w & 1) * 64;        // k-offset (basis rows)
    const int wc = (w >> 1) * 64;       // c-offset

    // double-buffered fp32 scratch + swizzled interleaved f16 tiles
    __shared__ __align__(16) float evS[2][32][128];   // 32 KB
    __shared__ __align__(16) float xS[2][32][256];    // 64 KB
    __shared__ __align__(16) f16 evT[128][64];        // 16 KB  hi|lo interleaved
    __shared__ __align__(16) f16 xT[256][64];         // 32 KB  hi|lo interleaved
    __shared__ __align__(16) float massS[512];        //  2 KB

    const size_t rb0 = (size_t)b * Nn + n0;
    const float* ebase = evecs + rb0 * Kn;
    const float* xbase = x + rb0 * Cn;

    f32x4 acc[4][4] = {};

    // prologue: mass (2 wave-loads), then strips 0 and 1 (6 wave-loads each)
    if (w < 2) gload_lds16(mass + rb0 + w * 256 + lane * 4, massS + w * 256);
#pragma unroll
    for (int ss = 0; ss < 2; ss++) {
        const float* eb = ebase + (size_t)ss * 32 * Kn;
        const float* xb = xbase + (size_t)ss * 32 * Cn;
#pragma unroll
        for (int iw = 0; iw < 2; iw++)
            gload_lds16(eb + (w * 2 + iw) * 256 + lane * 4, &evS[ss][0][0] + (w * 2 + iw) * 256);
#pragma unroll
        for (int iw = 0; iw < 4; iw++)
            gload_lds16(xb + (w * 4 + iw) * 256 + lane * 4, &xS[ss][0][0] + (w * 4 + iw) * 256);
    }

    for (int s = 0; s < 16; s++) {
        const int p = s & 1;
        // strip s's loads (oldest 6, plus mass on waves 0-1 at s=0) must land;
        // strip s+1's 6 loads stay in flight.
        if (s == 15) { asm volatile("s_waitcnt vmcnt(0)" ::: "memory"); }
        else         { asm volatile("s_waitcnt vmcnt(6)" ::: "memory"); }
        __builtin_amdgcn_sched_barrier(0);
        __builtin_amdgcn_s_barrier();

        // transpose+split ev: thread -> tile row k, n-group g (8 n's)
        {
            const int k = t & 127;
            const int g = t >> 7;          // wave-uniform
            f16x8 hv, lv;
#pragma unroll
            for (int r = 0; r < 8; r++) {
                const float f = evS[p][g * 8 + r][k];
                const f16 h = (f16)f;
                hv[r] = h;
                lv[r] = (f16)(f - (float)h);
            }
            *(f16x8*)&evT[k][((g) ^ (k & 7)) * 8] = hv;
            *(f16x8*)&evT[k][((4 + g) ^ (k & 7)) * 8] = lv;
        }
        // transpose+split x*mass: thread -> tile row c, two n-groups
        {
            const int c = t & 255;
            const int g2 = t >> 8;         // wave-uniform
#pragma unroll
            for (int jj = 0; jj < 2; jj++) {
                const int ch = g2 * 2 + jj;
                f16x8 hv, lv;
#pragma unroll
                for (int r = 0; r < 8; r++) {
                    const int n = ch * 8 + r;
                    const float f = xS[p][n][c] * massS[s * 32 + n];
                    const f16 h = (f16)f;
                    hv[r] = h;
                    lv[r] = (f16)(f - (float)h);
                }
                *(f16x8*)&xT[c][((ch) ^ (c & 7)) * 8] = hv;
                *(f16x8*)&xT[c][((4 + ch) ^ (c & 7)) * 8] = lv;
            }
        }

        // tiles visible to all waves; scratch buf p fully consumed
        asm volatile("s_waitcnt lgkmcnt(0)" ::: "memory");
        __builtin_amdgcn_sched_barrier(0);
        __builtin_amdgcn_s_barrier();

        // stage strip s+2 into buf p (overlaps the MFMA phase below)
        if (s + 2 < 16) {
            const float* eb = ebase + (size_t)(s + 2) * 32 * Kn;
            const float* xb = xbase + (size_t)(s + 2) * 32 * Cn;
#pragma unroll
            for (int iw = 0; iw < 2; iw++)
                gload_lds16(eb + (w * 2 + iw) * 256 + lane * 4, &evS[p][0][0] + (w * 2 + iw) * 256);
#pragma unroll
            for (int iw = 0; iw < 4; iw++)
                gload_lds16(xb + (w * 4 + iw) * 256 + lane * 4, &xS[p][0][0] + (w * 4 + iw) * 256);
        }

        // frag reads (swizzled, conflict-free) + MFMA
        f16x8 aH[4], aL[4], bH[4], bL[4];
#pragma unroll
        for (int i = 0; i < 4; i++) {
            const int rk = wm + i * 16 + lr;
            aH[i] = *(const f16x8*)&evT[rk][((lg) ^ (rk & 7)) * 8];
            aL[i] = *(const f16x8*)&evT[rk][((4 + lg) ^ (rk & 7)) * 8];
            const int rc = wc + i * 16 + lr;
            bH[i] = *(const f16x8*)&xT[rc][((lg) ^ (rc & 7)) * 8];
            bL[i] = *(const f16x8*)&xT[rc][((4 + lg) ^ (rc & 7)) * 8];
        }
#pragma unroll
        for (int i = 0; i < 4; i++)
#pragma unroll
            for (int j = 0; j < 4; j++) {
                acc[i][j] = __builtin_amdgcn_mfma_f32_16x16x32_f16(aH[i], bH[j], acc[i][j], 0, 0, 0);
                acc[i][j] = __builtin_amdgcn_mfma_f32_16x16x32_f16(aH[i], bL[j], acc[i][j], 0, 0, 0);
                acc[i][j] = __builtin_amdgcn_mfma_f32_16x16x32_f16(aL[i], bH[j], acc[i][j], 0, 0, 0);
            }
    }

    // epilogue: C/D layout col=lane&15, row=(lane>>4)*4+reg  [m89]
    float* dst = part + ((size_t)b * NCH + nch) * (Kn * Cn);
#pragma unroll
    for (int i = 0; i < 4; i++)
#pragma unroll
        for (int j = 0; j < 4; j++) {
            const int m0 = wm + i * 16 + lg * 4;
            const int c = wc + j * 16 + lr;
#pragma unroll
            for (int r = 0; r < 4; r++)
                dst[(size_t)(m0 + r) * Cn + c] = acc[i][j][r];
        }
}

// ---------------------------------------------------------------------------
// Reduce chunk partials and apply heat coefficient exp(-eval * t_c)
// ---------------------------------------------------------------------------
__global__ __launch_bounds__(256) void k_reduce(
    const float* __restrict__ part, int nchunks,
    const float* __restrict__ evals, const float* __restrict__ tvec,
    float* __restrict__ spec)
{
    const int b = blockIdx.x >> 7, k = blockIdx.x & 127, c = threadIdx.x;
    float ssum = 0.f;
    const float* p = part + ((size_t)b * nchunks * Kn + k) * Cn + c;
    for (int j = 0; j < nchunks; j++) ssum += p[(size_t)j * Kn * Cn];
    const float lam = evals[b * Kn + k];
    const float tt = fmaxf(tvec[c], 1e-8f);
    spec[((size_t)b * Kn + k) * Cn + c] = ssum * __expf(-lam * tt);
}

// ---------------------------------------------------------------------------
// Gather evecs & mass at far indices
// ---------------------------------------------------------------------------
__global__ __launch_bounds__(128) void k_gather(
    const float* __restrict__ evecs, const float* __restrict__ mass,
    const int* __restrict__ far, float* __restrict__ evf, float* __restrict__ massf)
{
    const int row = blockIdx.x;  // b*M + m
    const int b = row >> 10;
    const int idx = far[row];
    const int t = threadIdx.x;
    evf[(size_t)row * Kn + t] = evecs[((size_t)b * Nn + idx) * Kn + t];
    if (t == 0) massf[row] = mass[(size_t)b * Nn + idx];
}

// ---------------------------------------------------------------------------
// Generic 64x64-tile GEMM: out[row][c'] = X[row][0:KD] @ W[KD][256] (+bias)(*mass)
// ---------------------------------------------------------------------------
struct G3 {
    const float* W[3];
    const float* bias[3];
    float* out[3];
};

template<int KD, bool PERB, bool MMASS>
__global__ __launch_bounds__(256) void k_gemm64(
    const float* __restrict__ X, G3 g, const float* __restrict__ massf)
{
    const int mt = blockIdx.x, ct = blockIdx.y, z = blockIdx.z;
    const int row0 = mt * 64, c0 = ct * 64;
    const int b = row0 >> 10;
    const float* Wp = g.W[z];
    const float* bias = g.bias[z];
    float* out = g.out[z];
    const size_t woff = PERB ? (size_t)b * KD * 256 : 0;

    __shared__ float xT[32][68];   // 68*4 = 272 B rows (16B-aligned)
    __shared__ float wl[32][64];
    const int t = threadIdx.x, tx = t & 15, ty = t >> 4;
    float acc[4][4] = {};

    for (int k0 = 0; k0 < KD; k0 += 32) {
        {
            const int m = t >> 2, cc0 = (t & 3) * 8;
            const float* xs = X + (size_t)(row0 + m) * KD + k0 + cc0;
            float4 a0 = *(const float4*)xs, a1 = *(const float4*)(xs + 4);
            xT[cc0 + 0][m] = a0.x; xT[cc0 + 1][m] = a0.y; xT[cc0 + 2][m] = a0.z; xT[cc0 + 3][m] = a0.w;
            xT[cc0 + 4][m] = a1.x; xT[cc0 + 5][m] = a1.y; xT[cc0 + 6][m] = a1.z; xT[cc0 + 7][m] = a1.w;
        }
        {
            const int cc = t >> 3, col = (t & 7) * 8;
            const float* wsrc = Wp + woff + (size_t)(k0 + cc) * 256 + c0 + col;
            float4 a0 = *(const float4*)wsrc, a1 = *(const float4*)(wsrc + 4);
            wl[cc][col + 0] = a0.x; wl[cc][col + 1] = a0.y; wl[cc][col + 2] = a0.z; wl[cc][col + 3] = a0.w;
            wl[cc][col + 4] = a1.x; wl[cc][col + 5] = a1.y; wl[cc][col + 6] = a1.z; wl[cc][col + 7] = a1.w;
        }
        __syncthreads();
#pragma unroll 8
        for (int cc = 0; cc < 32; cc++) {
            float4 xv = *(const float4*)&xT[cc][ty * 4];
            float4 wv = *(const float4*)&wl[cc][tx * 4];
            float xa[4] = {xv.x, xv.y, xv.z, xv.w};
            float wa[4] = {wv.x, wv.y, wv.z, wv.w};
#pragma unroll
            for (int i = 0; i < 4; i++)
#pragma unroll
                for (int j = 0; j < 4; j++) acc[i][j] += xa[i] * wa[j];
        }
        __syncthreads();
    }
    float bj[4] = {0.f, 0.f, 0.f, 0.f};
    if (bias) {
#pragma unroll
        for (int j = 0; j < 4; j++) bj[j] = bias[c0 + tx * 4 + j];
    }
#pragma unroll
    for (int i = 0; i < 4; i++) {
        const int row = row0 + ty * 4 + i;
        const float mm = MMASS ? massf[row] : 1.f;
        *(float4*)(out + (size_t)row * 256 + c0 + tx * 4) =
            make_float4((acc[i][0] + bj[0]) * mm, (acc[i][1] + bj[1]) * mm,
                        (acc[i][2] + bj[2]) * mm, (acc[i][3] + bj[3]) * mm);
    }
}

// ---------------------------------------------------------------------------
// GroupNorm stats: per (b, g) mean/invstd over M x 8 channels
// ---------------------------------------------------------------------------
__global__ __launch_bounds__(256) void k_gnstats(const float* __restrict__ xfar, float* __restrict__ gst)
{
    const int b = blockIdx.x >> 5, g = blockIdx.x & 31;
    const int t = threadIdx.x;
    float s = 0.f, s2 = 0.f;
#pragma unroll
    for (int i = 0; i < 4; i++) {
        const int m = t * 4 + i;
        const float* p = xfar + ((size_t)b * Mn + m) * Cn + g * 8;
        float4 a = *(const float4*)p;
        float4 c = *(const float4*)(p + 4);
        s += a.x + a.y + a.z + a.w + c.x + c.y + c.z + c.w;
        s2 += a.x * a.x + a.y * a.y + a.z * a.z + a.w * a.w +
              c.x * c.x + c.y * c.y + c.z * c.z + c.w * c.w;
    }
    __shared__ float sb[256], sb2[256];
    sb[t] = s; sb2[t] = s2;
    __syncthreads();
    for (int o = 128; o > 0; o >>= 1) {
        if (t < o) { sb[t] += sb[t + o]; sb2[t] += sb2[t + o]; }
        __syncthreads();
    }
    if (t == 0) {
        const float mean = sb[0] * (1.f / 8192.f);
        const float var = sb2[0] * (1.f / 8192.f) - mean * mean;
        gst[2 * blockIdx.x] = mean;
        gst[2 * blockIdx.x + 1] = rsqrtf(var + 1e-6f);
    }
}

__global__ __launch_bounds__(256) void k_gnapply(
    const float* __restrict__ xfar, const float* __restrict__ gst,
    const float* __restrict__ gw, const float* __restrict__ gb, float* __restrict__ xn)
{
    const int idx = (blockIdx.x * 256 + threadIdx.x) * 4;
    const int c = idx & 255;
    const int row = idx >> 8;
    const int b = row >> 10;
    const int g = c >> 3;
    const float2 st = *(const float2*)&gst[2 * (b * 32 + g)];
    float4 vv = *(const float4*)&xfar[idx];
    float4 w4 = *(const float4*)&gw[c];
    float4 b4 = *(const float4*)&gb[c];
    float4 o;
    o.x = (vv.x - st.x) * st.y * w4.x + b4.x;
    o.y = (vv.y - st.x) * st.y * w4.y + b4.y;
    o.z = (vv.z - st.x) * st.y * w4.z + b4.z;
    o.w = (vv.w - st.x) * st.y * w4.w + b4.w;
    *(float4*)&xn[idx] = o;
}

// ---------------------------------------------------------------------------
// Flash attention, outer-product tiles (64 q x 128 keys per block).
// ---------------------------------------------------------------------------
__global__ __launch_bounds__(256) void k_attn(
    const float* __restrict__ q, const float* __restrict__ kbuf, const float* __restrict__ vbuf,
    float* __restrict__ pacc, float* __restrict__ pm, float* __restrict__ pl)
{
    const int qt = blockIdx.x;      // 16 tiles of 64 q-rows
    const int seg = blockIdx.y;     // SEG segs of 128 keys
    const int bh = blockIdx.z;
    const int b = bh >> 3, h = bh & 7;
    const int t = threadIdx.x;
    const int tx = t & 15, ty = t >> 4;

    __shared__ float qT[32][68];    // [d][q-row]
    __shared__ float kT[32][68];    // [d][key]
    __shared__ float vsm[64][36];   // [key][d]
    __shared__ float psT[64][72];   // [key][q-row]
    __shared__ float red[64][16];   // per-q-row cross-thread partials

    const int q0 = qt * 64;
    {
        const int row = t >> 2, d0 = (t & 3) * 8;
        const float* qp = q + ((size_t)b * Mn + q0 + row) * Cn + h * Dn + d0;
        float4 a0 = *(const float4*)qp, a1 = *(const float4*)(qp + 4);
        qT[d0 + 0][row] = a0.x; qT[d0 + 1][row] = a0.y; qT[d0 + 2][row] = a0.z; qT[d0 + 3][row] = a0.w;
        qT[d0 + 4][row] = a1.x; qT[d0 + 5][row] = a1.y; qT[d0 + 6][row] = a1.z; qT[d0 + 7][row] = a1.w;
    }

    const float scale = 0.17677669529663687f;  // 1/sqrt(32)
    float m_i[4], l_i[4], acc[4][2];
#pragma unroll
    for (int i = 0; i < 4; i++) { m_i[i] = -1e30f; l_i[i] = 0.f; acc[i][0] = 0.f; acc[i][1] = 0.f; }

    for (int kt = 0; kt < 2; kt++) {
        __syncthreads();  // qT visible (kt=0); psT/kT/vsm reads done (kt=1)
        {
            const int row = t >> 2, d0 = (t & 3) * 8;
            const int k0 = seg * 128 + kt * 64;
            const float* kp = kbuf + ((size_t)b * Mn + k0 + row) * Cn + h * Dn + d0;
            float4 a0 = *(const float4*)kp, a1 = *(const float4*)(kp + 4);
            kT[d0 + 0][row] = a0.x; kT[d0 + 1][row] = a0.y; kT[d0 + 2][row] = a0.z; kT[d0 + 3][row] = a0.w;
            kT[d0 + 4][row] = a1.x; kT[d0 + 5][row] = a1.y; kT[d0 + 6][row] = a1.z; kT[d0 + 7][row] = a1.w;
            const float* vp = vbuf + ((size_t)b * Mn + k0 + row) * Cn + h * Dn + d0;
            *(float4*)&vsm[row][d0] = *(const float4*)vp;
            *(float4*)&vsm[row][d0 + 4] = *(const float4*)(vp + 4);
        }
        __syncthreads();

        float s[4][4] = {};
#pragma unroll 8
        for (int d = 0; d < 32; d++) {
            float4 qv = *(const float4*)&qT[d][ty * 4];
            float4 kv = *(const float4*)&kT[d][tx * 4];
            float qa[4] = {qv.x, qv.y, qv.z, qv.w};
            float ka[4] = {kv.x, kv.y, kv.z, kv.w};
#pragma unroll
            for (int i = 0; i < 4; i++)
#pragma unroll
                for (int j = 0; j < 4; j++) s[i][j] += qa[i] * ka[j];
        }
        float tmax[4];
#pragma unroll
        for (int i = 0; i < 4; i++) {
            s[i][0] *= scale; s[i][1] *= scale; s[i][2] *= scale; s[i][3] *= scale;
            tmax[i] = fmaxf(fmaxf(s[i][0], s[i][1]), fmaxf(s[i][2], s[i][3]));
        }
#pragma unroll
        for (int i = 0; i < 4; i++) red[ty * 4 + i][tx] = tmax[i];
        __syncthreads();
        float nm[4];
#pragma unroll
        for (int i = 0; i < 4; i++) {
            const int row = ty * 4 + i;
            float mx = m_i[i];
#pragma unroll
            for (int xj = 0; xj < 16; xj++) mx = fmaxf(mx, red[row][xj]);
            nm[i] = mx;
        }
        __syncthreads();  // red reads done before sum-phase writes
        float tsum[4];
#pragma unroll
        for (int i = 0; i < 4; i++) {
            float p0 = __expf(s[i][0] - nm[i]);
            float p1 = __expf(s[i][1] - nm[i]);
            float p2 = __expf(s[i][2] - nm[i]);
            float p3 = __expf(s[i][3] - nm[i]);
            s[i][0] = p0; s[i][1] = p1; s[i][2] = p2; s[i][3] = p3;
            tsum[i] = p0 + p1 + p2 + p3;
        }
#pragma unroll
        for (int kk = 0; kk < 4; kk++)
            *(float4*)&psT[tx * 4 + kk][ty * 4] = make_float4(s[0][kk], s[1][kk], s[2][kk], s[3][kk]);
#pragma unroll
        for (int i = 0; i < 4; i++) red[ty * 4 + i][tx] = tsum[i];
        __syncthreads();
#pragma unroll
        for (int i = 0; i < 4; i++) {
            const int row = ty * 4 + i;
            float rs = 0.f;
#pragma unroll
            for (int xj = 0; xj < 16; xj++) rs += red[row][xj];
            const float r = __expf(m_i[i] - nm[i]);
            l_i[i] = l_i[i] * r + rs;
            m_i[i] = nm[i];
            acc[i][0] *= r; acc[i][1] *= r;
        }
#pragma unroll 8
        for (int k = 0; k < 64; k++) {
            float4 pv = *(const float4*)&psT[k][ty * 4];
            float2 vv = *(const float2*)&vsm[k][tx * 2];
            acc[0][0] += pv.x * vv.x; acc[0][1] += pv.x * vv.y;
            acc[1][0] += pv.y * vv.x; acc[1][1] += pv.y * vv.y;
            acc[2][0] += pv.z * vv.x; acc[2][1] += pv.z * vv.y;
            acc[3][0] += pv.w * vv.x; acc[3][1] += pv.w * vv.y;
        }
    }
#pragma unroll
    for (int i = 0; i < 4; i++) {
        const int m = q0 + ty * 4 + i;
        const size_t pr = (((size_t)seg * Bn + b) * Hn + h) * Mn + m;
        if (tx == 0) { pm[pr] = m_i[i]; pl[pr] = l_i[i]; }
        *(float2*)(pacc + pr * 32 + tx * 2) = make_float2(acc[i][0], acc[i][1]);
    }
}

__global__ __launch_bounds__(256) void k_comb(
    const float* __restrict__ pacc, const float* __restrict__ pm, const float* __restrict__ pl,
    float* __restrict__ att)
{
    const int t = threadIdx.x;
    const size_t row = (size_t)blockIdx.x * 8 + (t >> 5);  // (b*8+h)*1024 + m
    const int j = t & 31;
    float M = -1e30f;
#pragma unroll
    for (int s = 0; s < SEG; s++) M = fmaxf(M, pm[(size_t)s * 32768 + row]);
    float L = 0.f, a = 0.f;
#pragma unroll
    for (int s = 0; s < SEG; s++) {
        const float w = __expf(pm[(size_t)s * 32768 + row] - M);
        L += w * pl[(size_t)s * 32768 + row];
        a += w * pacc[((size_t)s * 32768 + row) * 32 + j];
    }
    const int bh = (int)(row >> 10);
    const int mrow = (int)(row & 1023);
    const int b = bh >> 3, h = bh & 7;
    att[((size_t)b * Mn + mrow) * Cn + h * 32 + j] = a / L;
}

// ---------------------------------------------------------------------------
// to_basis #2 over far rows only
// ---------------------------------------------------------------------------
__global__ __launch_bounds__(256) void k_tobasis2(
    const float* __restrict__ evf, const float* __restrict__ xo, float* __restrict__ part)
{
    const int mch = blockIdx.x, ct = blockIdx.y, b = blockIdx.z;
    const int m0 = mch * (Mn / MCH);
    const int c0 = ct * 128;
    __shared__ float ev[32][128];
    __shared__ float xm[32][128];
    const int t = threadIdx.x, tx = t & 15, ty = t >> 4;
    float acc[8][8];
#pragma unroll
    for (int i = 0; i < 8; i++)
#pragma unroll
        for (int j = 0; j < 8; j++) acc[i][j] = 0.f;
    const int lr = t >> 3, lc = (t & 7) * 16;
    for (int s = 0; s < Mn / MCH; s += 32) {
        const size_t mrow = (size_t)b * Mn + m0 + s + lr;
        {
            const float* es = evf + mrow * Kn + lc;
            *(float4*)&ev[lr][lc]      = *(const float4*)es;
            *(float4*)&ev[lr][lc + 4]  = *(const float4*)(es + 4);
            *(float4*)&ev[lr][lc + 8]  = *(const float4*)(es + 8);
            *(float4*)&ev[lr][lc + 12] = *(const float4*)(es + 12);
            const float* xs = xo + mrow * Cn + c0 + lc;
            *(float4*)&xm[lr][lc]      = *(const float4*)xs;
            *(float4*)&xm[lr][lc + 4]  = *(const float4*)(xs + 4);
            *(float4*)&xm[lr][lc + 8]  = *(const float4*)(xs + 8);
            *(float4*)&xm[lr][lc + 12] = *(const float4*)(xs + 12);
        }
        __syncthreads();
#pragma unroll 4
        for (int nn = 0; nn < 32; nn++) {
            float4 e0 = *(const float4*)&ev[nn][ty * 4];
            float4 e1 = *(const float4*)&ev[nn][64 + ty * 4];
            float4 x0 = *(const float4*)&xm[nn][tx * 4];
            float4 x1 = *(const float4*)&xm[nn][64 + tx * 4];
            float ee[8] = {e0.x, e0.y, e0.z, e0.w, e1.x, e1.y, e1.z, e1.w};
            float xx[8] = {x0.x, x0.y, x0.z, x0.w, x1.x, x1.y, x1.z, x1.w};
#pragma unroll
            for (int i = 0; i < 8; i++)
#pragma unroll
                for (int j = 0; j < 8; j++) acc[i][j] += ee[i] * xx[j];
        }
        __syncthreads();
    }
    float* dst = part + ((size_t)b * MCH + mch) * (Kn * Cn);
#pragma unroll
    for (int i = 0; i < 8; i++) {
        const int k = (i < 4) ? (ty * 4 + i) : (64 + ty * 4 + i - 4);
        *(float4*)(dst + (size_t)k * Cn + c0 + tx * 4) =
            make_float4(acc[i][0], acc[i][1], acc[i][2], acc[i][3]);
        *(float4*)(dst + (size_t)k * Cn + c0 + 64 + tx * 4) =
            make_float4(acc[i][4], acc[i][5], acc[i][6], acc[i][7]);
    }
}

// ---------------------------------------------------------------------------
// from_basis #2: out[b,n,c] = out_w[c] * sum_k evecs[b,n,k]*spec2'[b,k,c]
// ---------------------------------------------------------------------------
__global__ __launch_bounds__(256) void k_frombasis2(
    const float* __restrict__ evecs, const float* __restrict__ spec,
    const float* __restrict__ outw, float* __restrict__ out)
{
    const int nt = blockIdx.x, ct = blockIdx.y, b = blockIdx.z;
    const int n0 = nt * 128, c0 = ct * 128;
    __shared__ float evT[32][132];
    __shared__ float sp[32][128];
    const int t = threadIdx.x, tx = t & 15, ty = t >> 4;
    float acc[8][8];
#pragma unroll
    for (int i = 0; i < 8; i++)
#pragma unroll
        for (int j = 0; j < 8; j++) acc[i][j] = 0.f;
    const int en = t >> 1, ek0 = (t & 1) * 16;
    const int sr = t >> 3, sc = (t & 7) * 16;
    for (int k0 = 0; k0 < Kn; k0 += 32) {
        {
            const float* es = evecs + ((size_t)b * Nn + n0 + en) * Kn + k0 + ek0;
            float4 a0 = *(const float4*)es, a1 = *(const float4*)(es + 4);
            float4 a2 = *(const float4*)(es + 8), a3 = *(const float4*)(es + 12);
            evT[ek0 + 0][en] = a0.x; evT[ek0 + 1][en] = a0.y; evT[ek0 + 2][en] = a0.z; evT[ek0 + 3][en] = a0.w;
            evT[ek0 + 4][en] = a1.x; evT[ek0 + 5][en] = a1.y; evT[ek0 + 6][en] = a1.z; evT[ek0 + 7][en] = a1.w;
            evT[ek0 + 8][en] = a2.x; evT[ek0 + 9][en] = a2.y; evT[ek0 + 10][en] = a2.z; evT[ek0 + 11][en] = a2.w;
            evT[ek0 + 12][en] = a3.x; evT[ek0 + 13][en] = a3.y; evT[ek0 + 14][en] = a3.z; evT[ek0 + 15][en] = a3.w;
            const float* ss = spec + ((size_t)b * Kn + k0 + sr) * Cn + c0 + sc;
            *(float4*)&sp[sr][sc]      = *(const float4*)ss;
            *(float4*)&sp[sr][sc + 4]  = *(const float4*)(ss + 4);
            *(float4*)&sp[sr][sc + 8]  = *(const float4*)(ss + 8);
            *(float4*)&sp[sr][sc + 12] = *(const float4*)(ss + 12);
        }
        __syncthreads();
#pragma unroll 4
        for (int kk2 = 0; kk2 < 32; kk2++) {
            float4 e0 = *(const float4*)&evT[kk2][ty * 4];
            float4 e1 = *(const float4*)&evT[kk2][64 + ty * 4];
            float4 s0 = *(const float4*)&sp[kk2][tx * 4];
            float4 s1 = *(const float4*)&sp[kk2][64 + tx * 4];
            float ee[8] = {e0.x, e0.y, e0.z, e0.w, e1.x, e1.y, e1.z, e1.w};
            float sv[8] = {s0.x, s0.y, s0.z, s0.w, s1.x, s1.y, s1.z, s1.w};
#pragma unroll
            for (int i = 0; i < 8; i++)
#pragma unroll
                for (int j = 0; j < 8; j++) acc[i][j] += ee[i] * sv[j];
        }
        __syncthreads();
    }
    float ow[8];
#pragma unroll
    for (int j = 0; j < 8; j++) {
        const int c = c0 + ((j < 4) ? (tx * 4 + j) : (64 + tx * 4 + j - 4));
        ow[j] = fmaxf(outw[c], 1e-8f);
    }
#pragma unroll
    for (int i = 0; i < 8; i++) {
        const int n = n0 + ((i < 4) ? (ty * 4 + i) : (64 + ty * 4 + i - 4));
        float* od = out + ((size_t)b * Nn + n) * Cn + c0;
        *(float4*)(od + tx * 4) =
            make_float4(acc[i][0] * ow[0], acc[i][1] * ow[1], acc[i][2] * ow[2], acc[i][3] * ow[3]);
        *(float4*)(od + 64 + tx * 4) =
            make_float4(acc[i][4] * ow[4], acc[i][5] * ow[5], acc[i][6] * ow[6], acc[i][7] * ow[7]);
    }
}

// ---------------------------------------------------------------------------
extern "C" void kernel_launch(void* const* d_in, const int* in_sizes, int n_in,
                              void* d_out, int out_size, void* d_ws, size_t ws_size,
                              hipStream_t stream)
{
    const float* x     = (const float*)d_in[0];
    const float* mass  = (const float*)d_in[1];
    const float* evals = (const float*)d_in[2];
    const float* evecs = (const float*)d_in[3];
    const int*   far   = (const int*)d_in[4];
    const float* t_in  = (const float*)d_in[5];
    const float* t_out = (const float*)d_in[6];
    const float* gn_w  = (const float*)d_in[7];
    const float* gn_b  = (const float*)d_in[8];
    const float* Wq    = (const float*)d_in[9];
    const float* bq    = (const float*)d_in[10];
    const float* Wk    = (const float*)d_in[11];
    const float* bk    = (const float*)d_in[12];
    const float* Wv    = (const float*)d_in[13];
    const float* bv    = (const float*)d_in[14];
    const float* Wo    = (const float*)d_in[15];
    const float* bo    = (const float*)d_in[16];
    const float* outw  = (const float*)d_in[17];
    float* out = (float*)d_out;
    float* ws = (float*)d_ws;

    // --- Tight lifetime-aliased workspace layout (high-water 14,815,488 floats
    // = 56.5 MiB). Lifetimes:
    //   A: part1(k1-2) -> pacc(k8-9) -> part2(k11-12)
    //   spec1(k2-4) / spec2(k11-12) share; xfar(k4-5) / xo(k9-10) share;
    //   xn(k5-6) / att(k8-9) share; q,kk,v(k6-7) exclusive.
    float* A     = ws;                      // 8,388,608
    float* evf   = ws    + 8388608;         //   524,288 (k3..k10)
    float* massf = evf   + 524288;          //     4,096 (k3..k9)
    float* gst   = massf + 4096;            //       256
    float* pm    = gst   + 256;             //   262,144 (k7..k8)
    float* pl    = pm    + 262144;          //   262,144
    float* spec1 = pl    + 262144;          //   131,072
    float* xfar  = spec1 + 131072;          // 1,048,576
    float* xn    = xfar  + 1048576;         // 1,048,576
    float* q     = xn    + 1048576;         // 1,048,576
    float* kk    = q     + 1048576;         // 1,048,576
    float* v     = kk    + 1048576;         // 1,048,576  (ends at 14,815,488)
    float* pacc  = A;
    float* part2 = A;
    float* spec2 = spec1;   // spec1 dead after from_basis1
    float* xo    = xfar;    // xfar dead after gnapply
    float* att   = xn;      // xn dead after QKV gemm

    k_tobasis1<<<dim3(NCH, 1, Bn), 512, 0, stream>>>(x, mass, evecs, A);
    k_reduce<<<Bn * Kn, Cn, 0, stream>>>(A, NCH, evals, t_in, spec1);
    k_gather<<<Bn * Mn, Kn, 0, stream>>>(evecs, mass, far, evf, massf);
    {
        G3 g{};
        g.W[0] = spec1; g.bias[0] = nullptr; g.out[0] = xfar;
        k_gemm64<128, true, false><<<dim3(64, 4, 1), 256, 0, stream>>>(evf, g, nullptr);
    }
    k_gnstats<<<Bn * 32, 256, 0, stream>>>(xfar, gst);
    k_gnapply<<<1024, 256, 0, stream>>>(xfar, gst, gn_w, gn_b, xn);
    {
        G3 g{};
        g.W[0] = Wq; g.W[1] = Wk; g.W[2] = Wv;
        g.bias[0] = bq; g.bias[1] = bk; g.bias[2] = bv;
        g.out[0] = q; g.out[1] = kk; g.out[2] = v;
        k_gemm64<256, false, false><<<dim3(64, 4, 3), 256, 0, stream>>>(xn, g, nullptr);
    }
    k_attn<<<dim3(16, SEG, 32), 256, 0, stream>>>(q, kk, v, pacc, pm, pl);
    k_comb<<<4096, 256, 0, stream>>>(pacc, pm, pl, att);
    {
        G3 g{};
        g.W[0] = Wo; g.bias[0] = bo; g.out[0] = xo;
        k_gemm64<256, false, true><<<dim3(64, 4, 1), 256, 0, stream>>>(att, g, massf);
    }
    k_tobasis2<<<dim3(MCH, 2, Bn), 256, 0, stream>>>(evf, xo, part2);
    k_reduce<<<Bn * Kn, Cn, 0, stream>>>(part2, MCH, evals, t_out, spec2);
    k_frombasis2<<<dim3(256, 2, Bn), 256, 0, stream>>>(evecs, spec2, outw, out);
}

// Round 3
// 534.905 us; speedup vs baseline: 1.2172x; 1.1230x over previous
//
#include <hip/hip_runtime.h>
#include <hip/hip_bf16.h>

// All inputs and the output are fp32 (established empirically in rounds 1-2).
// Workspace layout is lifetime-aliased (high-water 56.5 MiB; see round-5 note).
//
// ROUND 8: k_attn rewritten as single-pass f16x3 MFMA flash attention.
//   Old: fp32 VALU outer-product flash w/ 8-way key segmentation + k_comb:
//   114 us, MfmaUtil 0, VALUBusy 44%, 1.44e7 LDS bank-conflict cycles (psT
//   stores stride 288B), 71 MB pacc/pm/pl partial traffic.
//   New: grid (16 qt x 32 bh), 4 waves x 16 q-rows, keys in 16 tiles of 64.
//   d=32 = exactly one mfma_f32_16x16x32_f16 K-step. Q/K frags straight from
//   rows (no transpose; layout verified by tb1). K hi/lo planes linear in
//   LDS; V transposed w/ 16B-chunk XOR swizzle (conflict-free both sides);
//   P per-wave [16][68] u32 (hi,lo) tile, v_perm extraction. Register
//   prefetch of next K/V tile across raw s_barriers (vmcnt never drained).
//   k_comb + partial buffers eliminated. Predicted ~12-18 us.
//   tb1 (round 7): ~88 us observed (-28 total); residual deferred.

#define Bn 4
#define Nn 32768
#define Kn 128
#define Cn 256
#define Mn 1024
#define Hn 8
#define Dn 32
#define NCH 64   // n-chunks for to_basis1 (chunk = 512 rows)
#define MCH 16   // m-chunks for to_basis2 (chunk = 64 rows)

typedef _Float16 f16;
typedef _Float16 f16x8 __attribute__((ext_vector_type(8)));
typedef float f32x4 __attribute__((ext_vector_type(4)));
typedef unsigned int u32;
typedef unsigned int u32x4 __attribute__((ext_vector_type(4)));

__device__ __forceinline__ void gload_lds16(const float* g, float* l) {
    __builtin_amdgcn_global_load_lds(
        (const __attribute__((address_space(1))) void*)g,
        (__attribute__((address_space(3))) void*)l, 16, 0, 0);
}

static __device__ __forceinline__ u32 packf16(f16 a, f16 b) {
    union { f16 h[2]; u32 u; } x;
    x.h[0] = a; x.h[1] = b;
    return x.u;
}

// ---------------------------------------------------------------------------
// K1: to_basis #1 (f16x3 MFMA).
// ---------------------------------------------------------------------------
__global__ __launch_bounds__(512) void k_tobasis1(
    const float* __restrict__ x, const float* __restrict__ mass,
    const float* __restrict__ evecs, float* __restrict__ part)
{
    const int nch = blockIdx.x, b = blockIdx.z;
    const int n0 = nch * (Nn / NCH);
    const int t = threadIdx.x;
    const int lane = t & 63, w = t >> 6;
    const int lr = lane & 15, lg = lane >> 4;
    const int wm = (w & 1) * 64;        // k-offset (basis rows)
    const int wc = (w >> 1) * 64;       // c-offset

    __shared__ __align__(16) float evS[2][32][128];   // 32 KB
    __shared__ __align__(16) float xS[2][32][256];    // 64 KB
    __shared__ __align__(16) f16 evT[128][64];        // 16 KB  hi|lo interleaved
    __shared__ __align__(16) f16 xT[256][64];         // 32 KB  hi|lo interleaved
    __shared__ __align__(16) float massS[512];        //  2 KB

    const size_t rb0 = (size_t)b * Nn + n0;
    const float* ebase = evecs + rb0 * Kn;
    const float* xbase = x + rb0 * Cn;

    f32x4 acc[4][4] = {};

    if (w < 2) gload_lds16(mass + rb0 + w * 256 + lane * 4, massS + w * 256);
#pragma unroll
    for (int ss = 0; ss < 2; ss++) {
        const float* eb = ebase + (size_t)ss * 32 * Kn;
        const float* xb = xbase + (size_t)ss * 32 * Cn;
#pragma unroll
        for (int iw = 0; iw < 2; iw++)
            gload_lds16(eb + (w * 2 + iw) * 256 + lane * 4, &evS[ss][0][0] + (w * 2 + iw) * 256);
#pragma unroll
        for (int iw = 0; iw < 4; iw++)
            gload_lds16(xb + (w * 4 + iw) * 256 + lane * 4, &xS[ss][0][0] + (w * 4 + iw) * 256);
    }

    for (int s = 0; s < 16; s++) {
        const int p = s & 1;
        if (s == 15) { asm volatile("s_waitcnt vmcnt(0)" ::: "memory"); }
        else         { asm volatile("s_waitcnt vmcnt(6)" ::: "memory"); }
        __builtin_amdgcn_sched_barrier(0);
        __builtin_amdgcn_s_barrier();

        {
            const int k = t & 127;
            const int g = t >> 7;          // wave-uniform
            f16x8 hv, lv;
#pragma unroll
            for (int r = 0; r < 8; r++) {
                const float f = evS[p][g * 8 + r][k];
                const f16 h = (f16)f;
                hv[r] = h;
                lv[r] = (f16)(f - (float)h);
            }
            *(f16x8*)&evT[k][((g) ^ (k & 7)) * 8] = hv;
            *(f16x8*)&evT[k][((4 + g) ^ (k & 7)) * 8] = lv;
        }
        {
            const int c = t & 255;
            const int g2 = t >> 8;         // wave-uniform
#pragma unroll
            for (int jj = 0; jj < 2; jj++) {
                const int ch = g2 * 2 + jj;
                f16x8 hv, lv;
#pragma unroll
                for (int r = 0; r < 8; r++) {
                    const int n = ch * 8 + r;
                    const float f = xS[p][n][c] * massS[s * 32 + n];
                    const f16 h = (f16)f;
                    hv[r] = h;
                    lv[r] = (f16)(f - (float)h);
                }
                *(f16x8*)&xT[c][((ch) ^ (c & 7)) * 8] = hv;
                *(f16x8*)&xT[c][((4 + ch) ^ (c & 7)) * 8] = lv;
            }
        }

        asm volatile("s_waitcnt lgkmcnt(0)" ::: "memory");
        __builtin_amdgcn_sched_barrier(0);
        __builtin_amdgcn_s_barrier();

        if (s + 2 < 16) {
            const float* eb = ebase + (size_t)(s + 2) * 32 * Kn;
            const float* xb = xbase + (size_t)(s + 2) * 32 * Cn;
#pragma unroll
            for (int iw = 0; iw < 2; iw++)
                gload_lds16(eb + (w * 2 + iw) * 256 + lane * 4, &evS[p][0][0] + (w * 2 + iw) * 256);
#pragma unroll
            for (int iw = 0; iw < 4; iw++)
                gload_lds16(xb + (w * 4 + iw) * 256 + lane * 4, &xS[p][0][0] + (w * 4 + iw) * 256);
        }

        f16x8 aH[4], aL[4], bH[4], bL[4];
#pragma unroll
        for (int i = 0; i < 4; i++) {
            const int rk = wm + i * 16 + lr;
            aH[i] = *(const f16x8*)&evT[rk][((lg) ^ (rk & 7)) * 8];
            aL[i] = *(const f16x8*)&evT[rk][((4 + lg) ^ (rk & 7)) * 8];
            const int rc = wc + i * 16 + lr;
            bH[i] = *(const f16x8*)&xT[rc][((lg) ^ (rc & 7)) * 8];
            bL[i] = *(const f16x8*)&xT[rc][((4 + lg) ^ (rc & 7)) * 8];
        }
#pragma unroll
        for (int i = 0; i < 4; i++)
#pragma unroll
            for (int j = 0; j < 4; j++) {
                acc[i][j] = __builtin_amdgcn_mfma_f32_16x16x32_f16(aH[i], bH[j], acc[i][j], 0, 0, 0);
                acc[i][j] = __builtin_amdgcn_mfma_f32_16x16x32_f16(aH[i], bL[j], acc[i][j], 0, 0, 0);
                acc[i][j] = __builtin_amdgcn_mfma_f32_16x16x32_f16(aL[i], bH[j], acc[i][j], 0, 0, 0);
            }
    }

    float* dst = part + ((size_t)b * NCH + nch) * (Kn * Cn);
#pragma unroll
    for (int i = 0; i < 4; i++)
#pragma unroll
        for (int j = 0; j < 4; j++) {
            const int m0 = wm + i * 16 + lg * 4;
            const int c = wc + j * 16 + lr;
#pragma unroll
            for (int r = 0; r < 4; r++)
                dst[(size_t)(m0 + r) * Cn + c] = acc[i][j][r];
        }
}

// ---------------------------------------------------------------------------
// Reduce chunk partials and apply heat coefficient exp(-eval * t_c)
// ---------------------------------------------------------------------------
__global__ __launch_bounds__(256) void k_reduce(
    const float* __restrict__ part, int nchunks,
    const float* __restrict__ evals, const float* __restrict__ tvec,
    float* __restrict__ spec)
{
    const int b = blockIdx.x >> 7, k = blockIdx.x & 127, c = threadIdx.x;
    float ssum = 0.f;
    const float* p = part + ((size_t)b * nchunks * Kn + k) * Cn + c;
    for (int j = 0; j < nchunks; j++) ssum += p[(size_t)j * Kn * Cn];
    const float lam = evals[b * Kn + k];
    const float tt = fmaxf(tvec[c], 1e-8f);
    spec[((size_t)b * Kn + k) * Cn + c] = ssum * __expf(-lam * tt);
}

// ---------------------------------------------------------------------------
// Gather evecs & mass at far indices
// ---------------------------------------------------------------------------
__global__ __launch_bounds__(128) void k_gather(
    const float* __restrict__ evecs, const float* __restrict__ mass,
    const int* __restrict__ far, float* __restrict__ evf, float* __restrict__ massf)
{
    const int row = blockIdx.x;  // b*M + m
    const int b = row >> 10;
    const int idx = far[row];
    const int t = threadIdx.x;
    evf[(size_t)row * Kn + t] = evecs[((size_t)b * Nn + idx) * Kn + t];
    if (t == 0) massf[row] = mass[(size_t)b * Nn + idx];
}

// ---------------------------------------------------------------------------
// Generic 64x64-tile GEMM: out[row][c'] = X[row][0:KD] @ W[KD][256] (+bias)(*mass)
// ---------------------------------------------------------------------------
struct G3 {
    const float* W[3];
    const float* bias[3];
    float* out[3];
};

template<int KD, bool PERB, bool MMASS>
__global__ __launch_bounds__(256) void k_gemm64(
    const float* __restrict__ X, G3 g, const float* __restrict__ massf)
{
    const int mt = blockIdx.x, ct = blockIdx.y, z = blockIdx.z;
    const int row0 = mt * 64, c0 = ct * 64;
    const int b = row0 >> 10;
    const float* Wp = g.W[z];
    const float* bias = g.bias[z];
    float* out = g.out[z];
    const size_t woff = PERB ? (size_t)b * KD * 256 : 0;

    __shared__ float xT[32][68];   // 68*4 = 272 B rows (16B-aligned)
    __shared__ float wl[32][64];
    const int t = threadIdx.x, tx = t & 15, ty = t >> 4;
    float acc[4][4] = {};

    for (int k0 = 0; k0 < KD; k0 += 32) {
        {
            const int m = t >> 2, cc0 = (t & 3) * 8;
            const float* xs = X + (size_t)(row0 + m) * KD + k0 + cc0;
            float4 a0 = *(const float4*)xs, a1 = *(const float4*)(xs + 4);
            xT[cc0 + 0][m] = a0.x; xT[cc0 + 1][m] = a0.y; xT[cc0 + 2][m] = a0.z; xT[cc0 + 3][m] = a0.w;
            xT[cc0 + 4][m] = a1.x; xT[cc0 + 5][m] = a1.y; xT[cc0 + 6][m] = a1.z; xT[cc0 + 7][m] = a1.w;
        }
        {
            const int cc = t >> 3, col = (t & 7) * 8;
            const float* wsrc = Wp + woff + (size_t)(k0 + cc) * 256 + c0 + col;
            float4 a0 = *(const float4*)wsrc, a1 = *(const float4*)(wsrc + 4);
            wl[cc][col + 0] = a0.x; wl[cc][col + 1] = a0.y; wl[cc][col + 2] = a0.z; wl[cc][col + 3] = a0.w;
            wl[cc][col + 4] = a1.x; wl[cc][col + 5] = a1.y; wl[cc][col + 6] = a1.z; wl[cc][col + 7] = a1.w;
        }
        __syncthreads();
#pragma unroll 8
        for (int cc = 0; cc < 32; cc++) {
            float4 xv = *(const float4*)&xT[cc][ty * 4];
            float4 wv = *(const float4*)&wl[cc][tx * 4];
            float xa[4] = {xv.x, xv.y, xv.z, xv.w};
            float wa[4] = {wv.x, wv.y, wv.z, wv.w};
#pragma unroll
            for (int i = 0; i < 4; i++)
#pragma unroll
                for (int j = 0; j < 4; j++) acc[i][j] += xa[i] * wa[j];
        }
        __syncthreads();
    }
    float bj[4] = {0.f, 0.f, 0.f, 0.f};
    if (bias) {
#pragma unroll
        for (int j = 0; j < 4; j++) bj[j] = bias[c0 + tx * 4 + j];
    }
#pragma unroll
    for (int i = 0; i < 4; i++) {
        const int row = row0 + ty * 4 + i;
        const float mm = MMASS ? massf[row] : 1.f;
        *(float4*)(out + (size_t)row * 256 + c0 + tx * 4) =
            make_float4((acc[i][0] + bj[0]) * mm, (acc[i][1] + bj[1]) * mm,
                        (acc[i][2] + bj[2]) * mm, (acc[i][3] + bj[3]) * mm);
    }
}

// ---------------------------------------------------------------------------
// GroupNorm stats: per (b, g) mean/invstd over M x 8 channels
// ---------------------------------------------------------------------------
__global__ __launch_bounds__(256) void k_gnstats(const float* __restrict__ xfar, float* __restrict__ gst)
{
    const int b = blockIdx.x >> 5, g = blockIdx.x & 31;
    const int t = threadIdx.x;
    float s = 0.f, s2 = 0.f;
#pragma unroll
    for (int i = 0; i < 4; i++) {
        const int m = t * 4 + i;
        const float* p = xfar + ((size_t)b * Mn + m) * Cn + g * 8;
        float4 a = *(const float4*)p;
        float4 c = *(const float4*)(p + 4);
        s += a.x + a.y + a.z + a.w + c.x + c.y + c.z + c.w;
        s2 += a.x * a.x + a.y * a.y + a.z * a.z + a.w * a.w +
              c.x * c.x + c.y * c.y + c.z * c.z + c.w * c.w;
    }
    __shared__ float sb[256], sb2[256];
    sb[t] = s; sb2[t] = s2;
    __syncthreads();
    for (int o = 128; o > 0; o >>= 1) {
        if (t < o) { sb[t] += sb[t + o]; sb2[t] += sb2[t + o]; }
        __syncthreads();
    }
    if (t == 0) {
        const float mean = sb[0] * (1.f / 8192.f);
        const float var = sb2[0] * (1.f / 8192.f) - mean * mean;
        gst[2 * blockIdx.x] = mean;
        gst[2 * blockIdx.x + 1] = rsqrtf(var + 1e-6f);
    }
}

__global__ __launch_bounds__(256) void k_gnapply(
    const float* __restrict__ xfar, const float* __restrict__ gst,
    const float* __restrict__ gw, const float* __restrict__ gb, float* __restrict__ xn)
{
    const int idx = (blockIdx.x * 256 + threadIdx.x) * 4;
    const int c = idx & 255;
    const int row = idx >> 8;
    const int b = row >> 10;
    const int g = c >> 3;
    const float2 st = *(const float2*)&gst[2 * (b * 32 + g)];
    float4 vv = *(const float4*)&xfar[idx];
    float4 w4 = *(const float4*)&gw[c];
    float4 b4 = *(const float4*)&gb[c];
    float4 o;
    o.x = (vv.x - st.x) * st.y * w4.x + b4.x;
    o.y = (vv.y - st.x) * st.y * w4.y + b4.y;
    o.z = (vv.z - st.x) * st.y * w4.z + b4.z;
    o.w = (vv.w - st.x) * st.y * w4.w + b4.w;
    *(float4*)&xn[idx] = o;
}

// ---------------------------------------------------------------------------
// Flash attention, f16x3 MFMA, single pass over all 1024 keys.
// Grid (16 q-tiles, 32 bh); 256 threads = 4 waves; wave w owns q-rows
// q0 + w*16 .. +15. Keys in 16 tiles of 64. d=32 = one mfma K-step.
// ---------------------------------------------------------------------------
__global__ __launch_bounds__(256) void k_attn(
    const float* __restrict__ q, const float* __restrict__ kbuf, const float* __restrict__ vbuf,
    float* __restrict__ att)
{
    const int qt = blockIdx.x;      // 16 tiles of 64 q-rows
    const int bh = blockIdx.y;      // b*8 + h
    const int b = bh >> 3, h = bh & 7;
    const int t = threadIdx.x;
    const int lane = t & 63, w = t >> 6;
    const int lr = lane & 15, lg = lane >> 4;

    __shared__ __align__(16) f16 Kh[64][32];     // [key][d] hi
    __shared__ __align__(16) f16 Kl[64][32];     // [key][d] lo
    __shared__ __align__(16) f16 Vh[32][64];     // [d][key] hi, 16B-chunk ^(d&7)
    __shared__ __align__(16) f16 Vl[32][64];     // [d][key] lo
    __shared__ __align__(16) u32 Pw[4][16][68];  // per-wave P (hi,lo) packed

    const size_t base = (size_t)b * Mn * Cn + h * Dn;
    const int q0 = qt * 64;

    // Q fragment (pre-scaled by 1/sqrt(32)), rows q0+w*16+lr, d = lg*8..+7
    f16x8 Qh, Ql;
    {
        const float* qp = q + base + (size_t)(q0 + w * 16 + lr) * Cn + lg * 8;
        f32x4 a0 = *(const f32x4*)qp;
        f32x4 a1 = *(const f32x4*)(qp + 4);
        const float scale = 0.17677669529663687f;
        float qv[8] = {a0[0], a0[1], a0[2], a0[3], a1[0], a1[1], a1[2], a1[3]};
#pragma unroll
        for (int r = 0; r < 8; r++) {
            const float f = qv[r] * scale;
            const f16 hh = (f16)f;
            Qh[r] = hh;
            Ql[r] = (f16)(f - (float)hh);
        }
    }

    // staging assignments
    const int krow = t >> 2, kdg = (t & 3) * 8;        // K: row, d-offset
    const int vrow = (t & 31) * 2, vdc = (t >> 5) * 4; // V: row-pair base, d-offset

    // prefetch tile 0
    f32x4 kr0, kr1, va, vb;
    {
        const float* kp = kbuf + base + (size_t)krow * Cn + kdg;
        kr0 = *(const f32x4*)kp; kr1 = *(const f32x4*)(kp + 4);
        const float* vp = vbuf + base + (size_t)vrow * Cn + vdc;
        va = *(const f32x4*)vp; vb = *(const f32x4*)(vp + Cn);
    }

    float m_i[4], l_i[4];
    f32x4 acc[2] = {};
#pragma unroll
    for (int r = 0; r < 4; r++) { m_i[r] = -1e30f; l_i[r] = 0.f; }

#pragma unroll 1
    for (int kt = 0; kt < 16; kt++) {
        asm volatile("" ::: "memory");
        __builtin_amdgcn_s_barrier();   // all waves done reading K/V of tile kt-1

        // convert + write K (kr* arrive via compiler vmcnt wait)
        {
            float kv[8] = {kr0[0], kr0[1], kr0[2], kr0[3], kr1[0], kr1[1], kr1[2], kr1[3]};
            f16x8 hv, lv;
#pragma unroll
            for (int r = 0; r < 8; r++) {
                const f16 hh = (f16)kv[r];
                hv[r] = hh;
                lv[r] = (f16)(kv[r] - (float)hh);
            }
            *(f16x8*)&Kh[krow][kdg] = hv;
            *(f16x8*)&Kl[krow][kdg] = lv;
        }
        // convert + write V transposed (chunk ^ (d&7) swizzle)
        {
            float v0[4] = {va[0], va[1], va[2], va[3]};
            float v1[4] = {vb[0], vb[1], vb[2], vb[3]};
#pragma unroll
            for (int j = 0; j < 4; j++) {
                const int d = vdc + j;
                const f16 h0 = (f16)v0[j], h1 = (f16)v1[j];
                const f16 l0 = (f16)(v0[j] - (float)h0), l1 = (f16)(v1[j] - (float)h1);
                const int col = vrow >> 1;                       // u32 col 0..31
                const int idx = (((col >> 2) ^ (d & 7)) << 2) | (col & 3);
                ((u32*)&Vh[d][0])[idx] = packf16(h0, h1);
                ((u32*)&Vl[d][0])[idx] = packf16(l0, l1);
            }
        }
        // prefetch tile kt+1
        if (kt < 15) {
            const float* kp = kbuf + base + (size_t)((kt + 1) * 64 + krow) * Cn + kdg;
            kr0 = *(const f32x4*)kp; kr1 = *(const f32x4*)(kp + 4);
            const float* vp = vbuf + base + (size_t)((kt + 1) * 64 + vrow) * Cn + vdc;
            va = *(const f32x4*)vp; vb = *(const f32x4*)(vp + Cn);
        }

        asm volatile("s_waitcnt lgkmcnt(0)" ::: "memory");
        __builtin_amdgcn_sched_barrier(0);
        __builtin_amdgcn_s_barrier();   // K/V tile visible

        // ---- S = Qs . K^T  (16q x 64k per wave) ----
        f32x4 s[4];
#pragma unroll
        for (int ct = 0; ct < 4; ct++) {
            const f16x8 khi = *(const f16x8*)&Kh[ct * 16 + lr][lg * 8];
            const f16x8 klo = *(const f16x8*)&Kl[ct * 16 + lr][lg * 8];
            f32x4 z = {};
            z = __builtin_amdgcn_mfma_f32_16x16x32_f16(Qh, khi, z, 0, 0, 0);
            z = __builtin_amdgcn_mfma_f32_16x16x32_f16(Qh, klo, z, 0, 0, 0);
            z = __builtin_amdgcn_mfma_f32_16x16x32_f16(Ql, khi, z, 0, 0, 0);
            s[ct] = z;
        }

        // ---- online softmax (rows = lg*4+r, reduce across 16 lanes lr) ----
        float tm[4];
#pragma unroll
        for (int r = 0; r < 4; r++)
            tm[r] = fmaxf(fmaxf(s[0][r], s[1][r]), fmaxf(s[2][r], s[3][r]));
#pragma unroll
        for (int r = 0; r < 4; r++) {
            tm[r] = fmaxf(tm[r], __shfl_xor(tm[r], 1));
            tm[r] = fmaxf(tm[r], __shfl_xor(tm[r], 2));
            tm[r] = fmaxf(tm[r], __shfl_xor(tm[r], 4));
            tm[r] = fmaxf(tm[r], __shfl_xor(tm[r], 8));
        }
        float corr[4], rs[4];
#pragma unroll
        for (int r = 0; r < 4; r++) {
            const float nm = fmaxf(m_i[r], tm[r]);
            corr[r] = __expf(m_i[r] - nm);
            m_i[r] = nm;
            rs[r] = 0.f;
        }
        // P = exp(s - m), pack hi/lo, store to per-wave LDS tile
#pragma unroll
        for (int ct = 0; ct < 4; ct++)
#pragma unroll
            for (int r = 0; r < 4; r++) {
                const float p = __expf(s[ct][r] - m_i[r]);
                rs[r] += p;
                const f16 ph = (f16)p;
                const f16 pl = (f16)(p - (float)ph);
                Pw[w][lg * 4 + r][ct * 16 + lr] = packf16(ph, pl);
            }
#pragma unroll
        for (int r = 0; r < 4; r++) {
            rs[r] += __shfl_xor(rs[r], 1);
            rs[r] += __shfl_xor(rs[r], 2);
            rs[r] += __shfl_xor(rs[r], 4);
            rs[r] += __shfl_xor(rs[r], 8);
            l_i[r] = l_i[r] * corr[r] + rs[r];
        }
#pragma unroll
        for (int dt = 0; dt < 2; dt++)
#pragma unroll
            for (int r = 0; r < 4; r++) acc[dt][r] *= corr[r];

        asm volatile("s_waitcnt lgkmcnt(0)" ::: "memory");
        __builtin_amdgcn_sched_barrier(0);

        // ---- P fragments (A-layout: row=lr, keys=kc*32+lg*8+j) ----
        f16x8 pah[2], pal[2];
#pragma unroll
        for (int kc = 0; kc < 2; kc++) {
            const u32* prow = &Pw[w][lr][0] + kc * 32 + lg * 8;
            u32x4 ua = *(const u32x4*)prow;
            u32x4 ub = *(const u32x4*)(prow + 4);
            union { u32 wd[4]; f16x8 v; } hh, ll;
            hh.wd[0] = __builtin_amdgcn_perm(ua[1], ua[0], 0x05040100u);
            hh.wd[1] = __builtin_amdgcn_perm(ua[3], ua[2], 0x05040100u);
            hh.wd[2] = __builtin_amdgcn_perm(ub[1], ub[0], 0x05040100u);
            hh.wd[3] = __builtin_amdgcn_perm(ub[3], ub[2], 0x05040100u);
            ll.wd[0] = __builtin_amdgcn_perm(ua[1], ua[0], 0x07060302u);
            ll.wd[1] = __builtin_amdgcn_perm(ua[3], ua[2], 0x07060302u);
            ll.wd[2] = __builtin_amdgcn_perm(ub[1], ub[0], 0x07060302u);
            ll.wd[3] = __builtin_amdgcn_perm(ub[3], ub[2], 0x07060302u);
            pah[kc] = hh.v;
            pal[kc] = ll.v;
        }

        // ---- O += P . V ----
#pragma unroll
        for (int dt = 0; dt < 2; dt++)
#pragma unroll
            for (int kc = 0; kc < 2; kc++) {
                const int d = dt * 16 + lr;
                const int ch = ((kc * 4 + lg) ^ (lr & 7)) * 8;
                const f16x8 vh = *(const f16x8*)&Vh[d][ch];
                const f16x8 vl = *(const f16x8*)&Vl[d][ch];
                acc[dt] = __builtin_amdgcn_mfma_f32_16x16x32_f16(pah[kc], vh, acc[dt], 0, 0, 0);
                acc[dt] = __builtin_amdgcn_mfma_f32_16x16x32_f16(pah[kc], vl, acc[dt], 0, 0, 0);
                acc[dt] = __builtin_amdgcn_mfma_f32_16x16x32_f16(pal[kc], vh, acc[dt], 0, 0, 0);
            }
    }

    // epilogue: C/D rows = lg*4+r, cols = dt*16+lr
#pragma unroll
    for (int r = 0; r < 4; r++) {
        const float inv = 1.f / l_i[r];
        const size_t orow = (size_t)b * Mn + q0 + w * 16 + lg * 4 + r;
#pragma unroll
        for (int dt = 0; dt < 2; dt++)
            att[orow * Cn + h * Dn + dt * 16 + lr] = acc[dt][r] * inv;
    }
}

// ---------------------------------------------------------------------------
// to_basis #2 over far rows only
// ---------------------------------------------------------------------------
__global__ __launch_bounds__(256) void k_tobasis2(
    const float* __restrict__ evf, const float* __restrict__ xo, float* __restrict__ part)
{
    const int mch = blockIdx.x, ct = blockIdx.y, b = blockIdx.z;
    const int m0 = mch * (Mn / MCH);
    const int c0 = ct * 128;
    __shared__ float ev[32][128];
    __shared__ float xm[32][128];
    const int t = threadIdx.x, tx = t & 15, ty = t >> 4;
    float acc[8][8];
#pragma unroll
    for (int i = 0; i < 8; i++)
#pragma unroll
        for (int j = 0; j < 8; j++) acc[i][j] = 0.f;
    const int lr = t >> 3, lc = (t & 7) * 16;
    for (int s = 0; s < Mn / MCH; s += 32) {
        const size_t mrow = (size_t)b * Mn + m0 + s + lr;
        {
            const float* es = evf + mrow * Kn + lc;
            *(float4*)&ev[lr][lc]      = *(const float4*)es;
            *(float4*)&ev[lr][lc + 4]  = *(const float4*)(es + 4);
            *(float4*)&ev[lr][lc + 8]  = *(const float4*)(es + 8);
            *(float4*)&ev[lr][lc + 12] = *(const float4*)(es + 12);
            const float* xs = xo + mrow * Cn + c0 + lc;
            *(float4*)&xm[lr][lc]      = *(const float4*)xs;
            *(float4*)&xm[lr][lc + 4]  = *(const float4*)(xs + 4);
            *(float4*)&xm[lr][lc + 8]  = *(const float4*)(xs + 8);
            *(float4*)&xm[lr][lc + 12] = *(const float4*)(xs + 12);
        }
        __syncthreads();
#pragma unroll 4
        for (int nn = 0; nn < 32; nn++) {
            float4 e0 = *(const float4*)&ev[nn][ty * 4];
            float4 e1 = *(const float4*)&ev[nn][64 + ty * 4];
            float4 x0 = *(const float4*)&xm[nn][tx * 4];
            float4 x1 = *(const float4*)&xm[nn][64 + tx * 4];
            float ee[8] = {e0.x, e0.y, e0.z, e0.w, e1.x, e1.y, e1.z, e1.w};
            float xx[8] = {x0.x, x0.y, x0.z, x0.w, x1.x, x1.y, x1.z, x1.w};
#pragma unroll
            for (int i = 0; i < 8; i++)
#pragma unroll
                for (int j = 0; j < 8; j++) acc[i][j] += ee[i] * xx[j];
        }
        __syncthreads();
    }
    float* dst = part + ((size_t)b * MCH + mch) * (Kn * Cn);
#pragma unroll
    for (int i = 0; i < 8; i++) {
        const int k = (i < 4) ? (ty * 4 + i) : (64 + ty * 4 + i - 4);
        *(float4*)(dst + (size_t)k * Cn + c0 + tx * 4) =
            make_float4(acc[i][0], acc[i][1], acc[i][2], acc[i][3]);
        *(float4*)(dst + (size_t)k * Cn + c0 + 64 + tx * 4) =
            make_float4(acc[i][4], acc[i][5], acc[i][6], acc[i][7]);
    }
}

// ---------------------------------------------------------------------------
// from_basis #2: out[b,n,c] = out_w[c] * sum_k evecs[b,n,k]*spec2'[b,k,c]
// ---------------------------------------------------------------------------
__global__ __launch_bounds__(256) void k_frombasis2(
    const float* __restrict__ evecs, const float* __restrict__ spec,
    const float* __restrict__ outw, float* __restrict__ out)
{
    const int nt = blockIdx.x, ct = blockIdx.y, b = blockIdx.z;
    const int n0 = nt * 128, c0 = ct * 128;
    __shared__ float evT[32][132];
    __shared__ float sp[32][128];
    const int t = threadIdx.x, tx = t & 15, ty = t >> 4;
    float acc[8][8];
#pragma unroll
    for (int i = 0; i < 8; i++)
#pragma unroll
        for (int j = 0; j < 8; j++) acc[i][j] = 0.f;
    const int en = t >> 1, ek0 = (t & 1) * 16;
    const int sr = t >> 3, sc = (t & 7) * 16;
    for (int k0 = 0; k0 < Kn; k0 += 32) {
        {
            const float* es = evecs + ((size_t)b * Nn + n0 + en) * Kn + k0 + ek0;
            float4 a0 = *(const float4*)es, a1 = *(const float4*)(es + 4);
            float4 a2 = *(const float4*)(es + 8), a3 = *(const float4*)(es + 12);
            evT[ek0 + 0][en] = a0.x; evT[ek0 + 1][en] = a0.y; evT[ek0 + 2][en] = a0.z; evT[ek0 + 3][en] = a0.w;
            evT[ek0 + 4][en] = a1.x; evT[ek0 + 5][en] = a1.y; evT[ek0 + 6][en] = a1.z; evT[ek0 + 7][en] = a1.w;
            evT[ek0 + 8][en] = a2.x; evT[ek0 + 9][en] = a2.y; evT[ek0 + 10][en] = a2.z; evT[ek0 + 11][en] = a2.w;
            evT[ek0 + 12][en] = a3.x; evT[ek0 + 13][en] = a3.y; evT[ek0 + 14][en] = a3.z; evT[ek0 + 15][en] = a3.w;
            const float* ss = spec + ((size_t)b * Kn + k0 + sr) * Cn + c0 + sc;
            *(float4*)&sp[sr][sc]      = *(const float4*)ss;
            *(float4*)&sp[sr][sc + 4]  = *(const float4*)(ss + 4);
            *(float4*)&sp[sr][sc + 8]  = *(const float4*)(ss + 8);
            *(float4*)&sp[sr][sc + 12] = *(const float4*)(ss + 12);
        }
        __syncthreads();
#pragma unroll 4
        for (int kk2 = 0; kk2 < 32; kk2++) {
            float4 e0 = *(const float4*)&evT[kk2][ty * 4];
            float4 e1 = *(const float4*)&evT[kk2][64 + ty * 4];
            float4 s0 = *(const float4*)&sp[kk2][tx * 4];
            float4 s1 = *(const float4*)&sp[kk2][64 + tx * 4];
            float ee[8] = {e0.x, e0.y, e0.z, e0.w, e1.x, e1.y, e1.z, e1.w};
            float sv[8] = {s0.x, s0.y, s0.z, s0.w, s1.x, s1.y, s1.z, s1.w};
#pragma unroll
            for (int i = 0; i < 8; i++)
#pragma unroll
                for (int j = 0; j < 8; j++) acc[i][j] += ee[i] * sv[j];
        }
        __syncthreads();
    }
    float ow[8];
#pragma unroll
    for (int j = 0; j < 8; j++) {
        const int c = c0 + ((j < 4) ? (tx * 4 + j) : (64 + tx * 4 + j - 4));
        ow[j] = fmaxf(outw[c], 1e-8f);
    }
#pragma unroll
    for (int i = 0; i < 8; i++) {
        const int n = n0 + ((i < 4) ? (ty * 4 + i) : (64 + ty * 4 + i - 4));
        float* od = out + ((size_t)b * Nn + n) * Cn + c0;
        *(float4*)(od + tx * 4) =
            make_float4(acc[i][0] * ow[0], acc[i][1] * ow[1], acc[i][2] * ow[2], acc[i][3] * ow[3]);
        *(float4*)(od + 64 + tx * 4) =
            make_float4(acc[i][4] * ow[4], acc[i][5] * ow[5], acc[i][6] * ow[6], acc[i][7] * ow[7]);
    }
}

// ---------------------------------------------------------------------------
extern "C" void kernel_launch(void* const* d_in, const int* in_sizes, int n_in,
                              void* d_out, int out_size, void* d_ws, size_t ws_size,
                              hipStream_t stream)
{
    const float* x     = (const float*)d_in[0];
    const float* mass  = (const float*)d_in[1];
    const float* evals = (const float*)d_in[2];
    const float* evecs = (const float*)d_in[3];
    const int*   far   = (const int*)d_in[4];
    const float* t_in  = (const float*)d_in[5];
    const float* t_out = (const float*)d_in[6];
    const float* gn_w  = (const float*)d_in[7];
    const float* gn_b  = (const float*)d_in[8];
    const float* Wq    = (const float*)d_in[9];
    const float* bq    = (const float*)d_in[10];
    const float* Wk    = (const float*)d_in[11];
    const float* bk    = (const float*)d_in[12];
    const float* Wv    = (const float*)d_in[13];
    const float* bv    = (const float*)d_in[14];
    const float* Wo    = (const float*)d_in[15];
    const float* bo    = (const float*)d_in[16];
    const float* outw  = (const float*)d_in[17];
    float* out = (float*)d_out;
    float* ws = (float*)d_ws;

    // --- Lifetime-aliased workspace layout (same offsets as round 5-7;
    //     pm/pl/pacc slots now unused after single-pass attention).
    float* A     = ws;                      // 8,388,608
    float* evf   = ws    + 8388608;         //   524,288 (k3..k10)
    float* massf = evf   + 524288;          //     4,096
    float* gst   = massf + 4096;            //       256
    float* pm    = gst   + 256;             //   262,144 (unused)
    float* pl    = pm    + 262144;          //   262,144 (unused)
    float* spec1 = pl    + 262144;          //   131,072
    float* xfar  = spec1 + 131072;          // 1,048,576
    float* xn    = xfar  + 1048576;         // 1,048,576
    float* q     = xn    + 1048576;         // 1,048,576
    float* kk    = q     + 1048576;         // 1,048,576
    float* v     = kk    + 1048576;         // 1,048,576  (ends at 14,815,488)
    float* part2 = A;
    float* spec2 = spec1;   // spec1 dead after from_basis1
    float* xo    = xfar;    // xfar dead after gnapply
    float* att   = xn;      // xn dead after QKV gemm
    (void)pm; (void)pl;

    k_tobasis1<<<dim3(NCH, 1, Bn), 512, 0, stream>>>(x, mass, evecs, A);
    k_reduce<<<Bn * Kn, Cn, 0, stream>>>(A, NCH, evals, t_in, spec1);
    k_gather<<<Bn * Mn, Kn, 0, stream>>>(evecs, mass, far, evf, massf);
    {
        G3 g{};
        g.W[0] = spec1; g.bias[0] = nullptr; g.out[0] = xfar;
        k_gemm64<128, true, false><<<dim3(64, 4, 1), 256, 0, stream>>>(evf, g, nullptr);
    }
    k_gnstats<<<Bn * 32, 256, 0, stream>>>(xfar, gst);
    k_gnapply<<<1024, 256, 0, stream>>>(xfar, gst, gn_w, gn_b, xn);
    {
        G3 g{};
        g.W[0] = Wq; g.W[1] = Wk; g.W[2] = Wv;
        g.bias[0] = bq; g.bias[1] = bk; g.bias[2] = bv;
        g.out[0] = q; g.out[1] = kk; g.out[2] = v;
        k_gemm64<256, false, false><<<dim3(64, 4, 3), 256, 0, stream>>>(xn, g, nullptr);
    }
    k_attn<<<dim3(16, 32), 256, 0, stream>>>(q, kk, v, att);
    {
        G3 g{};
        g.W[0] = Wo; g.bias[0] = bo; g.out[0] = xo;
        k_gemm64<256, false, true><<<dim3(64, 4, 1), 256, 0, stream>>>(att, g, massf);
    }
    k_tobasis2<<<dim3(MCH, 2, Bn), 256, 0, stream>>>(evf, xo, part2);
    k_reduce<<<Bn * Kn, Cn, 0, stream>>>(part2, MCH, evals, t_out, spec2);
    k_frombasis2<<<dim3(256, 2, Bn), 256, 0, stream>>>(evecs, spec2, outw, out);
}

// Round 4
// 533.042 us; speedup vs baseline: 1.2215x; 1.0035x over previous
//
#include <hip/hip_runtime.h>
#include <hip/hip_bf16.h>

// All inputs and the output are fp32 (established empirically in rounds 1-2).
// Workspace layout is lifetime-aliased (high-water 56.5 MiB; see round-5 note).
//
// ROUND 9: k_frombasis2 rewritten as zero-LDS f16x3 MFMA GEMM.
//   Old: fp32 VALU outer-product, 105 us, MfmaUtil 0, VALUBusy 67%, 4.2M LDS
//   bank-conflict cycles, evecs read twice (ct=2 grid) -> 178 MB traffic at
//   21% peak. HBM floor is ~33 us (out 134 MB + evecs 67 MB once).
//   New: both MFMA operands are fragment-contiguous in global memory:
//   A = evecs[n][k] rows (16B f32 slices, convert to f16 hi/lo in-reg,
//   pre-scaled x256 so the lo-residual stays f16-normal; undone in epilogue);
//   B = spec transposed to [c][k] f16 hi/lo planes by tiny new k_spectr
//   (128 KB/batch, L2-resident). Block = 128n x 256c (evecs read ONCE),
//   512 thr = 8 waves (2n x 4c), K=128 in 4 steps. No LDS, no barriers.
//   Predicted: ~35-42 us, HBM-bound; bank conflicts ~0.
//   History: tb1 f16x3 (r7) ~88 us; attn f16x3 single-pass (r8) ~45 us.

#define Bn 4
#define Nn 32768
#define Kn 128
#define Cn 256
#define Mn 1024
#define Hn 8
#define Dn 32
#define NCH 64   // n-chunks for to_basis1 (chunk = 512 rows)
#define MCH 16   // m-chunks for to_basis2 (chunk = 64 rows)

typedef _Float16 f16;
typedef _Float16 f16x8 __attribute__((ext_vector_type(8)));
typedef float f32x4 __attribute__((ext_vector_type(4)));
typedef unsigned int u32;
typedef unsigned int u32x4 __attribute__((ext_vector_type(4)));

__device__ __forceinline__ void gload_lds16(const float* g, float* l) {
    __builtin_amdgcn_global_load_lds(
        (const __attribute__((address_space(1))) void*)g,
        (__attribute__((address_space(3))) void*)l, 16, 0, 0);
}

static __device__ __forceinline__ u32 packf16(f16 a, f16 b) {
    union { f16 h[2]; u32 u; } x;
    x.h[0] = a; x.h[1] = b;
    return x.u;
}

// ---------------------------------------------------------------------------
// K1: to_basis #1 (f16x3 MFMA).
// ---------------------------------------------------------------------------
__global__ __launch_bounds__(512) void k_tobasis1(
    const float* __restrict__ x, const float* __restrict__ mass,
    const float* __restrict__ evecs, float* __restrict__ part)
{
    const int nch = blockIdx.x, b = blockIdx.z;
    const int n0 = nch * (Nn / NCH);
    const int t = threadIdx.x;
    const int lane = t & 63, w = t >> 6;
    const int lr = lane & 15, lg = lane >> 4;
    const int wm = (w & 1) * 64;        // k-offset (basis rows)
    const int wc = (w >> 1) * 64;       // c-offset

    __shared__ __align__(16) float evS[2][32][128];   // 32 KB
    __shared__ __align__(16) float xS[2][32][256];    // 64 KB
    __shared__ __align__(16) f16 evT[128][64];        // 16 KB  hi|lo interleaved
    __shared__ __align__(16) f16 xT[256][64];         // 32 KB  hi|lo interleaved
    __shared__ __align__(16) float massS[512];        //  2 KB

    const size_t rb0 = (size_t)b * Nn + n0;
    const float* ebase = evecs + rb0 * Kn;
    const float* xbase = x + rb0 * Cn;

    f32x4 acc[4][4] = {};

    if (w < 2) gload_lds16(mass + rb0 + w * 256 + lane * 4, massS + w * 256);
#pragma unroll
    for (int ss = 0; ss < 2; ss++) {
        const float* eb = ebase + (size_t)ss * 32 * Kn;
        const float* xb = xbase + (size_t)ss * 32 * Cn;
#pragma unroll
        for (int iw = 0; iw < 2; iw++)
            gload_lds16(eb + (w * 2 + iw) * 256 + lane * 4, &evS[ss][0][0] + (w * 2 + iw) * 256);
#pragma unroll
        for (int iw = 0; iw < 4; iw++)
            gload_lds16(xb + (w * 4 + iw) * 256 + lane * 4, &xS[ss][0][0] + (w * 4 + iw) * 256);
    }

    for (int s = 0; s < 16; s++) {
        const int p = s & 1;
        if (s == 15) { asm volatile("s_waitcnt vmcnt(0)" ::: "memory"); }
        else         { asm volatile("s_waitcnt vmcnt(6)" ::: "memory"); }
        __builtin_amdgcn_sched_barrier(0);
        __builtin_amdgcn_s_barrier();

        {
            const int k = t & 127;
            const int g = t >> 7;          // wave-uniform
            f16x8 hv, lv;
#pragma unroll
            for (int r = 0; r < 8; r++) {
                const float f = evS[p][g * 8 + r][k];
                const f16 h = (f16)f;
                hv[r] = h;
                lv[r] = (f16)(f - (float)h);
            }
            *(f16x8*)&evT[k][((g) ^ (k & 7)) * 8] = hv;
            *(f16x8*)&evT[k][((4 + g) ^ (k & 7)) * 8] = lv;
        }
        {
            const int c = t & 255;
            const int g2 = t >> 8;         // wave-uniform
#pragma unroll
            for (int jj = 0; jj < 2; jj++) {
                const int ch = g2 * 2 + jj;
                f16x8 hv, lv;
#pragma unroll
                for (int r = 0; r < 8; r++) {
                    const int n = ch * 8 + r;
                    const float f = xS[p][n][c] * massS[s * 32 + n];
                    const f16 h = (f16)f;
                    hv[r] = h;
                    lv[r] = (f16)(f - (float)h);
                }
                *(f16x8*)&xT[c][((ch) ^ (c & 7)) * 8] = hv;
                *(f16x8*)&xT[c][((4 + ch) ^ (c & 7)) * 8] = lv;
            }
        }

        asm volatile("s_waitcnt lgkmcnt(0)" ::: "memory");
        __builtin_amdgcn_sched_barrier(0);
        __builtin_amdgcn_s_barrier();

        if (s + 2 < 16) {
            const float* eb = ebase + (size_t)(s + 2) * 32 * Kn;
            const float* xb = xbase + (size_t)(s + 2) * 32 * Cn;
#pragma unroll
            for (int iw = 0; iw < 2; iw++)
                gload_lds16(eb + (w * 2 + iw) * 256 + lane * 4, &evS[p][0][0] + (w * 2 + iw) * 256);
#pragma unroll
            for (int iw = 0; iw < 4; iw++)
                gload_lds16(xb + (w * 4 + iw) * 256 + lane * 4, &xS[p][0][0] + (w * 4 + iw) * 256);
        }

        f16x8 aH[4], aL[4], bH[4], bL[4];
#pragma unroll
        for (int i = 0; i < 4; i++) {
            const int rk = wm + i * 16 + lr;
            aH[i] = *(const f16x8*)&evT[rk][((lg) ^ (rk & 7)) * 8];
            aL[i] = *(const f16x8*)&evT[rk][((4 + lg) ^ (rk & 7)) * 8];
            const int rc = wc + i * 16 + lr;
            bH[i] = *(const f16x8*)&xT[rc][((lg) ^ (rc & 7)) * 8];
            bL[i] = *(const f16x8*)&xT[rc][((4 + lg) ^ (rc & 7)) * 8];
        }
#pragma unroll
        for (int i = 0; i < 4; i++)
#pragma unroll
            for (int j = 0; j < 4; j++) {
                acc[i][j] = __builtin_amdgcn_mfma_f32_16x16x32_f16(aH[i], bH[j], acc[i][j], 0, 0, 0);
                acc[i][j] = __builtin_amdgcn_mfma_f32_16x16x32_f16(aH[i], bL[j], acc[i][j], 0, 0, 0);
                acc[i][j] = __builtin_amdgcn_mfma_f32_16x16x32_f16(aL[i], bH[j], acc[i][j], 0, 0, 0);
            }
    }

    float* dst = part + ((size_t)b * NCH + nch) * (Kn * Cn);
#pragma unroll
    for (int i = 0; i < 4; i++)
#pragma unroll
        for (int j = 0; j < 4; j++) {
            const int m0 = wm + i * 16 + lg * 4;
            const int c = wc + j * 16 + lr;
#pragma unroll
            for (int r = 0; r < 4; r++)
                dst[(size_t)(m0 + r) * Cn + c] = acc[i][j][r];
        }
}

// ---------------------------------------------------------------------------
// Reduce chunk partials and apply heat coefficient exp(-eval * t_c)
// ---------------------------------------------------------------------------
__global__ __launch_bounds__(256) void k_reduce(
    const float* __restrict__ part, int nchunks,
    const float* __restrict__ evals, const float* __restrict__ tvec,
    float* __restrict__ spec)
{
    const int b = blockIdx.x >> 7, k = blockIdx.x & 127, c = threadIdx.x;
    float ssum = 0.f;
    const float* p = part + ((size_t)b * nchunks * Kn + k) * Cn + c;
    for (int j = 0; j < nchunks; j++) ssum += p[(size_t)j * Kn * Cn];
    const float lam = evals[b * Kn + k];
    const float tt = fmaxf(tvec[c], 1e-8f);
    spec[((size_t)b * Kn + k) * Cn + c] = ssum * __expf(-lam * tt);
}

// ---------------------------------------------------------------------------
// Transpose+split spec2 fp32 [b][k][c] -> specT hi/lo f16 [b][c][k]
// ---------------------------------------------------------------------------
__global__ __launch_bounds__(256) void k_spectr(
    const float* __restrict__ spec, f16* __restrict__ sTh, f16* __restrict__ sTl)
{
    const int kc = blockIdx.x, b = blockIdx.y;
    const int t = threadIdx.x;
    __shared__ f16 lh[32][258];   // 258 f16 = 129 dwords (odd) -> conflict-free cols
    __shared__ f16 ll[32][258];
#pragma unroll 8
    for (int k2 = 0; k2 < 32; k2++) {
        const float f = spec[((size_t)b * Kn + kc * 32 + k2) * Cn + t];
        const f16 h = (f16)f;
        lh[k2][t] = h;
        ll[k2][t] = (f16)(f - (float)h);
    }
    __syncthreads();
    f16x8 vh[4], vl[4];
#pragma unroll
    for (int q = 0; q < 4; q++)
#pragma unroll
        for (int j = 0; j < 8; j++) { vh[q][j] = lh[q * 8 + j][t]; vl[q][j] = ll[q * 8 + j][t]; }
    f16* dh = sTh + ((size_t)b * 256 + t) * Kn + kc * 32;
    f16* dl = sTl + ((size_t)b * 256 + t) * Kn + kc * 32;
#pragma unroll
    for (int q = 0; q < 4; q++) {
        *(f16x8*)(dh + q * 8) = vh[q];
        *(f16x8*)(dl + q * 8) = vl[q];
    }
}

// ---------------------------------------------------------------------------
// Gather evecs & mass at far indices
// ---------------------------------------------------------------------------
__global__ __launch_bounds__(128) void k_gather(
    const float* __restrict__ evecs, const float* __restrict__ mass,
    const int* __restrict__ far, float* __restrict__ evf, float* __restrict__ massf)
{
    const int row = blockIdx.x;  // b*M + m
    const int b = row >> 10;
    const int idx = far[row];
    const int t = threadIdx.x;
    evf[(size_t)row * Kn + t] = evecs[((size_t)b * Nn + idx) * Kn + t];
    if (t == 0) massf[row] = mass[(size_t)b * Nn + idx];
}

// ---------------------------------------------------------------------------
// Generic 64x64-tile GEMM: out[row][c'] = X[row][0:KD] @ W[KD][256] (+bias)(*mass)
// ---------------------------------------------------------------------------
struct G3 {
    const float* W[3];
    const float* bias[3];
    float* out[3];
};

template<int KD, bool PERB, bool MMASS>
__global__ __launch_bounds__(256) void k_gemm64(
    const float* __restrict__ X, G3 g, const float* __restrict__ massf)
{
    const int mt = blockIdx.x, ct = blockIdx.y, z = blockIdx.z;
    const int row0 = mt * 64, c0 = ct * 64;
    const int b = row0 >> 10;
    const float* Wp = g.W[z];
    const float* bias = g.bias[z];
    float* out = g.out[z];
    const size_t woff = PERB ? (size_t)b * KD * 256 : 0;

    __shared__ float xT[32][68];   // 68*4 = 272 B rows (16B-aligned)
    __shared__ float wl[32][64];
    const int t = threadIdx.x, tx = t & 15, ty = t >> 4;
    float acc[4][4] = {};

    for (int k0 = 0; k0 < KD; k0 += 32) {
        {
            const int m = t >> 2, cc0 = (t & 3) * 8;
            const float* xs = X + (size_t)(row0 + m) * KD + k0 + cc0;
            float4 a0 = *(const float4*)xs, a1 = *(const float4*)(xs + 4);
            xT[cc0 + 0][m] = a0.x; xT[cc0 + 1][m] = a0.y; xT[cc0 + 2][m] = a0.z; xT[cc0 + 3][m] = a0.w;
            xT[cc0 + 4][m] = a1.x; xT[cc0 + 5][m] = a1.y; xT[cc0 + 6][m] = a1.z; xT[cc0 + 7][m] = a1.w;
        }
        {
            const int cc = t >> 3, col = (t & 7) * 8;
            const float* wsrc = Wp + woff + (size_t)(k0 + cc) * 256 + c0 + col;
            float4 a0 = *(const float4*)wsrc, a1 = *(const float4*)(wsrc + 4);
            wl[cc][col + 0] = a0.x; wl[cc][col + 1] = a0.y; wl[cc][col + 2] = a0.z; wl[cc][col + 3] = a0.w;
            wl[cc][col + 4] = a1.x; wl[cc][col + 5] = a1.y; wl[cc][col + 6] = a1.z; wl[cc][col + 7] = a1.w;
        }
        __syncthreads();
#pragma unroll 8
        for (int cc = 0; cc < 32; cc++) {
            float4 xv = *(const float4*)&xT[cc][ty * 4];
            float4 wv = *(const float4*)&wl[cc][tx * 4];
            float xa[4] = {xv.x, xv.y, xv.z, xv.w};
            float wa[4] = {wv.x, wv.y, wv.z, wv.w};
#pragma unroll
            for (int i = 0; i < 4; i++)
#pragma unroll
                for (int j = 0; j < 4; j++) acc[i][j] += xa[i] * wa[j];
        }
        __syncthreads();
    }
    float bj[4] = {0.f, 0.f, 0.f, 0.f};
    if (bias) {
#pragma unroll
        for (int j = 0; j < 4; j++) bj[j] = bias[c0 + tx * 4 + j];
    }
#pragma unroll
    for (int i = 0; i < 4; i++) {
        const int row = row0 + ty * 4 + i;
        const float mm = MMASS ? massf[row] : 1.f;
        *(float4*)(out + (size_t)row * 256 + c0 + tx * 4) =
            make_float4((acc[i][0] + bj[0]) * mm, (acc[i][1] + bj[1]) * mm,
                        (acc[i][2] + bj[2]) * mm, (acc[i][3] + bj[3]) * mm);
    }
}

// ---------------------------------------------------------------------------
// GroupNorm stats: per (b, g) mean/invstd over M x 8 channels
// ---------------------------------------------------------------------------
__global__ __launch_bounds__(256) void k_gnstats(const float* __restrict__ xfar, float* __restrict__ gst)
{
    const int b = blockIdx.x >> 5, g = blockIdx.x & 31;
    const int t = threadIdx.x;
    float s = 0.f, s2 = 0.f;
#pragma unroll
    for (int i = 0; i < 4; i++) {
        const int m = t * 4 + i;
        const float* p = xfar + ((size_t)b * Mn + m) * Cn + g * 8;
        float4 a = *(const float4*)p;
        float4 c = *(const float4*)(p + 4);
        s += a.x + a.y + a.z + a.w + c.x + c.y + c.z + c.w;
        s2 += a.x * a.x + a.y * a.y + a.z * a.z + a.w * a.w +
              c.x * c.x + c.y * c.y + c.z * c.z + c.w * c.w;
    }
    __shared__ float sb[256], sb2[256];
    sb[t] = s; sb2[t] = s2;
    __syncthreads();
    for (int o = 128; o > 0; o >>= 1) {
        if (t < o) { sb[t] += sb[t + o]; sb2[t] += sb2[t + o]; }
        __syncthreads();
    }
    if (t == 0) {
        const float mean = sb[0] * (1.f / 8192.f);
        const float var = sb2[0] * (1.f / 8192.f) - mean * mean;
        gst[2 * blockIdx.x] = mean;
        gst[2 * blockIdx.x + 1] = rsqrtf(var + 1e-6f);
    }
}

__global__ __launch_bounds__(256) void k_gnapply(
    const float* __restrict__ xfar, const float* __restrict__ gst,
    const float* __restrict__ gw, const float* __restrict__ gb, float* __restrict__ xn)
{
    const int idx = (blockIdx.x * 256 + threadIdx.x) * 4;
    const int c = idx & 255;
    const int row = idx >> 8;
    const int b = row >> 10;
    const int g = c >> 3;
    const float2 st = *(const float2*)&gst[2 * (b * 32 + g)];
    float4 vv = *(const float4*)&xfar[idx];
    float4 w4 = *(const float4*)&gw[c];
    float4 b4 = *(const float4*)&gb[c];
    float4 o;
    o.x = (vv.x - st.x) * st.y * w4.x + b4.x;
    o.y = (vv.y - st.x) * st.y * w4.y + b4.y;
    o.z = (vv.z - st.x) * st.y * w4.z + b4.z;
    o.w = (vv.w - st.x) * st.y * w4.w + b4.w;
    *(float4*)&xn[idx] = o;
}

// ---------------------------------------------------------------------------
// Flash attention, f16x3 MFMA, single pass over all 1024 keys.
// ---------------------------------------------------------------------------
__global__ __launch_bounds__(256) void k_attn(
    const float* __restrict__ q, const float* __restrict__ kbuf, const float* __restrict__ vbuf,
    float* __restrict__ att)
{
    const int qt = blockIdx.x;      // 16 tiles of 64 q-rows
    const int bh = blockIdx.y;      // b*8 + h
    const int b = bh >> 3, h = bh & 7;
    const int t = threadIdx.x;
    const int lane = t & 63, w = t >> 6;
    const int lr = lane & 15, lg = lane >> 4;

    __shared__ __align__(16) f16 Kh[64][32];     // [key][d] hi
    __shared__ __align__(16) f16 Kl[64][32];     // [key][d] lo
    __shared__ __align__(16) f16 Vh[32][64];     // [d][key] hi, 16B-chunk ^(d&7)
    __shared__ __align__(16) f16 Vl[32][64];     // [d][key] lo
    __shared__ __align__(16) u32 Pw[4][16][68];  // per-wave P (hi,lo) packed

    const size_t base = (size_t)b * Mn * Cn + h * Dn;
    const int q0 = qt * 64;

    f16x8 Qh, Ql;
    {
        const float* qp = q + base + (size_t)(q0 + w * 16 + lr) * Cn + lg * 8;
        f32x4 a0 = *(const f32x4*)qp;
        f32x4 a1 = *(const f32x4*)(qp + 4);
        const float scale = 0.17677669529663687f;
        float qv[8] = {a0[0], a0[1], a0[2], a0[3], a1[0], a1[1], a1[2], a1[3]};
#pragma unroll
        for (int r = 0; r < 8; r++) {
            const float f = qv[r] * scale;
            const f16 hh = (f16)f;
            Qh[r] = hh;
            Ql[r] = (f16)(f - (float)hh);
        }
    }

    const int krow = t >> 2, kdg = (t & 3) * 8;        // K: row, d-offset
    const int vrow = (t & 31) * 2, vdc = (t >> 5) * 4; // V: row-pair base, d-offset

    f32x4 kr0, kr1, va, vb;
    {
        const float* kp = kbuf + base + (size_t)krow * Cn + kdg;
        kr0 = *(const f32x4*)kp; kr1 = *(const f32x4*)(kp + 4);
        const float* vp = vbuf + base + (size_t)vrow * Cn + vdc;
        va = *(const f32x4*)vp; vb = *(const f32x4*)(vp + Cn);
    }

    float m_i[4], l_i[4];
    f32x4 acc[2] = {};
#pragma unroll
    for (int r = 0; r < 4; r++) { m_i[r] = -1e30f; l_i[r] = 0.f; }

#pragma unroll 1
    for (int kt = 0; kt < 16; kt++) {
        asm volatile("" ::: "memory");
        __builtin_amdgcn_s_barrier();   // all waves done reading K/V of tile kt-1

        {
            float kv[8] = {kr0[0], kr0[1], kr0[2], kr0[3], kr1[0], kr1[1], kr1[2], kr1[3]};
            f16x8 hv, lv;
#pragma unroll
            for (int r = 0; r < 8; r++) {
                const f16 hh = (f16)kv[r];
                hv[r] = hh;
                lv[r] = (f16)(kv[r] - (float)hh);
            }
            *(f16x8*)&Kh[krow][kdg] = hv;
            *(f16x8*)&Kl[krow][kdg] = lv;
        }
        {
            float v0[4] = {va[0], va[1], va[2], va[3]};
            float v1[4] = {vb[0], vb[1], vb[2], vb[3]};
#pragma unroll
            for (int j = 0; j < 4; j++) {
                const int d = vdc + j;
                const f16 h0 = (f16)v0[j], h1 = (f16)v1[j];
                const f16 l0 = (f16)(v0[j] - (float)h0), l1 = (f16)(v1[j] - (float)h1);
                const int col = vrow >> 1;                       // u32 col 0..31
                const int idx = (((col >> 2) ^ (d & 7)) << 2) | (col & 3);
                ((u32*)&Vh[d][0])[idx] = packf16(h0, h1);
                ((u32*)&Vl[d][0])[idx] = packf16(l0, l1);
            }
        }
        if (kt < 15) {
            const float* kp = kbuf + base + (size_t)((kt + 1) * 64 + krow) * Cn + kdg;
            kr0 = *(const f32x4*)kp; kr1 = *(const f32x4*)(kp + 4);
            const float* vp = vbuf + base + (size_t)((kt + 1) * 64 + vrow) * Cn + vdc;
            va = *(const f32x4*)vp; vb = *(const f32x4*)(vp + Cn);
        }

        asm volatile("s_waitcnt lgkmcnt(0)" ::: "memory");
        __builtin_amdgcn_sched_barrier(0);
        __builtin_amdgcn_s_barrier();   // K/V tile visible

        f32x4 s[4];
#pragma unroll
        for (int ct = 0; ct < 4; ct++) {
            const f16x8 khi = *(const f16x8*)&Kh[ct * 16 + lr][lg * 8];
            const f16x8 klo = *(const f16x8*)&Kl[ct * 16 + lr][lg * 8];
            f32x4 z = {};
            z = __builtin_amdgcn_mfma_f32_16x16x32_f16(Qh, khi, z, 0, 0, 0);
            z = __builtin_amdgcn_mfma_f32_16x16x32_f16(Qh, klo, z, 0, 0, 0);
            z = __builtin_amdgcn_mfma_f32_16x16x32_f16(Ql, khi, z, 0, 0, 0);
            s[ct] = z;
        }

        float tm[4];
#pragma unroll
        for (int r = 0; r < 4; r++)
            tm[r] = fmaxf(fmaxf(s[0][r], s[1][r]), fmaxf(s[2][r], s[3][r]));
#pragma unroll
        for (int r = 0; r < 4; r++) {
            tm[r] = fmaxf(tm[r], __shfl_xor(tm[r], 1));
            tm[r] = fmaxf(tm[r], __shfl_xor(tm[r], 2));
            tm[r] = fmaxf(tm[r], __shfl_xor(tm[r], 4));
            tm[r] = fmaxf(tm[r], __shfl_xor(tm[r], 8));
        }
        float corr[4], rs[4];
#pragma unroll
        for (int r = 0; r < 4; r++) {
            const float nm = fmaxf(m_i[r], tm[r]);
            corr[r] = __expf(m_i[r] - nm);
            m_i[r] = nm;
            rs[r] = 0.f;
        }
#pragma unroll
        for (int ct = 0; ct < 4; ct++)
#pragma unroll
            for (int r = 0; r < 4; r++) {
                const float p = __expf(s[ct][r] - m_i[r]);
                rs[r] += p;
                const f16 ph = (f16)p;
                const f16 pl = (f16)(p - (float)ph);
                Pw[w][lg * 4 + r][ct * 16 + lr] = packf16(ph, pl);
            }
#pragma unroll
        for (int r = 0; r < 4; r++) {
            rs[r] += __shfl_xor(rs[r], 1);
            rs[r] += __shfl_xor(rs[r], 2);
            rs[r] += __shfl_xor(rs[r], 4);
            rs[r] += __shfl_xor(rs[r], 8);
            l_i[r] = l_i[r] * corr[r] + rs[r];
        }
#pragma unroll
        for (int dt = 0; dt < 2; dt++)
#pragma unroll
            for (int r = 0; r < 4; r++) acc[dt][r] *= corr[r];

        asm volatile("s_waitcnt lgkmcnt(0)" ::: "memory");
        __builtin_amdgcn_sched_barrier(0);

        f16x8 pah[2], pal[2];
#pragma unroll
        for (int kc = 0; kc < 2; kc++) {
            const u32* prow = &Pw[w][lr][0] + kc * 32 + lg * 8;
            u32x4 ua = *(const u32x4*)prow;
            u32x4 ub = *(const u32x4*)(prow + 4);
            union { u32 wd[4]; f16x8 v; } hh, ll;
            hh.wd[0] = __builtin_amdgcn_perm(ua[1], ua[0], 0x05040100u);
            hh.wd[1] = __builtin_amdgcn_perm(ua[3], ua[2], 0x05040100u);
            hh.wd[2] = __builtin_amdgcn_perm(ub[1], ub[0], 0x05040100u);
            hh.wd[3] = __builtin_amdgcn_perm(ub[3], ub[2], 0x05040100u);
            ll.wd[0] = __builtin_amdgcn_perm(ua[1], ua[0], 0x07060302u);
            ll.wd[1] = __builtin_amdgcn_perm(ua[3], ua[2], 0x07060302u);
            ll.wd[2] = __builtin_amdgcn_perm(ub[1], ub[0], 0x07060302u);
            ll.wd[3] = __builtin_amdgcn_perm(ub[3], ub[2], 0x07060302u);
            pah[kc] = hh.v;
            pal[kc] = ll.v;
        }

#pragma unroll
        for (int dt = 0; dt < 2; dt++)
#pragma unroll
            for (int kc = 0; kc < 2; kc++) {
                const int d = dt * 16 + lr;
                const int ch = ((kc * 4 + lg) ^ (lr & 7)) * 8;
                const f16x8 vh = *(const f16x8*)&Vh[d][ch];
                const f16x8 vl = *(const f16x8*)&Vl[d][ch];
                acc[dt] = __builtin_amdgcn_mfma_f32_16x16x32_f16(pah[kc], vh, acc[dt], 0, 0, 0);
                acc[dt] = __builtin_amdgcn_mfma_f32_16x16x32_f16(pah[kc], vl, acc[dt], 0, 0, 0);
                acc[dt] = __builtin_amdgcn_mfma_f32_16x16x32_f16(pal[kc], vh, acc[dt], 0, 0, 0);
            }
    }

#pragma unroll
    for (int r = 0; r < 4; r++) {
        const float inv = 1.f / l_i[r];
        const size_t orow = (size_t)b * Mn + q0 + w * 16 + lg * 4 + r;
#pragma unroll
        for (int dt = 0; dt < 2; dt++)
            att[orow * Cn + h * Dn + dt * 16 + lr] = acc[dt][r] * inv;
    }
}

// ---------------------------------------------------------------------------
// to_basis #2 over far rows only
// ---------------------------------------------------------------------------
__global__ __launch_bounds__(256) void k_tobasis2(
    const float* __restrict__ evf, const float* __restrict__ xo, float* __restrict__ part)
{
    const int mch = blockIdx.x, ct = blockIdx.y, b = blockIdx.z;
    const int m0 = mch * (Mn / MCH);
    const int c0 = ct * 128;
    __shared__ float ev[32][128];
    __shared__ float xm[32][128];
    const int t = threadIdx.x, tx = t & 15, ty = t >> 4;
    float acc[8][8];
#pragma unroll
    for (int i = 0; i < 8; i++)
#pragma unroll
        for (int j = 0; j < 8; j++) acc[i][j] = 0.f;
    const int lr = t >> 3, lc = (t & 7) * 16;
    for (int s = 0; s < Mn / MCH; s += 32) {
        const size_t mrow = (size_t)b * Mn + m0 + s + lr;
        {
            const float* es = evf + mrow * Kn + lc;
            *(float4*)&ev[lr][lc]      = *(const float4*)es;
            *(float4*)&ev[lr][lc + 4]  = *(const float4*)(es + 4);
            *(float4*)&ev[lr][lc + 8]  = *(const float4*)(es + 8);
            *(float4*)&ev[lr][lc + 12] = *(const float4*)(es + 12);
            const float* xs = xo + mrow * Cn + c0 + lc;
            *(float4*)&xm[lr][lc]      = *(const float4*)xs;
            *(float4*)&xm[lr][lc + 4]  = *(const float4*)(xs + 4);
            *(float4*)&xm[lr][lc + 8]  = *(const float4*)(xs + 8);
            *(float4*)&xm[lr][lc + 12] = *(const float4*)(xs + 12);
        }
        __syncthreads();
#pragma unroll 4
        for (int nn = 0; nn < 32; nn++) {
            float4 e0 = *(const float4*)&ev[nn][ty * 4];
            float4 e1 = *(const float4*)&ev[nn][64 + ty * 4];
            float4 x0 = *(const float4*)&xm[nn][tx * 4];
            float4 x1 = *(const float4*)&xm[nn][64 + tx * 4];
            float ee[8] = {e0.x, e0.y, e0.z, e0.w, e1.x, e1.y, e1.z, e1.w};
            float xx[8] = {x0.x, x0.y, x0.z, x0.w, x1.x, x1.y, x1.z, x1.w};
#pragma unroll
            for (int i = 0; i < 8; i++)
#pragma unroll
                for (int j = 0; j < 8; j++) acc[i][j] += ee[i] * xx[j];
        }
        __syncthreads();
    }
    float* dst = part + ((size_t)b * MCH + mch) * (Kn * Cn);
#pragma unroll
    for (int i = 0; i < 8; i++) {
        const int k = (i < 4) ? (ty * 4 + i) : (64 + ty * 4 + i - 4);
        *(float4*)(dst + (size_t)k * Cn + c0 + tx * 4) =
            make_float4(acc[i][0], acc[i][1], acc[i][2], acc[i][3]);
        *(float4*)(dst + (size_t)k * Cn + c0 + 64 + tx * 4) =
            make_float4(acc[i][4], acc[i][5], acc[i][6], acc[i][7]);
    }
}

// ---------------------------------------------------------------------------
// from_basis #2 (f16x3 MFMA, zero-LDS):
// out[b,n,c] = ow[c] * sum_k evecs[b,n,k] * spec2[b,k,c]
// A = evecs rows (fp32 -> f16 hi/lo in-reg, pre-scaled x256),
// B = specT hi/lo f16 [c][k] (global, L2-resident).
// Block 128n x 256c, 512 thr = 8 waves (2n x 4c). K=128 in 4 steps.
// ---------------------------------------------------------------------------
__global__ __launch_bounds__(512) void k_frombasis2(
    const float* __restrict__ evecs, const f16* __restrict__ sTh,
    const f16* __restrict__ sTl, const float* __restrict__ outw,
    float* __restrict__ out)
{
    const int nt = blockIdx.x, b = blockIdx.z;
    const int n0 = nt * 128;
    const int t = threadIdx.x;
    const int lane = t & 63, w = t >> 6;
    const int lr = lane & 15, lg = lane >> 4;
    const int wn = (w & 1) * 64;        // n-offset within block
    const int wc = (w >> 1) * 64;       // c-offset

    const float* Abase = evecs + ((size_t)b * Nn + n0 + wn + lr) * Kn + lg * 8;
    const f16* Bh = sTh + ((size_t)(b * 256 + wc + lr)) * Kn + lg * 8;
    const f16* Bl = sTl + ((size_t)(b * 256 + wc + lr)) * Kn + lg * 8;

    f32x4 acc[4][4] = {};

#pragma unroll
    for (int kk = 0; kk < 4; kk++) {
        f16x8 bh[4], bl[4];
#pragma unroll
        for (int cf = 0; cf < 4; cf++) {
            bh[cf] = *(const f16x8*)(Bh + (size_t)cf * 16 * Kn + kk * 32);
            bl[cf] = *(const f16x8*)(Bl + (size_t)cf * 16 * Kn + kk * 32);
        }
#pragma unroll
        for (int rf = 0; rf < 4; rf++) {
            const float* ap = Abase + (size_t)rf * 16 * Kn + kk * 32;
            f32x4 a0 = *(const f32x4*)ap;
            f32x4 a1 = *(const f32x4*)(ap + 4);
            float av[8] = {a0[0], a0[1], a0[2], a0[3], a1[0], a1[1], a1[2], a1[3]};
            f16x8 ah, al;
#pragma unroll
            for (int r = 0; r < 8; r++) {
                const float f = av[r] * 256.f;      // exact scale: lo stays f16-normal
                const f16 hh = (f16)f;
                ah[r] = hh;
                al[r] = (f16)(f - (float)hh);
            }
#pragma unroll
            for (int cf = 0; cf < 4; cf++) {
                acc[rf][cf] = __builtin_amdgcn_mfma_f32_16x16x32_f16(ah, bh[cf], acc[rf][cf], 0, 0, 0);
                acc[rf][cf] = __builtin_amdgcn_mfma_f32_16x16x32_f16(ah, bl[cf], acc[rf][cf], 0, 0, 0);
                acc[rf][cf] = __builtin_amdgcn_mfma_f32_16x16x32_f16(al, bh[cf], acc[rf][cf], 0, 0, 0);
            }
        }
    }

    float ow4[4];
#pragma unroll
    for (int cf = 0; cf < 4; cf++)
        ow4[cf] = fmaxf(outw[wc + cf * 16 + lr], 1e-8f) * (1.f / 256.f);
#pragma unroll
    for (int rf = 0; rf < 4; rf++)
#pragma unroll
        for (int cf = 0; cf < 4; cf++) {
            const int nn = n0 + wn + rf * 16 + lg * 4;
            const int c = wc + cf * 16 + lr;
#pragma unroll
            for (int r = 0; r < 4; r++)
                out[((size_t)b * Nn + nn + r) * Cn + c] = acc[rf][cf][r] * ow4[cf];
        }
}

// ---------------------------------------------------------------------------
extern "C" void kernel_launch(void* const* d_in, const int* in_sizes, int n_in,
                              void* d_out, int out_size, void* d_ws, size_t ws_size,
                              hipStream_t stream)
{
    const float* x     = (const float*)d_in[0];
    const float* mass  = (const float*)d_in[1];
    const float* evals = (const float*)d_in[2];
    const float* evecs = (const float*)d_in[3];
    const int*   far   = (const int*)d_in[4];
    const float* t_in  = (const float*)d_in[5];
    const float* t_out = (const float*)d_in[6];
    const float* gn_w  = (const float*)d_in[7];
    const float* gn_b  = (const float*)d_in[8];
    const float* Wq    = (const float*)d_in[9];
    const float* bq    = (const float*)d_in[10];
    const float* Wk    = (const float*)d_in[11];
    const float* bk    = (const float*)d_in[12];
    const float* Wv    = (const float*)d_in[13];
    const float* bv    = (const float*)d_in[14];
    const float* Wo    = (const float*)d_in[15];
    const float* bo    = (const float*)d_in[16];
    const float* outw  = (const float*)d_in[17];
    float* out = (float*)d_out;
    float* ws = (float*)d_ws;

    // --- Lifetime-aliased workspace layout (same offsets as rounds 5-8).
    //     pm slot (1 MB) now hosts the specT f16 hi/lo planes (512 KB used).
    float* A     = ws;                      // 8,388,608
    float* evf   = ws    + 8388608;         //   524,288 (k3..k10)
    float* massf = evf   + 524288;          //     4,096
    float* gst   = massf + 4096;            //       256
    float* pm    = gst   + 256;             //   262,144 (-> specT planes)
    float* pl    = pm    + 262144;          //   262,144 (unused)
    float* spec1 = pl    + 262144;          //   131,072
    float* xfar  = spec1 + 131072;          // 1,048,576
    float* xn    = xfar  + 1048576;         // 1,048,576
    float* q     = xn    + 1048576;         // 1,048,576
    float* kk    = q     + 1048576;         // 1,048,576
    float* v     = kk    + 1048576;         // 1,048,576  (ends at 14,815,488)
    float* part2 = A;
    float* spec2 = spec1;   // spec1 dead after from_basis1
    float* xo    = xfar;    // xfar dead after gnapply
    float* att   = xn;      // xn dead after QKV gemm
    f16* specTh  = (f16*)pm;            // 131072 f16 = 256 KB
    f16* specTl  = specTh + 131072;     // 131072 f16 = 256 KB (fits pm slot)
    (void)pl;

    k_tobasis1<<<dim3(NCH, 1, Bn), 512, 0, stream>>>(x, mass, evecs, A);
    k_reduce<<<Bn * Kn, Cn, 0, stream>>>(A, NCH, evals, t_in, spec1);
    k_gather<<<Bn * Mn, Kn, 0, stream>>>(evecs, mass, far, evf, massf);
    {
        G3 g{};
        g.W[0] = spec1; g.bias[0] = nullptr; g.out[0] = xfar;
        k_gemm64<128, true, false><<<dim3(64, 4, 1), 256, 0, stream>>>(evf, g, nullptr);
    }
    k_gnstats<<<Bn * 32, 256, 0, stream>>>(xfar, gst);
    k_gnapply<<<1024, 256, 0, stream>>>(xfar, gst, gn_w, gn_b, xn);
    {
        G3 g{};
        g.W[0] = Wq; g.W[1] = Wk; g.W[2] = Wv;
        g.bias[0] = bq; g.bias[1] = bk; g.bias[2] = bv;
        g.out[0] = q; g.out[1] = kk; g.out[2] = v;
        k_gemm64<256, false, false><<<dim3(64, 4, 3), 256, 0, stream>>>(xn, g, nullptr);
    }
    k_attn<<<dim3(16, 32), 256, 0, stream>>>(q, kk, v, att);
    {
        G3 g{};
        g.W[0] = Wo; g.bias[0] = bo; g.out[0] = xo;
        k_gemm64<256, false, true><<<dim3(64, 4, 1), 256, 0, stream>>>(att, g, massf);
    }
    k_tobasis2<<<dim3(MCH, 2, Bn), 256, 0, stream>>>(evf, xo, part2);
    k_reduce<<<Bn * Kn, Cn, 0, stream>>>(part2, MCH, evals, t_out, spec2);
    k_spectr<<<dim3(4, Bn), 256, 0, stream>>>(spec2, specTh, specTl);
    k_frombasis2<<<dim3(256, 1, Bn), 512, 0, stream>>>(evecs, specTh, specTl, outw, out);
}

// Round 6
// 506.220 us; speedup vs baseline: 1.2862x; 1.0530x over previous
//
#include <hip/hip_runtime.h>
#include <hip/hip_bf16.h>

// All inputs and the output are fp32 (established empirically in rounds 1-2).
// Workspace layout is lifetime-aliased (high-water 56.5 MiB; see round-5 note).
//
// ROUND 11 = ROUND 10 RESUBMIT (round-10 bench died in container acquisition;
// no execution signal, so the kernel is unchanged).
//
// ROUND 10: k_frombasis2 take 2 -- fix the latency-bound zero-LDS design.
//   Round-9 landed 93 us with MfmaUtil 10 / VALU 11 / HBM 23 / occ 17.8%:
//   all pipes idle = latency-bound. 80 VGPRs held one kk-step of operands;
//   each of 4 kk-steps serialized {issue loads -> ~700cy wait -> MFMA} with
//   ~1.4 waves/SIMD resident. Fix (attn r8 pattern): reg-stage A with
//   register prefetch across barriers into double-buffered f16 hi|lo LDS
//   tiles (chunk^(row&7) swizzle, proven conflict-free), B-loads issued
//   before the barrier so L2 latency overlaps it. One barrier/step.
//   Predicted: ~40-48 us, HBM ~50%.
//   History: tb1 f16x3 (r7) ~88; attn f16x3 (r8) ~45; fb2 v1 (r9) 93.

#define Bn 4
#define Nn 32768
#define Kn 128
#define Cn 256
#define Mn 1024
#define Hn 8
#define Dn 32
#define NCH 64   // n-chunks for to_basis1 (chunk = 512 rows)
#define MCH 16   // m-chunks for to_basis2 (chunk = 64 rows)

typedef _Float16 f16;
typedef _Float16 f16x8 __attribute__((ext_vector_type(8)));
typedef float f32x4 __attribute__((ext_vector_type(4)));
typedef unsigned int u32;
typedef unsigned int u32x4 __attribute__((ext_vector_type(4)));

__device__ __forceinline__ void gload_lds16(const float* g, float* l) {
    __builtin_amdgcn_global_load_lds(
        (const __attribute__((address_space(1))) void*)g,
        (__attribute__((address_space(3))) void*)l, 16, 0, 0);
}

static __device__ __forceinline__ u32 packf16(f16 a, f16 b) {
    union { f16 h[2]; u32 u; } x;
    x.h[0] = a; x.h[1] = b;
    return x.u;
}

// ---------------------------------------------------------------------------
// K1: to_basis #1 (f16x3 MFMA).
// ---------------------------------------------------------------------------
__global__ __launch_bounds__(512) void k_tobasis1(
    const float* __restrict__ x, const float* __restrict__ mass,
    const float* __restrict__ evecs, float* __restrict__ part)
{
    const int nch = blockIdx.x, b = blockIdx.z;
    const int n0 = nch * (Nn / NCH);
    const int t = threadIdx.x;
    const int lane = t & 63, w = t >> 6;
    const int lr = lane & 15, lg = lane >> 4;
    const int wm = (w & 1) * 64;        // k-offset (basis rows)
    const int wc = (w >> 1) * 64;       // c-offset

    __shared__ __align__(16) float evS[2][32][128];   // 32 KB
    __shared__ __align__(16) float xS[2][32][256];    // 64 KB
    __shared__ __align__(16) f16 evT[128][64];        // 16 KB  hi|lo interleaved
    __shared__ __align__(16) f16 xT[256][64];         // 32 KB  hi|lo interleaved
    __shared__ __align__(16) float massS[512];        //  2 KB

    const size_t rb0 = (size_t)b * Nn + n0;
    const float* ebase = evecs + rb0 * Kn;
    const float* xbase = x + rb0 * Cn;

    f32x4 acc[4][4] = {};

    if (w < 2) gload_lds16(mass + rb0 + w * 256 + lane * 4, massS + w * 256);
#pragma unroll
    for (int ss = 0; ss < 2; ss++) {
        const float* eb = ebase + (size_t)ss * 32 * Kn;
        const float* xb = xbase + (size_t)ss * 32 * Cn;
#pragma unroll
        for (int iw = 0; iw < 2; iw++)
            gload_lds16(eb + (w * 2 + iw) * 256 + lane * 4, &evS[ss][0][0] + (w * 2 + iw) * 256);
#pragma unroll
        for (int iw = 0; iw < 4; iw++)
            gload_lds16(xb + (w * 4 + iw) * 256 + lane * 4, &xS[ss][0][0] + (w * 4 + iw) * 256);
    }

    for (int s = 0; s < 16; s++) {
        const int p = s & 1;
        if (s == 15) { asm volatile("s_waitcnt vmcnt(0)" ::: "memory"); }
        else         { asm volatile("s_waitcnt vmcnt(6)" ::: "memory"); }
        __builtin_amdgcn_sched_barrier(0);
        __builtin_amdgcn_s_barrier();

        {
            const int k = t & 127;
            const int g = t >> 7;          // wave-uniform
            f16x8 hv, lv;
#pragma unroll
            for (int r = 0; r < 8; r++) {
                const float f = evS[p][g * 8 + r][k];
                const f16 h = (f16)f;
                hv[r] = h;
                lv[r] = (f16)(f - (float)h);
            }
            *(f16x8*)&evT[k][((g) ^ (k & 7)) * 8] = hv;
            *(f16x8*)&evT[k][((4 + g) ^ (k & 7)) * 8] = lv;
        }
        {
            const int c = t & 255;
            const int g2 = t >> 8;         // wave-uniform
#pragma unroll
            for (int jj = 0; jj < 2; jj++) {
                const int ch = g2 * 2 + jj;
                f16x8 hv, lv;
#pragma unroll
                for (int r = 0; r < 8; r++) {
                    const int n = ch * 8 + r;
                    const float f = xS[p][n][c] * massS[s * 32 + n];
                    const f16 h = (f16)f;
                    hv[r] = h;
                    lv[r] = (f16)(f - (float)h);
                }
                *(f16x8*)&xT[c][((ch) ^ (c & 7)) * 8] = hv;
                *(f16x8*)&xT[c][((4 + ch) ^ (c & 7)) * 8] = lv;
            }
        }

        asm volatile("s_waitcnt lgkmcnt(0)" ::: "memory");
        __builtin_amdgcn_sched_barrier(0);
        __builtin_amdgcn_s_barrier();

        if (s + 2 < 16) {
            const float* eb = ebase + (size_t)(s + 2) * 32 * Kn;
            const float* xb = xbase + (size_t)(s + 2) * 32 * Cn;
#pragma unroll
            for (int iw = 0; iw < 2; iw++)
                gload_lds16(eb + (w * 2 + iw) * 256 + lane * 4, &evS[p][0][0] + (w * 2 + iw) * 256);
#pragma unroll
            for (int iw = 0; iw < 4; iw++)
                gload_lds16(xb + (w * 4 + iw) * 256 + lane * 4, &xS[p][0][0] + (w * 4 + iw) * 256);
        }

        f16x8 aH[4], aL[4], bH[4], bL[4];
#pragma unroll
        for (int i = 0; i < 4; i++) {
            const int rk = wm + i * 16 + lr;
            aH[i] = *(const f16x8*)&evT[rk][((lg) ^ (rk & 7)) * 8];
            aL[i] = *(const f16x8*)&evT[rk][((4 + lg) ^ (rk & 7)) * 8];
            const int rc = wc + i * 16 + lr;
            bH[i] = *(const f16x8*)&xT[rc][((lg) ^ (rc & 7)) * 8];
            bL[i] = *(const f16x8*)&xT[rc][((4 + lg) ^ (rc & 7)) * 8];
        }
#pragma unroll
        for (int i = 0; i < 4; i++)
#pragma unroll
            for (int j = 0; j < 4; j++) {
                acc[i][j] = __builtin_amdgcn_mfma_f32_16x16x32_f16(aH[i], bH[j], acc[i][j], 0, 0, 0);
                acc[i][j] = __builtin_amdgcn_mfma_f32_16x16x32_f16(aH[i], bL[j], acc[i][j], 0, 0, 0);
                acc[i][j] = __builtin_amdgcn_mfma_f32_16x16x32_f16(aL[i], bH[j], acc[i][j], 0, 0, 0);
            }
    }

    float* dst = part + ((size_t)b * NCH + nch) * (Kn * Cn);
#pragma unroll
    for (int i = 0; i < 4; i++)
#pragma unroll
        for (int j = 0; j < 4; j++) {
            const int m0 = wm + i * 16 + lg * 4;
            const int c = wc + j * 16 + lr;
#pragma unroll
            for (int r = 0; r < 4; r++)
                dst[(size_t)(m0 + r) * Cn + c] = acc[i][j][r];
        }
}

// ---------------------------------------------------------------------------
// Reduce chunk partials and apply heat coefficient exp(-eval * t_c)
// ---------------------------------------------------------------------------
__global__ __launch_bounds__(256) void k_reduce(
    const float* __restrict__ part, int nchunks,
    const float* __restrict__ evals, const float* __restrict__ tvec,
    float* __restrict__ spec)
{
    const int b = blockIdx.x >> 7, k = blockIdx.x & 127, c = threadIdx.x;
    float ssum = 0.f;
    const float* p = part + ((size_t)b * nchunks * Kn + k) * Cn + c;
    for (int j = 0; j < nchunks; j++) ssum += p[(size_t)j * Kn * Cn];
    const float lam = evals[b * Kn + k];
    const float tt = fmaxf(tvec[c], 1e-8f);
    spec[((size_t)b * Kn + k) * Cn + c] = ssum * __expf(-lam * tt);
}

// ---------------------------------------------------------------------------
// Transpose+split spec2 fp32 [b][k][c] -> specT hi/lo f16 [b][c][k]
// ---------------------------------------------------------------------------
__global__ __launch_bounds__(256) void k_spectr(
    const float* __restrict__ spec, f16* __restrict__ sTh, f16* __restrict__ sTl)
{
    const int kc = blockIdx.x, b = blockIdx.y;
    const int t = threadIdx.x;
    __shared__ f16 lh[32][258];   // odd-dword rows -> conflict-free columns
    __shared__ f16 ll[32][258];
#pragma unroll 8
    for (int k2 = 0; k2 < 32; k2++) {
        const float f = spec[((size_t)b * Kn + kc * 32 + k2) * Cn + t];
        const f16 h = (f16)f;
        lh[k2][t] = h;
        ll[k2][t] = (f16)(f - (float)h);
    }
    __syncthreads();
    f16x8 vh[4], vl[4];
#pragma unroll
    for (int q = 0; q < 4; q++)
#pragma unroll
        for (int j = 0; j < 8; j++) { vh[q][j] = lh[q * 8 + j][t]; vl[q][j] = ll[q * 8 + j][t]; }
    f16* dh = sTh + ((size_t)b * 256 + t) * Kn + kc * 32;
    f16* dl = sTl + ((size_t)b * 256 + t) * Kn + kc * 32;
#pragma unroll
    for (int q = 0; q < 4; q++) {
        *(f16x8*)(dh + q * 8) = vh[q];
        *(f16x8*)(dl + q * 8) = vl[q];
    }
}

// ---------------------------------------------------------------------------
// Gather evecs & mass at far indices
// ---------------------------------------------------------------------------
__global__ __launch_bounds__(128) void k_gather(
    const float* __restrict__ evecs, const float* __restrict__ mass,
    const int* __restrict__ far, float* __restrict__ evf, float* __restrict__ massf)
{
    const int row = blockIdx.x;  // b*M + m
    const int b = row >> 10;
    const int idx = far[row];
    const int t = threadIdx.x;
    evf[(size_t)row * Kn + t] = evecs[((size_t)b * Nn + idx) * Kn + t];
    if (t == 0) massf[row] = mass[(size_t)b * Nn + idx];
}

// ---------------------------------------------------------------------------
// Generic 64x64-tile GEMM: out[row][c'] = X[row][0:KD] @ W[KD][256] (+bias)(*mass)
// ---------------------------------------------------------------------------
struct G3 {
    const float* W[3];
    const float* bias[3];
    float* out[3];
};

template<int KD, bool PERB, bool MMASS>
__global__ __launch_bounds__(256) void k_gemm64(
    const float* __restrict__ X, G3 g, const float* __restrict__ massf)
{
    const int mt = blockIdx.x, ct = blockIdx.y, z = blockIdx.z;
    const int row0 = mt * 64, c0 = ct * 64;
    const int b = row0 >> 10;
    const float* Wp = g.W[z];
    const float* bias = g.bias[z];
    float* out = g.out[z];
    const size_t woff = PERB ? (size_t)b * KD * 256 : 0;

    __shared__ float xT[32][68];   // 68*4 = 272 B rows (16B-aligned)
    __shared__ float wl[32][64];
    const int t = threadIdx.x, tx = t & 15, ty = t >> 4;
    float acc[4][4] = {};

    for (int k0 = 0; k0 < KD; k0 += 32) {
        {
            const int m = t >> 2, cc0 = (t & 3) * 8;
            const float* xs = X + (size_t)(row0 + m) * KD + k0 + cc0;
            float4 a0 = *(const float4*)xs, a1 = *(const float4*)(xs + 4);
            xT[cc0 + 0][m] = a0.x; xT[cc0 + 1][m] = a0.y; xT[cc0 + 2][m] = a0.z; xT[cc0 + 3][m] = a0.w;
            xT[cc0 + 4][m] = a1.x; xT[cc0 + 5][m] = a1.y; xT[cc0 + 6][m] = a1.z; xT[cc0 + 7][m] = a1.w;
        }
        {
            const int cc = t >> 3, col = (t & 7) * 8;
            const float* wsrc = Wp + woff + (size_t)(k0 + cc) * 256 + c0 + col;
            float4 a0 = *(const float4*)wsrc, a1 = *(const float4*)(wsrc + 4);
            wl[cc][col + 0] = a0.x; wl[cc][col + 1] = a0.y; wl[cc][col + 2] = a0.z; wl[cc][col + 3] = a0.w;
            wl[cc][col + 4] = a1.x; wl[cc][col + 5] = a1.y; wl[cc][col + 6] = a1.z; wl[cc][col + 7] = a1.w;
        }
        __syncthreads();
#pragma unroll 8
        for (int cc = 0; cc < 32; cc++) {
            float4 xv = *(const float4*)&xT[cc][ty * 4];
            float4 wv = *(const float4*)&wl[cc][tx * 4];
            float xa[4] = {xv.x, xv.y, xv.z, xv.w};
            float wa[4] = {wv.x, wv.y, wv.z, wv.w};
#pragma unroll
            for (int i = 0; i < 4; i++)
#pragma unroll
                for (int j = 0; j < 4; j++) acc[i][j] += xa[i] * wa[j];
        }
        __syncthreads();
    }
    float bj[4] = {0.f, 0.f, 0.f, 0.f};
    if (bias) {
#pragma unroll
        for (int j = 0; j < 4; j++) bj[j] = bias[c0 + tx * 4 + j];
    }
#pragma unroll
    for (int i = 0; i < 4; i++) {
        const int row = row0 + ty * 4 + i;
        const float mm = MMASS ? massf[row] : 1.f;
        *(float4*)(out + (size_t)row * 256 + c0 + tx * 4) =
            make_float4((acc[i][0] + bj[0]) * mm, (acc[i][1] + bj[1]) * mm,
                        (acc[i][2] + bj[2]) * mm, (acc[i][3] + bj[3]) * mm);
    }
}

// ---------------------------------------------------------------------------
// GroupNorm stats: per (b, g) mean/invstd over M x 8 channels
// ---------------------------------------------------------------------------
__global__ __launch_bounds__(256) void k_gnstats(const float* __restrict__ xfar, float* __restrict__ gst)
{
    const int b = blockIdx.x >> 5, g = blockIdx.x & 31;
    const int t = threadIdx.x;
    float s = 0.f, s2 = 0.f;
#pragma unroll
    for (int i = 0; i < 4; i++) {
        const int m = t * 4 + i;
        const float* p = xfar + ((size_t)b * Mn + m) * Cn + g * 8;
        float4 a = *(const float4*)p;
        float4 c = *(const float4*)(p + 4);
        s += a.x + a.y + a.z + a.w + c.x + c.y + c.z + c.w;
        s2 += a.x * a.x + a.y * a.y + a.z * a.z + a.w * a.w +
              c.x * c.x + c.y * c.y + c.z * c.z + c.w * c.w;
    }
    __shared__ float sb[256], sb2[256];
    sb[t] = s; sb2[t] = s2;
    __syncthreads();
    for (int o = 128; o > 0; o >>= 1) {
        if (t < o) { sb[t] += sb[t + o]; sb2[t] += sb2[t + o]; }
        __syncthreads();
    }
    if (t == 0) {
        const float mean = sb[0] * (1.f / 8192.f);
        const float var = sb2[0] * (1.f / 8192.f) - mean * mean;
        gst[2 * blockIdx.x] = mean;
        gst[2 * blockIdx.x + 1] = rsqrtf(var + 1e-6f);
    }
}

__global__ __launch_bounds__(256) void k_gnapply(
    const float* __restrict__ xfar, const float* __restrict__ gst,
    const float* __restrict__ gw, const float* __restrict__ gb, float* __restrict__ xn)
{
    const int idx = (blockIdx.x * 256 + threadIdx.x) * 4;
    const int c = idx & 255;
    const int row = idx >> 8;
    const int b = row >> 10;
    const int g = c >> 3;
    const float2 st = *(const float2*)&gst[2 * (b * 32 + g)];
    float4 vv = *(const float4*)&xfar[idx];
    float4 w4 = *(const float4*)&gw[c];
    float4 b4 = *(const float4*)&gb[c];
    float4 o;
    o.x = (vv.x - st.x) * st.y * w4.x + b4.x;
    o.y = (vv.y - st.x) * st.y * w4.y + b4.y;
    o.z = (vv.z - st.x) * st.y * w4.z + b4.z;
    o.w = (vv.w - st.x) * st.y * w4.w + b4.w;
    *(float4*)&xn[idx] = o;
}

// ---------------------------------------------------------------------------
// Flash attention, f16x3 MFMA, single pass over all 1024 keys.
// ---------------------------------------------------------------------------
__global__ __launch_bounds__(256) void k_attn(
    const float* __restrict__ q, const float* __restrict__ kbuf, const float* __restrict__ vbuf,
    float* __restrict__ att)
{
    const int qt = blockIdx.x;      // 16 tiles of 64 q-rows
    const int bh = blockIdx.y;      // b*8 + h
    const int b = bh >> 3, h = bh & 7;
    const int t = threadIdx.x;
    const int lane = t & 63, w = t >> 6;
    const int lr = lane & 15, lg = lane >> 4;

    __shared__ __align__(16) f16 Kh[64][32];     // [key][d] hi
    __shared__ __align__(16) f16 Kl[64][32];     // [key][d] lo
    __shared__ __align__(16) f16 Vh[32][64];     // [d][key] hi, 16B-chunk ^(d&7)
    __shared__ __align__(16) f16 Vl[32][64];     // [d][key] lo
    __shared__ __align__(16) u32 Pw[4][16][68];  // per-wave P (hi,lo) packed

    const size_t base = (size_t)b * Mn * Cn + h * Dn;
    const int q0 = qt * 64;

    f16x8 Qh, Ql;
    {
        const float* qp = q + base + (size_t)(q0 + w * 16 + lr) * Cn + lg * 8;
        f32x4 a0 = *(const f32x4*)qp;
        f32x4 a1 = *(const f32x4*)(qp + 4);
        const float scale = 0.17677669529663687f;
        float qv[8] = {a0[0], a0[1], a0[2], a0[3], a1[0], a1[1], a1[2], a1[3]};
#pragma unroll
        for (int r = 0; r < 8; r++) {
            const float f = qv[r] * scale;
            const f16 hh = (f16)f;
            Qh[r] = hh;
            Ql[r] = (f16)(f - (float)hh);
        }
    }

    const int krow = t >> 2, kdg = (t & 3) * 8;        // K: row, d-offset
    const int vrow = (t & 31) * 2, vdc = (t >> 5) * 4; // V: row-pair base, d-offset

    f32x4 kr0, kr1, va, vb;
    {
        const float* kp = kbuf + base + (size_t)krow * Cn + kdg;
        kr0 = *(const f32x4*)kp; kr1 = *(const f32x4*)(kp + 4);
        const float* vp = vbuf + base + (size_t)vrow * Cn + vdc;
        va = *(const f32x4*)vp; vb = *(const f32x4*)(vp + Cn);
    }

    float m_i[4], l_i[4];
    f32x4 acc[2] = {};
#pragma unroll
    for (int r = 0; r < 4; r++) { m_i[r] = -1e30f; l_i[r] = 0.f; }

#pragma unroll 1
    for (int kt = 0; kt < 16; kt++) {
        asm volatile("" ::: "memory");
        __builtin_amdgcn_s_barrier();   // all waves done reading K/V of tile kt-1

        {
            float kv[8] = {kr0[0], kr0[1], kr0[2], kr0[3], kr1[0], kr1[1], kr1[2], kr1[3]};
            f16x8 hv, lv;
#pragma unroll
            for (int r = 0; r < 8; r++) {
                const f16 hh = (f16)kv[r];
                hv[r] = hh;
                lv[r] = (f16)(kv[r] - (float)hh);
            }
            *(f16x8*)&Kh[krow][kdg] = hv;
            *(f16x8*)&Kl[krow][kdg] = lv;
        }
        {
            float v0[4] = {va[0], va[1], va[2], va[3]};
            float v1[4] = {vb[0], vb[1], vb[2], vb[3]};
#pragma unroll
            for (int j = 0; j < 4; j++) {
                const int d = vdc + j;
                const f16 h0 = (f16)v0[j], h1 = (f16)v1[j];
                const f16 l0 = (f16)(v0[j] - (float)h0), l1 = (f16)(v1[j] - (float)h1);
                const int col = vrow >> 1;                       // u32 col 0..31
                const int idx = (((col >> 2) ^ (d & 7)) << 2) | (col & 3);
                ((u32*)&Vh[d][0])[idx] = packf16(h0, h1);
                ((u32*)&Vl[d][0])[idx] = packf16(l0, l1);
            }
        }
        if (kt < 15) {
            const float* kp = kbuf + base + (size_t)((kt + 1) * 64 + krow) * Cn + kdg;
            kr0 = *(const f32x4*)kp; kr1 = *(const f32x4*)(kp + 4);
            const float* vp = vbuf + base + (size_t)((kt + 1) * 64 + vrow) * Cn + vdc;
            va = *(const f32x4*)vp; vb = *(const f32x4*)(vp + Cn);
        }

        asm volatile("s_waitcnt lgkmcnt(0)" ::: "memory");
        __builtin_amdgcn_sched_barrier(0);
        __builtin_amdgcn_s_barrier();   // K/V tile visible

        f32x4 s[4];
#pragma unroll
        for (int ct = 0; ct < 4; ct++) {
            const f16x8 khi = *(const f16x8*)&Kh[ct * 16 + lr][lg * 8];
            const f16x8 klo = *(const f16x8*)&Kl[ct * 16 + lr][lg * 8];
            f32x4 z = {};
            z = __builtin_amdgcn_mfma_f32_16x16x32_f16(Qh, khi, z, 0, 0, 0);
            z = __builtin_amdgcn_mfma_f32_16x16x32_f16(Qh, klo, z, 0, 0, 0);
            z = __builtin_amdgcn_mfma_f32_16x16x32_f16(Ql, khi, z, 0, 0, 0);
            s[ct] = z;
        }

        float tm[4];
#pragma unroll
        for (int r = 0; r < 4; r++)
            tm[r] = fmaxf(fmaxf(s[0][r], s[1][r]), fmaxf(s[2][r], s[3][r]));
#pragma unroll
        for (int r = 0; r < 4; r++) {
            tm[r] = fmaxf(tm[r], __shfl_xor(tm[r], 1));
            tm[r] = fmaxf(tm[r], __shfl_xor(tm[r], 2));
            tm[r] = fmaxf(tm[r], __shfl_xor(tm[r], 4));
            tm[r] = fmaxf(tm[r], __shfl_xor(tm[r], 8));
        }
        float corr[4], rs[4];
#pragma unroll
        for (int r = 0; r < 4; r++) {
            const float nm = fmaxf(m_i[r], tm[r]);
            corr[r] = __expf(m_i[r] - nm);
            m_i[r] = nm;
            rs[r] = 0.f;
        }
#pragma unroll
        for (int ct = 0; ct < 4; ct++)
#pragma unroll
            for (int r = 0; r < 4; r++) {
                const float p = __expf(s[ct][r] - m_i[r]);
                rs[r] += p;
                const f16 ph = (f16)p;
                const f16 pl = (f16)(p - (float)ph);
                Pw[w][lg * 4 + r][ct * 16 + lr] = packf16(ph, pl);
            }
#pragma unroll
        for (int r = 0; r < 4; r++) {
            rs[r] += __shfl_xor(rs[r], 1);
            rs[r] += __shfl_xor(rs[r], 2);
            rs[r] += __shfl_xor(rs[r], 4);
            rs[r] += __shfl_xor(rs[r], 8);
            l_i[r] = l_i[r] * corr[r] + rs[r];
        }
#pragma unroll
        for (int dt = 0; dt < 2; dt++)
#pragma unroll
            for (int r = 0; r < 4; r++) acc[dt][r] *= corr[r];

        asm volatile("s_waitcnt lgkmcnt(0)" ::: "memory");
        __builtin_amdgcn_sched_barrier(0);

        f16x8 pah[2], pal[2];
#pragma unroll
        for (int kc = 0; kc < 2; kc++) {
            const u32* prow = &Pw[w][lr][0] + kc * 32 + lg * 8;
            u32x4 ua = *(const u32x4*)prow;
            u32x4 ub = *(const u32x4*)(prow + 4);
            union { u32 wd[4]; f16x8 v; } hh, ll;
            hh.wd[0] = __builtin_amdgcn_perm(ua[1], ua[0], 0x05040100u);
            hh.wd[1] = __builtin_amdgcn_perm(ua[3], ua[2], 0x05040100u);
            hh.wd[2] = __builtin_amdgcn_perm(ub[1], ub[0], 0x05040100u);
            hh.wd[3] = __builtin_amdgcn_perm(ub[3], ub[2], 0x05040100u);
            ll.wd[0] = __builtin_amdgcn_perm(ua[1], ua[0], 0x07060302u);
            ll.wd[1] = __builtin_amdgcn_perm(ua[3], ua[2], 0x07060302u);
            ll.wd[2] = __builtin_amdgcn_perm(ub[1], ub[0], 0x07060302u);
            ll.wd[3] = __builtin_amdgcn_perm(ub[3], ub[2], 0x07060302u);
            pah[kc] = hh.v;
            pal[kc] = ll.v;
        }

#pragma unroll
        for (int dt = 0; dt < 2; dt++)
#pragma unroll
            for (int kc = 0; kc < 2; kc++) {
                const int d = dt * 16 + lr;
                const int ch = ((kc * 4 + lg) ^ (lr & 7)) * 8;
                const f16x8 vh = *(const f16x8*)&Vh[d][ch];
                const f16x8 vl = *(const f16x8*)&Vl[d][ch];
                acc[dt] = __builtin_amdgcn_mfma_f32_16x16x32_f16(pah[kc], vh, acc[dt], 0, 0, 0);
                acc[dt] = __builtin_amdgcn_mfma_f32_16x16x32_f16(pah[kc], vl, acc[dt], 0, 0, 0);
                acc[dt] = __builtin_amdgcn_mfma_f32_16x16x32_f16(pal[kc], vh, acc[dt], 0, 0, 0);
            }
    }

#pragma unroll
    for (int r = 0; r < 4; r++) {
        const float inv = 1.f / l_i[r];
        const size_t orow = (size_t)b * Mn + q0 + w * 16 + lg * 4 + r;
#pragma unroll
        for (int dt = 0; dt < 2; dt++)
            att[orow * Cn + h * Dn + dt * 16 + lr] = acc[dt][r] * inv;
    }
}

// ---------------------------------------------------------------------------
// to_basis #2 over far rows only
// ---------------------------------------------------------------------------
__global__ __launch_bounds__(256) void k_tobasis2(
    const float* __restrict__ evf, const float* __restrict__ xo, float* __restrict__ part)
{
    const int mch = blockIdx.x, ct = blockIdx.y, b = blockIdx.z;
    const int m0 = mch * (Mn / MCH);
    const int c0 = ct * 128;
    __shared__ float ev[32][128];
    __shared__ float xm[32][128];
    const int t = threadIdx.x, tx = t & 15, ty = t >> 4;
    float acc[8][8];
#pragma unroll
    for (int i = 0; i < 8; i++)
#pragma unroll
        for (int j = 0; j < 8; j++) acc[i][j] = 0.f;
    const int lr = t >> 3, lc = (t & 7) * 16;
    for (int s = 0; s < Mn / MCH; s += 32) {
        const size_t mrow = (size_t)b * Mn + m0 + s + lr;
        {
            const float* es = evf + mrow * Kn + lc;
            *(float4*)&ev[lr][lc]      = *(const float4*)es;
            *(float4*)&ev[lr][lc + 4]  = *(const float4*)(es + 4);
            *(float4*)&ev[lr][lc + 8]  = *(const float4*)(es + 8);
            *(float4*)&ev[lr][lc + 12] = *(const float4*)(es + 12);
            const float* xs = xo + mrow * Cn + c0 + lc;
            *(float4*)&xm[lr][lc]      = *(const float4*)xs;
            *(float4*)&xm[lr][lc + 4]  = *(const float4*)(xs + 4);
            *(float4*)&xm[lr][lc + 8]  = *(const float4*)(xs + 8);
            *(float4*)&xm[lr][lc + 12] = *(const float4*)(xs + 12);
        }
        __syncthreads();
#pragma unroll 4
        for (int nn = 0; nn < 32; nn++) {
            float4 e0 = *(const float4*)&ev[nn][ty * 4];
            float4 e1 = *(const float4*)&ev[nn][64 + ty * 4];
            float4 x0 = *(const float4*)&xm[nn][tx * 4];
            float4 x1 = *(const float4*)&xm[nn][64 + tx * 4];
            float ee[8] = {e0.x, e0.y, e0.z, e0.w, e1.x, e1.y, e1.z, e1.w};
            float xx[8] = {x0.x, x0.y, x0.z, x0.w, x1.x, x1.y, x1.z, x1.w};
#pragma unroll
            for (int i = 0; i < 8; i++)
#pragma unroll
                for (int j = 0; j < 8; j++) acc[i][j] += ee[i] * xx[j];
        }
        __syncthreads();
    }
    float* dst = part + ((size_t)b * MCH + mch) * (Kn * Cn);
#pragma unroll
    for (int i = 0; i < 8; i++) {
        const int k = (i < 4) ? (ty * 4 + i) : (64 + ty * 4 + i - 4);
        *(float4*)(dst + (size_t)k * Cn + c0 + tx * 4) =
            make_float4(acc[i][0], acc[i][1], acc[i][2], acc[i][3]);
        *(float4*)(dst + (size_t)k * Cn + c0 + 64 + tx * 4) =
            make_float4(acc[i][4], acc[i][5], acc[i][6], acc[i][7]);
    }
}

// ---------------------------------------------------------------------------
// from_basis #2 (f16x3 MFMA, pipelined LDS staging):
// out[b,n,c] = ow[c] * sum_k evecs[b,n,k] * spec2[b,k,c]
// A = evecs rows reg-staged -> f16 hi|lo LDS tiles (chunk^(row&7) swizzle),
// double-buffered; A-prefetch + B-loads issued before the barrier so their
// latency overlaps it. B = specT hi/lo f16 [c][k] direct from global (L2).
// Block 128n x 256c, 512 thr = 8 waves (2n x 4c). K=128 in 4 steps.
// ---------------------------------------------------------------------------
__global__ __launch_bounds__(512) void k_frombasis2(
    const float* __restrict__ evecs, const f16* __restrict__ sTh,
    const f16* __restrict__ sTl, const float* __restrict__ outw,
    float* __restrict__ out)
{
    const int nt = blockIdx.x, b = blockIdx.z;
    const int n0 = nt * 128;
    const int t = threadIdx.x;
    const int lane = t & 63, w = t >> 6;
    const int lr = lane & 15, lg = lane >> 4;
    const int wn = (w & 1) * 64;        // n-offset within block
    const int wc = (w >> 1) * 64;       // c-offset

    __shared__ __align__(16) f16 aT[2][128][64];   // 32 KB, hi|lo interleaved

    // staging role: thread -> (row, 8-float k-chunk)
    const int srow = t >> 2;        // 0..127
    const int skc = t & 3;          // 0..3
    const float* Abase = evecs + ((size_t)b * Nn + n0 + srow) * Kn + skc * 8;

    const f16* Bh = sTh + ((size_t)b * 256 + wc + lr) * Kn + lg * 8;
    const f16* Bl = sTl + ((size_t)b * 256 + wc + lr) * Kn + lg * 8;

    f32x4 acc[4][4] = {};

    // prefetch A for kk=0
    f32x4 a0 = *(const f32x4*)(Abase);
    f32x4 a1 = *(const f32x4*)(Abase + 4);

#pragma unroll 1
    for (int kk = 0; kk < 4; kk++) {
        const int p = kk & 1;
        // convert in-flight A regs -> aT[p] (compiler waits vmcnt for a0/a1)
        {
            float av[8] = {a0[0], a0[1], a0[2], a0[3], a1[0], a1[1], a1[2], a1[3]};
            f16x8 hv, lv;
#pragma unroll
            for (int r = 0; r < 8; r++) {
                const float f = av[r] * 256.f;   // exact scale: lo stays normal
                const f16 hh = (f16)f;
                hv[r] = hh;
                lv[r] = (f16)(f - (float)hh);
            }
            *(f16x8*)&aT[p][srow][((skc) ^ (srow & 7)) * 8] = hv;
            *(f16x8*)&aT[p][srow][((4 + skc) ^ (srow & 7)) * 8] = lv;
        }
        // prefetch A for kk+1 (latency hidden under barrier + MFMA)
        if (kk < 3) {
            a0 = *(const f32x4*)(Abase + (kk + 1) * 32);
            a1 = *(const f32x4*)(Abase + (kk + 1) * 32 + 4);
        }
        // B loads for this step (L2-resident; issued before barrier)
        f16x8 bh[4], bl[4];
#pragma unroll
        for (int cf = 0; cf < 4; cf++) {
            bh[cf] = *(const f16x8*)(Bh + (size_t)cf * 16 * Kn + kk * 32);
            bl[cf] = *(const f16x8*)(Bl + (size_t)cf * 16 * Kn + kk * 32);
        }

        asm volatile("s_waitcnt lgkmcnt(0)" ::: "memory");
        __builtin_amdgcn_sched_barrier(0);
        __builtin_amdgcn_s_barrier();   // aT[p] visible to all waves

        // frag reads (swizzled, conflict-free) + MFMA
#pragma unroll
        for (int rf = 0; rf < 4; rf++) {
            const int rn = wn + rf * 16 + lr;
            const f16x8 ah = *(const f16x8*)&aT[p][rn][((lg) ^ (rn & 7)) * 8];
            const f16x8 al = *(const f16x8*)&aT[p][rn][((4 + lg) ^ (rn & 7)) * 8];
#pragma unroll
            for (int cf = 0; cf < 4; cf++) {
                acc[rf][cf] = __builtin_amdgcn_mfma_f32_16x16x32_f16(ah, bh[cf], acc[rf][cf], 0, 0, 0);
                acc[rf][cf] = __builtin_amdgcn_mfma_f32_16x16x32_f16(ah, bl[cf], acc[rf][cf], 0, 0, 0);
                acc[rf][cf] = __builtin_amdgcn_mfma_f32_16x16x32_f16(al, bh[cf], acc[rf][cf], 0, 0, 0);
            }
        }
    }

    float ow4[4];
#pragma unroll
    for (int cf = 0; cf < 4; cf++)
        ow4[cf] = fmaxf(outw[wc + cf * 16 + lr], 1e-8f) * (1.f / 256.f);
#pragma unroll
    for (int rf = 0; rf < 4; rf++)
#pragma unroll
        for (int cf = 0; cf < 4; cf++) {
            const int nn = n0 + wn + rf * 16 + lg * 4;
            const int c = wc + cf * 16 + lr;
#pragma unroll
            for (int r = 0; r < 4; r++)
                out[((size_t)b * Nn + nn + r) * Cn + c] = acc[rf][cf][r] * ow4[cf];
        }
}

// ---------------------------------------------------------------------------
extern "C" void kernel_launch(void* const* d_in, const int* in_sizes, int n_in,
                              void* d_out, int out_size, void* d_ws, size_t ws_size,
                              hipStream_t stream)
{
    const float* x     = (const float*)d_in[0];
    const float* mass  = (const float*)d_in[1];
    const float* evals = (const float*)d_in[2];
    const float* evecs = (const float*)d_in[3];
    const int*   far   = (const int*)d_in[4];
    const float* t_in  = (const float*)d_in[5];
    const float* t_out = (const float*)d_in[6];
    const float* gn_w  = (const float*)d_in[7];
    const float* gn_b  = (const float*)d_in[8];
    const float* Wq    = (const float*)d_in[9];
    const float* bq    = (const float*)d_in[10];
    const float* Wk    = (const float*)d_in[11];
    const float* bk    = (const float*)d_in[12];
    const float* Wv    = (const float*)d_in[13];
    const float* bv    = (const float*)d_in[14];
    const float* Wo    = (const float*)d_in[15];
    const float* bo    = (const float*)d_in[16];
    const float* outw  = (const float*)d_in[17];
    float* out = (float*)d_out;
    float* ws = (float*)d_ws;

    // --- Lifetime-aliased workspace layout (same offsets as rounds 5-9).
    //     pm slot (1 MB) hosts the specT f16 hi/lo planes (512 KB used).
    float* A     = ws;                      // 8,388,608
    float* evf   = ws    + 8388608;         //   524,288 (k3..k10)
    float* massf = evf   + 524288;          //     4,096
    float* gst   = massf + 4096;            //       256
    float* pm    = gst   + 256;             //   262,144 (-> specT planes)
    float* pl    = pm    + 262144;          //   262,144 (unused)
    float* spec1 = pl    + 262144;          //   131,072
    float* xfar  = spec1 + 131072;          // 1,048,576
    float* xn    = xfar  + 1048576;         // 1,048,576
    float* q     = xn    + 1048576;         // 1,048,576
    float* kk    = q     + 1048576;         // 1,048,576
    float* v     = kk    + 1048576;         // 1,048,576  (ends at 14,815,488)
    float* part2 = A;
    float* spec2 = spec1;   // spec1 dead after from_basis1
    float* xo    = xfar;    // xfar dead after gnapply
    float* att   = xn;      // xn dead after QKV gemm
    f16* specTh  = (f16*)pm;            // 131072 f16 = 256 KB
    f16* specTl  = specTh + 131072;     // 131072 f16 = 256 KB (fits pm slot)
    (void)pl;

    k_tobasis1<<<dim3(NCH, 1, Bn), 512, 0, stream>>>(x, mass, evecs, A);
    k_reduce<<<Bn * Kn, Cn, 0, stream>>>(A, NCH, evals, t_in, spec1);
    k_gather<<<Bn * Mn, Kn, 0, stream>>>(evecs, mass, far, evf, massf);
    {
        G3 g{};
        g.W[0] = spec1; g.bias[0] = nullptr; g.out[0] = xfar;
        k_gemm64<128, true, false><<<dim3(64, 4, 1), 256, 0, stream>>>(evf, g, nullptr);
    }
    k_gnstats<<<Bn * 32, 256, 0, stream>>>(xfar, gst);
    k_gnapply<<<1024, 256, 0, stream>>>(xfar, gst, gn_w, gn_b, xn);
    {
        G3 g{};
        g.W[0] = Wq; g.W[1] = Wk; g.W[2] = Wv;
        g.bias[0] = bq; g.bias[1] = bk; g.bias[2] = bv;
        g.out[0] = q; g.out[1] = kk; g.out[2] = v;
        k_gemm64<256, false, false><<<dim3(64, 4, 3), 256, 0, stream>>>(xn, g, nullptr);
    }
    k_attn<<<dim3(16, 32), 256, 0, stream>>>(q, kk, v, att);
    {
        G3 g{};
        g.W[0] = Wo; g.bias[0] = bo; g.out[0] = xo;
        k_gemm64<256, false, true><<<dim3(64, 4, 1), 256, 0, stream>>>(att, g, massf);
    }
    k_tobasis2<<<dim3(MCH, 2, Bn), 256, 0, stream>>>(evf, xo, part2);
    k_reduce<<<Bn * Kn, Cn, 0, stream>>>(part2, MCH, evals, t_out, spec2);
    k_spectr<<<dim3(4, Bn), 256, 0, stream>>>(spec2, specTh, specTl);
    k_frombasis2<<<dim3(256, 1, Bn), 512, 0, stream>>>(evecs, specTh, specTl, outw, out);
}

// Round 7
// 503.994 us; speedup vs baseline: 1.2919x; 1.0044x over previous
//
#include <hip/hip_runtime.h>
#include <hip/hip_bf16.h>

// All inputs and the output are fp32 (established empirically in rounds 1-2).
// Workspace layout is lifetime-aliased (high-water 56.5 MiB; see round-5 note).
//
// ROUND 12: k_tobasis1 take 3 -- occupancy fix (2 blocks/CU).
//   Round-7/11 version: 95 us, MfmaUtil 10.5 / VALU 8.8 / hbm 17.8 / occ 19.8,
//   bank-conflicts 0.  LDS was 149.5 KB -> 1 block/CU, 2 waves/SIMD: every
//   phase stall (vmcnt wait, barriers, lgkm drain) fully exposed -- no
//   independent waves to overlap (m114 mechanism). 228k cy/block vs ~77k of
//   HBM+work. Fix: LDS 149.5 -> 64 KB = 2 blocks/CU:
//   (1) x fp32 scratch (64 KB) dropped -- x reg-staged (fb2/attn pattern),
//       transposed u32 n-pair writes, swizzle ch^((c>>3)&7) (write 4-way
//       @1.58x, read ~2-way free). ev path byte-identical (0 conflicts).
//   (2) ev scratch single-buffered (16 KB): s+1 gloads issue post-B2, reads
//       complete pre-B2 -- no hazard.
//   (3) __launch_bounds__(512,4) pins VGPR <=128 for 4 waves/SIMD.
//   Predicted: ~45-55 us, occ ~40%, hbm ~33%.
//   History: tb1 f16x3 (r7) ~95; attn (r8) ~45; fb2 (r9) 93 -> (r10) ~60.

#define Bn 4
#define Nn 32768
#define Kn 128
#define Cn 256
#define Mn 1024
#define Hn 8
#define Dn 32
#define NCH 64   // n-chunks for to_basis1 (chunk = 512 rows)
#define MCH 16   // m-chunks for to_basis2 (chunk = 64 rows)

typedef _Float16 f16;
typedef _Float16 f16x8 __attribute__((ext_vector_type(8)));
typedef float f32x4 __attribute__((ext_vector_type(4)));
typedef float f32x2 __attribute__((ext_vector_type(2)));
typedef unsigned int u32;
typedef unsigned int u32x4 __attribute__((ext_vector_type(4)));

__device__ __forceinline__ void gload_lds16(const float* g, float* l) {
    __builtin_amdgcn_global_load_lds(
        (const __attribute__((address_space(1))) void*)g,
        (__attribute__((address_space(3))) void*)l, 16, 0, 0);
}

static __device__ __forceinline__ u32 packf16(f16 a, f16 b) {
    union { f16 h[2]; u32 u; } x;
    x.h[0] = a; x.h[1] = b;
    return x.u;
}

// ---------------------------------------------------------------------------
// K1: to_basis #1 (f16x3 MFMA, 2 blocks/CU).
// part[b][nch][k][c] = sum_{n in chunk} evecs[b,n,k] * x[b,n,c]*mass[b,n]
// 512 thr = 8 waves (2 k-halves x 4 c-qtrs), 16 strips of 32 rows.
// LDS 64 KB: evS 16 (fp32 scratch, single-buf) + evT 16 + xT 32.
// ---------------------------------------------------------------------------
__global__ __launch_bounds__(512, 4) void k_tobasis1(
    const float* __restrict__ x, const float* __restrict__ mass,
    const float* __restrict__ evecs, float* __restrict__ part)
{
    const int nch = blockIdx.x, b = blockIdx.z;
    const int n0 = nch * (Nn / NCH);
    const int t = threadIdx.x;
    const int lane = t & 63, w = t >> 6;
    const int lr = lane & 15, lg = lane >> 4;
    const int wm = (w & 1) * 64;        // k-offset (basis rows)
    const int wc = (w >> 1) * 64;       // c-offset

    __shared__ __align__(16) float evS[32][128];      // 16 KB fp32 scratch
    __shared__ __align__(16) f16 evT[128][64];        // 16 KB hi|lo, ^(k&7)
    __shared__ __align__(16) f16 xT[256][64];         // 32 KB hi|lo, ^((c>>3)&7)

    const size_t rb0 = (size_t)b * Nn + n0;
    const float* ebase = evecs + rb0 * Kn;
    const float* xbase = x + rb0 * Cn;
    const float* mbase = mass + rb0;

    // x staging role: thread -> rows (2np, 2np+1), c-slice cc*8..+7
    const int cc = t & 31, np = t >> 5;

    f32x4 acc[4][4] = {};

    // prologue: strip 0 (ev -> LDS scratch via gload; x + mass -> regs)
#pragma unroll
    for (int iw = 0; iw < 2; iw++)
        gload_lds16(ebase + (w * 2 + iw) * 256 + lane * 4, &evS[0][0] + (w * 2 + iw) * 256);
    f32x4 xa0, xa1, xb0, xb1;
    f32x2 mreg;
    {
        const float* xp = xbase + (size_t)(np * 2) * Cn + cc * 8;
        xa0 = *(const f32x4*)xp;       xa1 = *(const f32x4*)(xp + 4);
        xb0 = *(const f32x4*)(xp + Cn); xb1 = *(const f32x4*)(xp + Cn + 4);
        mreg = *(const f32x2*)(mbase + np * 2);
    }

    for (int s = 0; s < 16; s++) {
        // ev gloads + x reg-loads for strip s all complete here.
        asm volatile("s_waitcnt vmcnt(0)" ::: "memory");
        __builtin_amdgcn_sched_barrier(0);
        __builtin_amdgcn_s_barrier();   // B1: tiles of s-1 fully read by all

        // transpose+split ev: evS -> evT  (swizzle ch ^ (k&7), measured 0-conflict)
        {
            const int k = t & 127;
            const int g = t >> 7;          // wave-uniform
            f16x8 hv, lv;
#pragma unroll
            for (int r = 0; r < 8; r++) {
                const float f = evS[g * 8 + r][k];
                const f16 h = (f16)f;
                hv[r] = h;
                lv[r] = (f16)(f - (float)h);
            }
            *(f16x8*)&evT[k][((g) ^ (k & 7)) * 8] = hv;
            *(f16x8*)&evT[k][((4 + g) ^ (k & 7)) * 8] = lv;
        }
        // convert x regs * mass -> xT transposed u32 n-pair writes
        // (swizzle ch ^ ((c>>3)&7); write 4-way, read ~2-way)
        {
            const float m0 = mreg[0], m1 = mreg[1];
            float r0[8] = {xa0[0]*m0, xa0[1]*m0, xa0[2]*m0, xa0[3]*m0,
                           xa1[0]*m0, xa1[1]*m0, xa1[2]*m0, xa1[3]*m0};
            float r1[8] = {xb0[0]*m1, xb0[1]*m1, xb0[2]*m1, xb0[3]*m1,
                           xb1[0]*m1, xb1[1]*m1, xb1[2]*m1, xb1[3]*m1};
#pragma unroll
            for (int j = 0; j < 8; j++) {
                const int c = cc * 8 + j;
                const int g = (c >> 3) & 7;
                const f16 h0 = (f16)r0[j], h1 = (f16)r1[j];
                const f16 l0 = (f16)(r0[j] - (float)h0), l1 = (f16)(r1[j] - (float)h1);
                u32* row = (u32*)&xT[c][0];
                row[((((np >> 2)    ) ^ g) << 2) | (np & 3)] = packf16(h0, h1);
                row[((((np >> 2) + 4) ^ g) << 2) | (np & 3)] = packf16(l0, l1);
            }
        }

        asm volatile("s_waitcnt lgkmcnt(0)" ::: "memory");
        __builtin_amdgcn_sched_barrier(0);
        __builtin_amdgcn_s_barrier();   // B2: tiles visible; evS fully consumed

        // stage strip s+1 (ev gloads into evS; x + mass into regs)
        if (s < 15) {
            const float* eb = ebase + (size_t)(s + 1) * 32 * Kn;
#pragma unroll
            for (int iw = 0; iw < 2; iw++)
                gload_lds16(eb + (w * 2 + iw) * 256 + lane * 4, &evS[0][0] + (w * 2 + iw) * 256);
            const float* xp = xbase + (size_t)((s + 1) * 32 + np * 2) * Cn + cc * 8;
            xa0 = *(const f32x4*)xp;       xa1 = *(const f32x4*)(xp + 4);
            xb0 = *(const f32x4*)(xp + Cn); xb1 = *(const f32x4*)(xp + Cn + 4);
            mreg = *(const f32x2*)(mbase + (s + 1) * 32 + np * 2);
        }

        // frag reads + MFMA
        f16x8 aH[4], aL[4], bH[4], bL[4];
#pragma unroll
        for (int i = 0; i < 4; i++) {
            const int rk = wm + i * 16 + lr;
            aH[i] = *(const f16x8*)&evT[rk][((lg) ^ (rk & 7)) * 8];
            aL[i] = *(const f16x8*)&evT[rk][((4 + lg) ^ (rk & 7)) * 8];
            const int rc = wc + i * 16 + lr;
            const int gg = (rc >> 3) & 7;
            bH[i] = *(const f16x8*)&xT[rc][((lg) ^ gg) * 8];
            bL[i] = *(const f16x8*)&xT[rc][((4 + lg) ^ gg) * 8];
        }
#pragma unroll
        for (int i = 0; i < 4; i++)
#pragma unroll
            for (int j = 0; j < 4; j++) {
                acc[i][j] = __builtin_amdgcn_mfma_f32_16x16x32_f16(aH[i], bH[j], acc[i][j], 0, 0, 0);
                acc[i][j] = __builtin_amdgcn_mfma_f32_16x16x32_f16(aH[i], bL[j], acc[i][j], 0, 0, 0);
                acc[i][j] = __builtin_amdgcn_mfma_f32_16x16x32_f16(aL[i], bH[j], acc[i][j], 0, 0, 0);
            }
    }

    // epilogue: C/D layout col=lane&15, row=(lane>>4)*4+reg  [m89]
    float* dst = part + ((size_t)b * NCH + nch) * (Kn * Cn);
#pragma unroll
    for (int i = 0; i < 4; i++)
#pragma unroll
        for (int j = 0; j < 4; j++) {
            const int m0 = wm + i * 16 + lg * 4;
            const int c = wc + j * 16 + lr;
#pragma unroll
            for (int r = 0; r < 4; r++)
                dst[(size_t)(m0 + r) * Cn + c] = acc[i][j][r];
        }
}

// ---------------------------------------------------------------------------
// Reduce chunk partials and apply heat coefficient exp(-eval * t_c)
// ---------------------------------------------------------------------------
__global__ __launch_bounds__(256) void k_reduce(
    const float* __restrict__ part, int nchunks,
    const float* __restrict__ evals, const float* __restrict__ tvec,
    float* __restrict__ spec)
{
    const int b = blockIdx.x >> 7, k = blockIdx.x & 127, c = threadIdx.x;
    float ssum = 0.f;
    const float* p = part + ((size_t)b * nchunks * Kn + k) * Cn + c;
    for (int j = 0; j < nchunks; j++) ssum += p[(size_t)j * Kn * Cn];
    const float lam = evals[b * Kn + k];
    const float tt = fmaxf(tvec[c], 1e-8f);
    spec[((size_t)b * Kn + k) * Cn + c] = ssum * __expf(-lam * tt);
}

// ---------------------------------------------------------------------------
// Transpose+split spec2 fp32 [b][k][c] -> specT hi/lo f16 [b][c][k]
// ---------------------------------------------------------------------------
__global__ __launch_bounds__(256) void k_spectr(
    const float* __restrict__ spec, f16* __restrict__ sTh, f16* __restrict__ sTl)
{
    const int kc = blockIdx.x, b = blockIdx.y;
    const int t = threadIdx.x;
    __shared__ f16 lh[32][258];   // odd-dword rows -> conflict-free columns
    __shared__ f16 ll[32][258];
#pragma unroll 8
    for (int k2 = 0; k2 < 32; k2++) {
        const float f = spec[((size_t)b * Kn + kc * 32 + k2) * Cn + t];
        const f16 h = (f16)f;
        lh[k2][t] = h;
        ll[k2][t] = (f16)(f - (float)h);
    }
    __syncthreads();
    f16x8 vh[4], vl[4];
#pragma unroll
    for (int q = 0; q < 4; q++)
#pragma unroll
        for (int j = 0; j < 8; j++) { vh[q][j] = lh[q * 8 + j][t]; vl[q][j] = ll[q * 8 + j][t]; }
    f16* dh = sTh + ((size_t)b * 256 + t) * Kn + kc * 32;
    f16* dl = sTl + ((size_t)b * 256 + t) * Kn + kc * 32;
#pragma unroll
    for (int q = 0; q < 4; q++) {
        *(f16x8*)(dh + q * 8) = vh[q];
        *(f16x8*)(dl + q * 8) = vl[q];
    }
}

// ---------------------------------------------------------------------------
// Gather evecs & mass at far indices
// ---------------------------------------------------------------------------
__global__ __launch_bounds__(128) void k_gather(
    const float* __restrict__ evecs, const float* __restrict__ mass,
    const int* __restrict__ far, float* __restrict__ evf, float* __restrict__ massf)
{
    const int row = blockIdx.x;  // b*M + m
    const int b = row >> 10;
    const int idx = far[row];
    const int t = threadIdx.x;
    evf[(size_t)row * Kn + t] = evecs[((size_t)b * Nn + idx) * Kn + t];
    if (t == 0) massf[row] = mass[(size_t)b * Nn + idx];
}

// ---------------------------------------------------------------------------
// Generic 64x64-tile GEMM: out[row][c'] = X[row][0:KD] @ W[KD][256] (+bias)(*mass)
// ---------------------------------------------------------------------------
struct G3 {
    const float* W[3];
    const float* bias[3];
    float* out[3];
};

template<int KD, bool PERB, bool MMASS>
__global__ __launch_bounds__(256) void k_gemm64(
    const float* __restrict__ X, G3 g, const float* __restrict__ massf)
{
    const int mt = blockIdx.x, ct = blockIdx.y, z = blockIdx.z;
    const int row0 = mt * 64, c0 = ct * 64;
    const int b = row0 >> 10;
    const float* Wp = g.W[z];
    const float* bias = g.bias[z];
    float* out = g.out[z];
    const size_t woff = PERB ? (size_t)b * KD * 256 : 0;

    __shared__ float xT[32][68];   // 68*4 = 272 B rows (16B-aligned)
    __shared__ float wl[32][64];
    const int t = threadIdx.x, tx = t & 15, ty = t >> 4;
    float acc[4][4] = {};

    for (int k0 = 0; k0 < KD; k0 += 32) {
        {
            const int m = t >> 2, cc0 = (t & 3) * 8;
            const float* xs = X + (size_t)(row0 + m) * KD + k0 + cc0;
            float4 a0 = *(const float4*)xs, a1 = *(const float4*)(xs + 4);
            xT[cc0 + 0][m] = a0.x; xT[cc0 + 1][m] = a0.y; xT[cc0 + 2][m] = a0.z; xT[cc0 + 3][m] = a0.w;
            xT[cc0 + 4][m] = a1.x; xT[cc0 + 5][m] = a1.y; xT[cc0 + 6][m] = a1.z; xT[cc0 + 7][m] = a1.w;
        }
        {
            const int cc = t >> 3, col = (t & 7) * 8;
            const float* wsrc = Wp + woff + (size_t)(k0 + cc) * 256 + c0 + col;
            float4 a0 = *(const float4*)wsrc, a1 = *(const float4*)(wsrc + 4);
            wl[cc][col + 0] = a0.x; wl[cc][col + 1] = a0.y; wl[cc][col + 2] = a0.z; wl[cc][col + 3] = a0.w;
            wl[cc][col + 4] = a1.x; wl[cc][col + 5] = a1.y; wl[cc][col + 6] = a1.z; wl[cc][col + 7] = a1.w;
        }
        __syncthreads();
#pragma unroll 8
        for (int cc = 0; cc < 32; cc++) {
            float4 xv = *(const float4*)&xT[cc][ty * 4];
            float4 wv = *(const float4*)&wl[cc][tx * 4];
            float xa[4] = {xv.x, xv.y, xv.z, xv.w};
            float wa[4] = {wv.x, wv.y, wv.z, wv.w};
#pragma unroll
            for (int i = 0; i < 4; i++)
#pragma unroll
                for (int j = 0; j < 4; j++) acc[i][j] += xa[i] * wa[j];
        }
        __syncthreads();
    }
    float bj[4] = {0.f, 0.f, 0.f, 0.f};
    if (bias) {
#pragma unroll
        for (int j = 0; j < 4; j++) bj[j] = bias[c0 + tx * 4 + j];
    }
#pragma unroll
    for (int i = 0; i < 4; i++) {
        const int row = row0 + ty * 4 + i;
        const float mm = MMASS ? massf[row] : 1.f;
        *(float4*)(out + (size_t)row * 256 + c0 + tx * 4) =
            make_float4((acc[i][0] + bj[0]) * mm, (acc[i][1] + bj[1]) * mm,
                        (acc[i][2] + bj[2]) * mm, (acc[i][3] + bj[3]) * mm);
    }
}

// ---------------------------------------------------------------------------
// GroupNorm stats: per (b, g) mean/invstd over M x 8 channels
// ---------------------------------------------------------------------------
__global__ __launch_bounds__(256) void k_gnstats(const float* __restrict__ xfar, float* __restrict__ gst)
{
    const int b = blockIdx.x >> 5, g = blockIdx.x & 31;
    const int t = threadIdx.x;
    float s = 0.f, s2 = 0.f;
#pragma unroll
    for (int i = 0; i < 4; i++) {
        const int m = t * 4 + i;
        const float* p = xfar + ((size_t)b * Mn + m) * Cn + g * 8;
        float4 a = *(const float4*)p;
        float4 c = *(const float4*)(p + 4);
        s += a.x + a.y + a.z + a.w + c.x + c.y + c.z + c.w;
        s2 += a.x * a.x + a.y * a.y + a.z * a.z + a.w * a.w +
              c.x * c.x + c.y * c.y + c.z * c.z + c.w * c.w;
    }
    __shared__ float sb[256], sb2[256];
    sb[t] = s; sb2[t] = s2;
    __syncthreads();
    for (int o = 128; o > 0; o >>= 1) {
        if (t < o) { sb[t] += sb[t + o]; sb2[t] += sb2[t + o]; }
        __syncthreads();
    }
    if (t == 0) {
        const float mean = sb[0] * (1.f / 8192.f);
        const float var = sb2[0] * (1.f / 8192.f) - mean * mean;
        gst[2 * blockIdx.x] = mean;
        gst[2 * blockIdx.x + 1] = rsqrtf(var + 1e-6f);
    }
}

__global__ __launch_bounds__(256) void k_gnapply(
    const float* __restrict__ xfar, const float* __restrict__ gst,
    const float* __restrict__ gw, const float* __restrict__ gb, float* __restrict__ xn)
{
    const int idx = (blockIdx.x * 256 + threadIdx.x) * 4;
    const int c = idx & 255;
    const int row = idx >> 8;
    const int b = row >> 10;
    const int g = c >> 3;
    const float2 st = *(const float2*)&gst[2 * (b * 32 + g)];
    float4 vv = *(const float4*)&xfar[idx];
    float4 w4 = *(const float4*)&gw[c];
    float4 b4 = *(const float4*)&gb[c];
    float4 o;
    o.x = (vv.x - st.x) * st.y * w4.x + b4.x;
    o.y = (vv.y - st.x) * st.y * w4.y + b4.y;
    o.z = (vv.z - st.x) * st.y * w4.z + b4.z;
    o.w = (vv.w - st.x) * st.y * w4.w + b4.w;
    *(float4*)&xn[idx] = o;
}

// ---------------------------------------------------------------------------
// Flash attention, f16x3 MFMA, single pass over all 1024 keys.
// ---------------------------------------------------------------------------
__global__ __launch_bounds__(256) void k_attn(
    const float* __restrict__ q, const float* __restrict__ kbuf, const float* __restrict__ vbuf,
    float* __restrict__ att)
{
    const int qt = blockIdx.x;      // 16 tiles of 64 q-rows
    const int bh = blockIdx.y;      // b*8 + h
    const int b = bh >> 3, h = bh & 7;
    const int t = threadIdx.x;
    const int lane = t & 63, w = t >> 6;
    const int lr = lane & 15, lg = lane >> 4;

    __shared__ __align__(16) f16 Kh[64][32];     // [key][d] hi
    __shared__ __align__(16) f16 Kl[64][32];     // [key][d] lo
    __shared__ __align__(16) f16 Vh[32][64];     // [d][key] hi, 16B-chunk ^(d&7)
    __shared__ __align__(16) f16 Vl[32][64];     // [d][key] lo
    __shared__ __align__(16) u32 Pw[4][16][68];  // per-wave P (hi,lo) packed

    const size_t base = (size_t)b * Mn * Cn + h * Dn;
    const int q0 = qt * 64;

    f16x8 Qh, Ql;
    {
        const float* qp = q + base + (size_t)(q0 + w * 16 + lr) * Cn + lg * 8;
        f32x4 a0 = *(const f32x4*)qp;
        f32x4 a1 = *(const f32x4*)(qp + 4);
        const float scale = 0.17677669529663687f;
        float qv[8] = {a0[0], a0[1], a0[2], a0[3], a1[0], a1[1], a1[2], a1[3]};
#pragma unroll
        for (int r = 0; r < 8; r++) {
            const float f = qv[r] * scale;
            const f16 hh = (f16)f;
            Qh[r] = hh;
            Ql[r] = (f16)(f - (float)hh);
        }
    }

    const int krow = t >> 2, kdg = (t & 3) * 8;        // K: row, d-offset
    const int vrow = (t & 31) * 2, vdc = (t >> 5) * 4; // V: row-pair base, d-offset

    f32x4 kr0, kr1, va, vb;
    {
        const float* kp = kbuf + base + (size_t)krow * Cn + kdg;
        kr0 = *(const f32x4*)kp; kr1 = *(const f32x4*)(kp + 4);
        const float* vp = vbuf + base + (size_t)vrow * Cn + vdc;
        va = *(const f32x4*)vp; vb = *(const f32x4*)(vp + Cn);
    }

    float m_i[4], l_i[4];
    f32x4 acc[2] = {};
#pragma unroll
    for (int r = 0; r < 4; r++) { m_i[r] = -1e30f; l_i[r] = 0.f; }

#pragma unroll 1
    for (int kt = 0; kt < 16; kt++) {
        asm volatile("" ::: "memory");
        __builtin_amdgcn_s_barrier();   // all waves done reading K/V of tile kt-1

        {
            float kv[8] = {kr0[0], kr0[1], kr0[2], kr0[3], kr1[0], kr1[1], kr1[2], kr1[3]};
            f16x8 hv, lv;
#pragma unroll
            for (int r = 0; r < 8; r++) {
                const f16 hh = (f16)kv[r];
                hv[r] = hh;
                lv[r] = (f16)(kv[r] - (float)hh);
            }
            *(f16x8*)&Kh[krow][kdg] = hv;
            *(f16x8*)&Kl[krow][kdg] = lv;
        }
        {
            float v0[4] = {va[0], va[1], va[2], va[3]};
            float v1[4] = {vb[0], vb[1], vb[2], vb[3]};
#pragma unroll
            for (int j = 0; j < 4; j++) {
                const int d = vdc + j;
                const f16 h0 = (f16)v0[j], h1 = (f16)v1[j];
                const f16 l0 = (f16)(v0[j] - (float)h0), l1 = (f16)(v1[j] - (float)h1);
                const int col = vrow >> 1;                       // u32 col 0..31
                const int idx = (((col >> 2) ^ (d & 7)) << 2) | (col & 3);
                ((u32*)&Vh[d][0])[idx] = packf16(h0, h1);
                ((u32*)&Vl[d][0])[idx] = packf16(l0, l1);
            }
        }
        if (kt < 15) {
            const float* kp = kbuf + base + (size_t)((kt + 1) * 64 + krow) * Cn + kdg;
            kr0 = *(const f32x4*)kp; kr1 = *(const f32x4*)(kp + 4);
            const float* vp = vbuf + base + (size_t)((kt + 1) * 64 + vrow) * Cn + vdc;
            va = *(const f32x4*)vp; vb = *(const f32x4*)(vp + Cn);
        }

        asm volatile("s_waitcnt lgkmcnt(0)" ::: "memory");
        __builtin_amdgcn_sched_barrier(0);
        __builtin_amdgcn_s_barrier();   // K/V tile visible

        f32x4 s[4];
#pragma unroll
        for (int ct = 0; ct < 4; ct++) {
            const f16x8 khi = *(const f16x8*)&Kh[ct * 16 + lr][lg * 8];
            const f16x8 klo = *(const f16x8*)&Kl[ct * 16 + lr][lg * 8];
            f32x4 z = {};
            z = __builtin_amdgcn_mfma_f32_16x16x32_f16(Qh, khi, z, 0, 0, 0);
            z = __builtin_amdgcn_mfma_f32_16x16x32_f16(Qh, klo, z, 0, 0, 0);
            z = __builtin_amdgcn_mfma_f32_16x16x32_f16(Ql, khi, z, 0, 0, 0);
            s[ct] = z;
        }

        float tm[4];
#pragma unroll
        for (int r = 0; r < 4; r++)
            tm[r] = fmaxf(fmaxf(s[0][r], s[1][r]), fmaxf(s[2][r], s[3][r]));
#pragma unroll
        for (int r = 0; r < 4; r++) {
            tm[r] = fmaxf(tm[r], __shfl_xor(tm[r], 1));
            tm[r] = fmaxf(tm[r], __shfl_xor(tm[r], 2));
            tm[r] = fmaxf(tm[r], __shfl_xor(tm[r], 4));
            tm[r] = fmaxf(tm[r], __shfl_xor(tm[r], 8));
        }
        float corr[4], rs[4];
#pragma unroll
        for (int r = 0; r < 4; r++) {
            const float nm = fmaxf(m_i[r], tm[r]);
            corr[r] = __expf(m_i[r] - nm);
            m_i[r] = nm;
            rs[r] = 0.f;
        }
#pragma unroll
        for (int ct = 0; ct < 4; ct++)
#pragma unroll
            for (int r = 0; r < 4; r++) {
                const float p = __expf(s[ct][r] - m_i[r]);
                rs[r] += p;
                const f16 ph = (f16)p;
                const f16 pl = (f16)(p - (float)ph);
                Pw[w][lg * 4 + r][ct * 16 + lr] = packf16(ph, pl);
            }
#pragma unroll
        for (int r = 0; r < 4; r++) {
            rs[r] += __shfl_xor(rs[r], 1);
            rs[r] += __shfl_xor(rs[r], 2);
            rs[r] += __shfl_xor(rs[r], 4);
            rs[r] += __shfl_xor(rs[r], 8);
            l_i[r] = l_i[r] * corr[r] + rs[r];
        }
#pragma unroll
        for (int dt = 0; dt < 2; dt++)
#pragma unroll
            for (int r = 0; r < 4; r++) acc[dt][r] *= corr[r];

        asm volatile("s_waitcnt lgkmcnt(0)" ::: "memory");
        __builtin_amdgcn_sched_barrier(0);

        f16x8 pah[2], pal[2];
#pragma unroll
        for (int kc = 0; kc < 2; kc++) {
            const u32* prow = &Pw[w][lr][0] + kc * 32 + lg * 8;
            u32x4 ua = *(const u32x4*)prow;
            u32x4 ub = *(const u32x4*)(prow + 4);
            union { u32 wd[4]; f16x8 v; } hh, ll;
            hh.wd[0] = __builtin_amdgcn_perm(ua[1], ua[0], 0x05040100u);
            hh.wd[1] = __builtin_amdgcn_perm(ua[3], ua[2], 0x05040100u);
            hh.wd[2] = __builtin_amdgcn_perm(ub[1], ub[0], 0x05040100u);
            hh.wd[3] = __builtin_amdgcn_perm(ub[3], ub[2], 0x05040100u);
            ll.wd[0] = __builtin_amdgcn_perm(ua[1], ua[0], 0x07060302u);
            ll.wd[1] = __builtin_amdgcn_perm(ua[3], ua[2], 0x07060302u);
            ll.wd[2] = __builtin_amdgcn_perm(ub[1], ub[0], 0x07060302u);
            ll.wd[3] = __builtin_amdgcn_perm(ub[3], ub[2], 0x07060302u);
            pah[kc] = hh.v;
            pal[kc] = ll.v;
        }

#pragma unroll
        for (int dt = 0; dt < 2; dt++)
#pragma unroll
            for (int kc = 0; kc < 2; kc++) {
                const int d = dt * 16 + lr;
                const int ch = ((kc * 4 + lg) ^ (lr & 7)) * 8;
                const f16x8 vh = *(const f16x8*)&Vh[d][ch];
                const f16x8 vl = *(const f16x8*)&Vl[d][ch];
                acc[dt] = __builtin_amdgcn_mfma_f32_16x16x32_f16(pah[kc], vh, acc[dt], 0, 0, 0);
                acc[dt] = __builtin_amdgcn_mfma_f32_16x16x32_f16(pah[kc], vl, acc[dt], 0, 0, 0);
                acc[dt] = __builtin_amdgcn_mfma_f32_16x16x32_f16(pal[kc], vh, acc[dt], 0, 0, 0);
            }
    }

#pragma unroll
    for (int r = 0; r < 4; r++) {
        const float inv = 1.f / l_i[r];
        const size_t orow = (size_t)b * Mn + q0 + w * 16 + lg * 4 + r;
#pragma unroll
        for (int dt = 0; dt < 2; dt++)
            att[orow * Cn + h * Dn + dt * 16 + lr] = acc[dt][r] * inv;
    }
}

// ---------------------------------------------------------------------------
// to_basis #2 over far rows only
// ---------------------------------------------------------------------------
__global__ __launch_bounds__(256) void k_tobasis2(
    const float* __restrict__ evf, const float* __restrict__ xo, float* __restrict__ part)
{
    const int mch = blockIdx.x, ct = blockIdx.y, b = blockIdx.z;
    const int m0 = mch * (Mn / MCH);
    const int c0 = ct * 128;
    __shared__ float ev[32][128];
    __shared__ float xm[32][128];
    const int t = threadIdx.x, tx = t & 15, ty = t >> 4;
    float acc[8][8];
#pragma unroll
    for (int i = 0; i < 8; i++)
#pragma unroll
        for (int j = 0; j < 8; j++) acc[i][j] = 0.f;
    const int lr = t >> 3, lc = (t & 7) * 16;
    for (int s = 0; s < Mn / MCH; s += 32) {
        const size_t mrow = (size_t)b * Mn + m0 + s + lr;
        {
            const float* es = evf + mrow * Kn + lc;
            *(float4*)&ev[lr][lc]      = *(const float4*)es;
            *(float4*)&ev[lr][lc + 4]  = *(const float4*)(es + 4);
            *(float4*)&ev[lr][lc + 8]  = *(const float4*)(es + 8);
            *(float4*)&ev[lr][lc + 12] = *(const float4*)(es + 12);
            const float* xs = xo + mrow * Cn + c0 + lc;
            *(float4*)&xm[lr][lc]      = *(const float4*)xs;
            *(float4*)&xm[lr][lc + 4]  = *(const float4*)(xs + 4);
            *(float4*)&xm[lr][lc + 8]  = *(const float4*)(xs + 8);
            *(float4*)&xm[lr][lc + 12] = *(const float4*)(xs + 12);
        }
        __syncthreads();
#pragma unroll 4
        for (int nn = 0; nn < 32; nn++) {
            float4 e0 = *(const float4*)&ev[nn][ty * 4];
            float4 e1 = *(const float4*)&ev[nn][64 + ty * 4];
            float4 x0 = *(const float4*)&xm[nn][tx * 4];
            float4 x1 = *(const float4*)&xm[nn][64 + tx * 4];
            float ee[8] = {e0.x, e0.y, e0.z, e0.w, e1.x, e1.y, e1.z, e1.w};
            float xx[8] = {x0.x, x0.y, x0.z, x0.w, x1.x, x1.y, x1.z, x1.w};
#pragma unroll
            for (int i = 0; i < 8; i++)
#pragma unroll
                for (int j = 0; j < 8; j++) acc[i][j] += ee[i] * xx[j];
        }
        __syncthreads();
    }
    float* dst = part + ((size_t)b * MCH + mch) * (Kn * Cn);
#pragma unroll
    for (int i = 0; i < 8; i++) {
        const int k = (i < 4) ? (ty * 4 + i) : (64 + ty * 4 + i - 4);
        *(float4*)(dst + (size_t)k * Cn + c0 + tx * 4) =
            make_float4(acc[i][0], acc[i][1], acc[i][2], acc[i][3]);
        *(float4*)(dst + (size_t)k * Cn + c0 + 64 + tx * 4) =
            make_float4(acc[i][4], acc[i][5], acc[i][6], acc[i][7]);
    }
}

// ---------------------------------------------------------------------------
// from_basis #2 (f16x3 MFMA, pipelined LDS staging):
// out[b,n,c] = ow[c] * sum_k evecs[b,n,k] * spec2[b,k,c]
// ---------------------------------------------------------------------------
__global__ __launch_bounds__(512) void k_frombasis2(
    const float* __restrict__ evecs, const f16* __restrict__ sTh,
    const f16* __restrict__ sTl, const float* __restrict__ outw,
    float* __restrict__ out)
{
    const int nt = blockIdx.x, b = blockIdx.z;
    const int n0 = nt * 128;
    const int t = threadIdx.x;
    const int lane = t & 63, w = t >> 6;
    const int lr = lane & 15, lg = lane >> 4;
    const int wn = (w & 1) * 64;        // n-offset within block
    const int wc = (w >> 1) * 64;       // c-offset

    __shared__ __align__(16) f16 aT[2][128][64];   // 32 KB, hi|lo interleaved

    const int srow = t >> 2;        // 0..127
    const int skc = t & 3;          // 0..3
    const float* Abase = evecs + ((size_t)b * Nn + n0 + srow) * Kn + skc * 8;

    const f16* Bh = sTh + ((size_t)b * 256 + wc + lr) * Kn + lg * 8;
    const f16* Bl = sTl + ((size_t)b * 256 + wc + lr) * Kn + lg * 8;

    f32x4 acc[4][4] = {};

    f32x4 a0 = *(const f32x4*)(Abase);
    f32x4 a1 = *(const f32x4*)(Abase + 4);

#pragma unroll 1
    for (int kk = 0; kk < 4; kk++) {
        const int p = kk & 1;
        {
            float av[8] = {a0[0], a0[1], a0[2], a0[3], a1[0], a1[1], a1[2], a1[3]};
            f16x8 hv, lv;
#pragma unroll
            for (int r = 0; r < 8; r++) {
                const float f = av[r] * 256.f;   // exact scale: lo stays normal
                const f16 hh = (f16)f;
                hv[r] = hh;
                lv[r] = (f16)(f - (float)hh);
            }
            *(f16x8*)&aT[p][srow][((skc) ^ (srow & 7)) * 8] = hv;
            *(f16x8*)&aT[p][srow][((4 + skc) ^ (srow & 7)) * 8] = lv;
        }
        if (kk < 3) {
            a0 = *(const f32x4*)(Abase + (kk + 1) * 32);
            a1 = *(const f32x4*)(Abase + (kk + 1) * 32 + 4);
        }
        f16x8 bh[4], bl[4];
#pragma unroll
        for (int cf = 0; cf < 4; cf++) {
            bh[cf] = *(const f16x8*)(Bh + (size_t)cf * 16 * Kn + kk * 32);
            bl[cf] = *(const f16x8*)(Bl + (size_t)cf * 16 * Kn + kk * 32);
        }

        asm volatile("s_waitcnt lgkmcnt(0)" ::: "memory");
        __builtin_amdgcn_sched_barrier(0);
        __builtin_amdgcn_s_barrier();   // aT[p] visible to all waves

#pragma unroll
        for (int rf = 0; rf < 4; rf++) {
            const int rn = wn + rf * 16 + lr;
            const f16x8 ah = *(const f16x8*)&aT[p][rn][((lg) ^ (rn & 7)) * 8];
            const f16x8 al = *(const f16x8*)&aT[p][rn][((4 + lg) ^ (rn & 7)) * 8];
#pragma unroll
            for (int cf = 0; cf < 4; cf++) {
                acc[rf][cf] = __builtin_amdgcn_mfma_f32_16x16x32_f16(ah, bh[cf], acc[rf][cf], 0, 0, 0);
                acc[rf][cf] = __builtin_amdgcn_mfma_f32_16x16x32_f16(ah, bl[cf], acc[rf][cf], 0, 0, 0);
                acc[rf][cf] = __builtin_amdgcn_mfma_f32_16x16x32_f16(al, bh[cf], acc[rf][cf], 0, 0, 0);
            }
        }
    }

    float ow4[4];
#pragma unroll
    for (int cf = 0; cf < 4; cf++)
        ow4[cf] = fmaxf(outw[wc + cf * 16 + lr], 1e-8f) * (1.f / 256.f);
#pragma unroll
    for (int rf = 0; rf < 4; rf++)
#pragma unroll
        for (int cf = 0; cf < 4; cf++) {
            const int nn = n0 + wn + rf * 16 + lg * 4;
            const int c = wc + cf * 16 + lr;
#pragma unroll
            for (int r = 0; r < 4; r++)
                out[((size_t)b * Nn + nn + r) * Cn + c] = acc[rf][cf][r] * ow4[cf];
        }
}

// ---------------------------------------------------------------------------
extern "C" void kernel_launch(void* const* d_in, const int* in_sizes, int n_in,
                              void* d_out, int out_size, void* d_ws, size_t ws_size,
                              hipStream_t stream)
{
    const float* x     = (const float*)d_in[0];
    const float* mass  = (const float*)d_in[1];
    const float* evals = (const float*)d_in[2];
    const float* evecs = (const float*)d_in[3];
    const int*   far   = (const int*)d_in[4];
    const float* t_in  = (const float*)d_in[5];
    const float* t_out = (const float*)d_in[6];
    const float* gn_w  = (const float*)d_in[7];
    const float* gn_b  = (const float*)d_in[8];
    const float* Wq    = (const float*)d_in[9];
    const float* bq    = (const float*)d_in[10];
    const float* Wk    = (const float*)d_in[11];
    const float* bk    = (const float*)d_in[12];
    const float* Wv    = (const float*)d_in[13];
    const float* bv    = (const float*)d_in[14];
    const float* Wo    = (const float*)d_in[15];
    const float* bo    = (const float*)d_in[16];
    const float* outw  = (const float*)d_in[17];
    float* out = (float*)d_out;
    float* ws = (float*)d_ws;

    // --- Lifetime-aliased workspace layout (same offsets as rounds 5-11).
    float* A     = ws;                      // 8,388,608
    float* evf   = ws    + 8388608;         //   524,288 (k3..k10)
    float* massf = evf   + 524288;          //     4,096
    float* gst   = massf + 4096;            //       256
    float* pm    = gst   + 256;             //   262,144 (-> specT planes)
    float* pl    = pm    + 262144;          //   262,144 (unused)
    float* spec1 = pl    + 262144;          //   131,072
    float* xfar  = spec1 + 131072;          // 1,048,576
    float* xn    = xfar  + 1048576;         // 1,048,576
    float* q     = xn    + 1048576;         // 1,048,576
    float* kk    = q     + 1048576;         // 1,048,576
    float* v     = kk    + 1048576;         // 1,048,576  (ends at 14,815,488)
    float* part2 = A;
    float* spec2 = spec1;   // spec1 dead after from_basis1
    float* xo    = xfar;    // xfar dead after gnapply
    float* att   = xn;      // xn dead after QKV gemm
    f16* specTh  = (f16*)pm;            // 131072 f16 = 256 KB
    f16* specTl  = specTh + 131072;     // 131072 f16 = 256 KB (fits pm slot)
    (void)pl;

    k_tobasis1<<<dim3(NCH, 1, Bn), 512, 0, stream>>>(x, mass, evecs, A);
    k_reduce<<<Bn * Kn, Cn, 0, stream>>>(A, NCH, evals, t_in, spec1);
    k_gather<<<Bn * Mn, Kn, 0, stream>>>(evecs, mass, far, evf, massf);
    {
        G3 g{};
        g.W[0] = spec1; g.bias[0] = nullptr; g.out[0] = xfar;
        k_gemm64<128, true, false><<<dim3(64, 4, 1), 256, 0, stream>>>(evf, g, nullptr);
    }
    k_gnstats<<<Bn * 32, 256, 0, stream>>>(xfar, gst);
    k_gnapply<<<1024, 256, 0, stream>>>(xfar, gst, gn_w, gn_b, xn);
    {
        G3 g{};
        g.W[0] = Wq; g.W[1] = Wk; g.W[2] = Wv;
        g.bias[0] = bq; g.bias[1] = bk; g.bias[2] = bv;
        g.out[0] = q; g.out[1] = kk; g.out[2] = v;
        k_gemm64<256, false, false><<<dim3(64, 4, 3), 256, 0, stream>>>(xn, g, nullptr);
    }
    k_attn<<<dim3(16, 32), 256, 0, stream>>>(q, kk, v, att);
    {
        G3 g{};
        g.W[0] = Wo; g.bias[0] = bo; g.out[0] = xo;
        k_gemm64<256, false, true><<<dim3(64, 4, 1), 256, 0, stream>>>(att, g, massf);
    }
    k_tobasis2<<<dim3(MCH, 2, Bn), 256, 0, stream>>>(evf, xo, part2);
    k_reduce<<<Bn * Kn, Cn, 0, stream>>>(part2, MCH, evals, t_out, spec2);
    k_spectr<<<dim3(4, Bn), 256, 0, stream>>>(spec2, specTh, specTl);
    k_frombasis2<<<dim3(256, 1, Bn), 512, 0, stream>>>(evecs, specTh, specTl, outw, out);
}